// Round 5
// baseline (5742.123 us; speedup 1.0000x reference)
//
#include <hip/hip_runtime.h>

#define BSZ   16
#define LSEQ  8192
#define DMDL  64
#define DSD   32
#define HDD   32
#define NHD   4
#define DIN   128
#define NLAY  2
#define NOUTC 6
#define DPRJ  324
#define QC    64
#define NCH   128   // LSEQ/QC

// ---- device-global scratch ----
__device__ float g_h0[BSZ*LSEQ*DMDL];
__device__ float g_za[BSZ*LSEQ*DIN];        // silu(z)
__device__ float g_xy[BSZ*LSEQ*DIN];        // y_intra (+D*x)
__device__ float g_Ca[BSZ*LSEQ*DSD];        // silu(C) (needed by k_s3)
__device__ float g_pc[BSZ*LSEQ*NHD];        // exp(S_t)
__device__ float g_cS[BSZ*NCH*NHD*HDD*DSD]; // chunk states, scanned in-place -> H_in
__device__ float g_cL[BSZ*NCH*NHD];
__device__ float g_pp[BSZ*16*DMDL];

__device__ __forceinline__ float silu_f(float v){ return v / (1.0f + __expf(-v)); }
__device__ __forceinline__ float softplus_f(float v){ return (v > 15.0f) ? v : __logf(1.0f + __expf(v)); }

// ---------------- linear_in ----------------
__global__ __launch_bounds__(256) void k_linin(
    const float* __restrict__ x, const float* __restrict__ W,
    const float* __restrict__ bias)
{
  __shared__ float xs[64*60];
  __shared__ float wl[57*64];
  const int tid = threadIdx.x;
  const long tb = (long)blockIdx.x * 64;
  for (int i = tid; i < 64*57; i += 256){
    int t = i / 57, k = i - t*57;
    xs[t*60 + k] = x[tb*57 + i];
  }
  for (int i = tid; i < 57*64; i += 256) wl[i] = W[i];
  __syncthreads();
  const int t0 = (tid >> 4) * 4, d0 = (tid & 15) * 4;
  float acc[4][4];
  #pragma unroll
  for (int i = 0; i < 4; ++i)
    #pragma unroll
    for (int j = 0; j < 4; ++j) acc[i][j] = 0.f;
  for (int k = 0; k < 57; ++k){
    float4 w4 = *(const float4*)&wl[k*64 + d0];
    float wv[4] = {w4.x, w4.y, w4.z, w4.w};
    #pragma unroll
    for (int i = 0; i < 4; ++i){
      float xv = xs[(t0+i)*60 + k];
      #pragma unroll
      for (int j = 0; j < 4; ++j) acc[i][j] += xv * wv[j];
    }
  }
  float4 b4 = *(const float4*)&bias[d0];
  float bv[4] = {b4.x, b4.y, b4.z, b4.w};
  #pragma unroll
  for (int i = 0; i < 4; ++i){
    float4 o;
    o.x = acc[i][0] + bv[0]; o.y = acc[i][1] + bv[1];
    o.z = acc[i][2] + bv[2]; o.w = acc[i][3] + bv[3];
    *(float4*)&g_h0[(tb + t0 + i)*64 + d0] = o;
  }
}

// ---------------- FUSED in_proj GEMM + chunk intra scan ----------------
__global__ __launch_bounds__(256,2) void k_ps1(
    const float* __restrict__ W, const float* __restrict__ bias,
    const float* __restrict__ dt_bias, const float* __restrict__ A_log,
    const float* __restrict__ Dp, int l)
{
  __shared__ float u_ab[2*32*68]; // phase A: hst[32][68] + Wt[32][68]; phase B alias: Gl[64][65]
  __shared__ float Xf[64*132];    // silu(x) [t][p=128] pad 132
  __shared__ float Bs[64*37];     // silu(B) [s][n]
  __shared__ float Cs[64*37];     // silu(C) [t][n]
  __shared__ float dtl[4*64];
  __shared__ float Sl[4*64];
  __shared__ float wl[4*64];
  __shared__ float carr[4*64];
  __shared__ float earr[16*64];   // phase B: [h][beta][t]; phase A alias: dtw[64][4]
  __shared__ float Send[4];
  __shared__ float Rb[16];
  const int tid = threadIdx.x;
  const int cI = blockIdx.x, b = blockIdx.y;
  const long tb = (long)b*LSEQ + (long)cI*QC;
  const float* Wl = W + (long)l*64*DPRJ;
  const float* bl = bias + (long)l*DPRJ;
  float* hst = u_ab;            // [32][68]
  float* Wt  = u_ab + 32*68;    // [32][68]
  float* dtw = earr;            // [64][4] alias (earr not yet live)
  const int t0 = (tid >> 4) * 4, c0 = (tid & 15) * 4;

  // stage dt weight columns (64 x 4) once
  if (tid < 256){
    const int k = tid >> 2, hh = tid & 3;
    dtw[k*4 + hh] = Wl[k*DPRJ + 320 + hh];
  }

  // ---- Phase A: GEMM h0[64x64] @ W[64x320] (5 static tiles) + dt dot ----
  float acc[5][4][4];           // 80 VGPRs, statically indexed only
  #pragma unroll
  for (int ct = 0; ct < 5; ++ct)
    #pragma unroll
    for (int i = 0; i < 4; ++i)
      #pragma unroll
      for (int j = 0; j < 4; ++j) acc[ct][i][j] = 0.f;
  float dtacc = 0.f;
  const int dtt = tid >> 2, dth = tid & 3;   // (token, head) for dt
  #pragma unroll
  for (int kh = 0; kh < 2; ++kh){
    __syncthreads();            // prior iteration's consumers done (and dtw staged, kh=0)
    for (int i = tid; i < 2048; i += 256){
      int t = i >> 5, k = i & 31;
      hst[k*68 + t] = g_h0[(tb + t)*64 + kh*32 + k];
    }
    #pragma unroll
    for (int ct = 0; ct < 5; ++ct){
      __syncthreads();          // hst ready (ct=0) / prior Wt consumed
      for (int i = tid; i < 2048; i += 256){
        int k = i >> 6, cc = i & 63;
        Wt[k*68 + cc] = Wl[(kh*32 + k)*DPRJ + ct*64 + cc];
      }
      __syncthreads();
      for (int k = 0; k < 32; ++k){
        float4 h4 = *(const float4*)&hst[k*68 + t0];
        float4 w4 = *(const float4*)&Wt[k*68 + c0];
        float hv[4] = {h4.x, h4.y, h4.z, h4.w};
        float wv[4] = {w4.x, w4.y, w4.z, w4.w};
        #pragma unroll
        for (int i = 0; i < 4; ++i)
          #pragma unroll
          for (int j = 0; j < 4; ++j) acc[ct][i][j] += hv[i] * wv[j];
      }
    }
    for (int k = 0; k < 32; ++k)          // dt partial for this K-half
      dtacc += hst[k*68 + dtt] * dtw[(kh*32 + k)*4 + dth];
  }
  // ---- epilogue: z -> global; x -> LDS; B -> LDS; C -> LDS+global; dt -> LDS ----
  #pragma unroll
  for (int ct = 0; ct < 2; ++ct){   // z
    const int gc0 = ct*64 + c0;
    float bv[4] = {bl[gc0], bl[gc0+1], bl[gc0+2], bl[gc0+3]};
    #pragma unroll
    for (int i = 0; i < 4; ++i){
      float4 o;
      o.x = silu_f(acc[ct][i][0] + bv[0]);
      o.y = silu_f(acc[ct][i][1] + bv[1]);
      o.z = silu_f(acc[ct][i][2] + bv[2]);
      o.w = silu_f(acc[ct][i][3] + bv[3]);
      *(float4*)&g_za[(tb + t0 + i)*128 + gc0] = o;
    }
  }
  #pragma unroll
  for (int ct = 2; ct < 4; ++ct){   // x
    const int gc0 = ct*64 + c0;
    const int p0 = gc0 - 128;
    float bv[4] = {bl[gc0], bl[gc0+1], bl[gc0+2], bl[gc0+3]};
    #pragma unroll
    for (int i = 0; i < 4; ++i){
      float4 o;
      o.x = silu_f(acc[ct][i][0] + bv[0]);
      o.y = silu_f(acc[ct][i][1] + bv[1]);
      o.z = silu_f(acc[ct][i][2] + bv[2]);
      o.w = silu_f(acc[ct][i][3] + bv[3]);
      *(float4*)&Xf[(t0+i)*132 + p0] = o;
    }
  }
  {                                  // B / C
    const int gc0 = 256 + c0;
    float bv[4] = {bl[gc0], bl[gc0+1], bl[gc0+2], bl[gc0+3]};
    if (c0 < 32){
      #pragma unroll
      for (int i = 0; i < 4; ++i)
        #pragma unroll
        for (int j = 0; j < 4; ++j)
          Bs[(t0+i)*37 + c0 + j] = silu_f(acc[4][i][j] + bv[j]);
    } else {
      const int n0 = c0 - 32;
      #pragma unroll
      for (int i = 0; i < 4; ++i){
        float4 o;
        o.x = silu_f(acc[4][i][0] + bv[0]);
        o.y = silu_f(acc[4][i][1] + bv[1]);
        o.z = silu_f(acc[4][i][2] + bv[2]);
        o.w = silu_f(acc[4][i][3] + bv[3]);
        Cs[(t0+i)*37 + n0    ] = o.x;
        Cs[(t0+i)*37 + n0 + 1] = o.y;
        Cs[(t0+i)*37 + n0 + 2] = o.z;
        Cs[(t0+i)*37 + n0 + 3] = o.w;
        *(float4*)&g_Ca[(tb + t0 + i)*32 + n0] = o;
      }
    }
  }
  // dt: every thread owns one (token, head)
  dtl[dth*64 + dtt] = softplus_f(dtacc + bl[320 + dth] + dt_bias[l*4 + dth]);
  __syncthreads();
  // ---- Phase B: chunk-local scan ----
  if (tid < 4){
    const int h = tid;
    const float Ah = -__expf(A_log[l*4 + h]);
    float run = 0.f;
    for (int t = 0; t < 64; ++t){
      if ((t & 15) == 0) Rb[h*4 + (t>>4)] = run;
      run += dtl[h*64 + t] * Ah;
      Sl[h*64 + t] = run;
    }
    Send[h] = run;
    g_cL[((long)b*NCH + cI)*4 + h] = run;
  }
  __syncthreads();
  {
    const int h = tid >> 6, s = tid & 63;
    const float sl = Sl[h*64 + s];
    wl[h*64 + s]   = __expf(Send[h] - sl) * dtl[h*64 + s];
    carr[h*64 + s] = __expf(Rb[h*4 + (s>>4)] - sl) * dtl[h*64 + s];
  }
  { int t = tid >> 2, h = tid & 3; g_pc[(tb + t)*4 + h] = __expf(Sl[h*64 + t]); }
  for (int i = tid; i < 1024; i += 256){
    const int h = i >> 8, bb = (i >> 6) & 3, t = i & 63;
    earr[i] = (t >= bb*16) ? __expf(Sl[h*64 + t] - Rb[h*4 + bb]) : 0.f;
  }
  float* Gl = u_ab;   // [64][65], aliases dead hst/Wt
  if (c0 <= t0 + 3){  // G[t][s] = B_s . C_t (lower-triangle tiles)
    const int s0 = c0;
    float ga[4][4];
    #pragma unroll
    for (int i = 0; i < 4; ++i)
      #pragma unroll
      for (int j = 0; j < 4; ++j) ga[i][j] = 0.f;
    for (int n = 0; n < 32; ++n){
      float bva[4], cva[4];
      #pragma unroll
      for (int j = 0; j < 4; ++j) bva[j] = Bs[(s0+j)*37 + n];
      #pragma unroll
      for (int i = 0; i < 4; ++i) cva[i] = Cs[(t0+i)*37 + n];
      #pragma unroll
      for (int i = 0; i < 4; ++i)
        #pragma unroll
        for (int j = 0; j < 4; ++j) ga[i][j] += cva[i] * bva[j];
    }
    #pragma unroll
    for (int i = 0; i < 4; ++i)
      #pragma unroll
      for (int j = 0; j < 4; ++j) Gl[(t0+i)*65 + s0 + j] = ga[i][j];
  }
  __syncthreads();
  const int tt0 = (tid >> 3) * 2;
  const int p0g = (tid & 7) * 4;
  const int tblk = tt0 >> 4;
  const int pp = tid >> 3;
  const int n0 = (tid & 7) * 4;
  for (int h = 0; h < NHD; ++h){
    const float Dh = Dp[l*4 + h];
    { // y_intra: M[t][s] = e[beta][t]*c[s]*G[t][s], s<=t
      float a0[4] = {0,0,0,0}, a1[4] = {0,0,0,0};
      for (int bb = 0; bb <= tblk; ++bb){
        const float e0 = earr[(h*4 + bb)*64 + tt0];
        const float e1 = earr[(h*4 + bb)*64 + tt0 + 1];
        const int sbase = bb * 16;
        if (bb < tblk){
          #pragma unroll
          for (int ss = 0; ss < 16; ++ss){
            const int s = sbase + ss;
            const float c = carr[h*64 + s];
            const float m0 = e0 * c * Gl[tt0*65 + s];
            const float m1 = e1 * c * Gl[(tt0+1)*65 + s];
            float4 x4 = *(const float4*)&Xf[s*132 + h*32 + p0g];
            float xv[4] = {x4.x, x4.y, x4.z, x4.w};
            #pragma unroll
            for (int j = 0; j < 4; ++j){ a0[j] += m0 * xv[j]; a1[j] += m1 * xv[j]; }
          }
        } else {
          #pragma unroll
          for (int ss = 0; ss < 16; ++ss){
            const int s = sbase + ss;
            const float c = carr[h*64 + s];
            const float m0 = (s <= tt0    ) ? e0 * c * Gl[tt0*65 + s]     : 0.f;
            const float m1 = (s <= tt0 + 1) ? e1 * c * Gl[(tt0+1)*65 + s] : 0.f;
            float4 x4 = *(const float4*)&Xf[s*132 + h*32 + p0g];
            float xv[4] = {x4.x, x4.y, x4.z, x4.w};
            #pragma unroll
            for (int j = 0; j < 4; ++j){ a0[j] += m0 * xv[j]; a1[j] += m1 * xv[j]; }
          }
        }
      }
      float4 xt0 = *(const float4*)&Xf[tt0*132 + h*32 + p0g];
      float4 xt1 = *(const float4*)&Xf[(tt0+1)*132 + h*32 + p0g];
      float4 o0, o1;
      o0.x = a0[0] + Dh*xt0.x; o0.y = a0[1] + Dh*xt0.y; o0.z = a0[2] + Dh*xt0.z; o0.w = a0[3] + Dh*xt0.w;
      o1.x = a1[0] + Dh*xt1.x; o1.y = a1[1] + Dh*xt1.y; o1.z = a1[2] + Dh*xt1.z; o1.w = a1[3] + Dh*xt1.w;
      *(float4*)&g_xy[(tb + tt0    )*128 + h*32 + p0g] = o0;
      *(float4*)&g_xy[(tb + tt0 + 1)*128 + h*32 + p0g] = o1;
    }
    { // chunkS[p][n] = sum_s wl[s] * X[s][p] * B[s][n]
      float accs[4] = {0,0,0,0};
      for (int s = 0; s < 64; ++s){
        const float wx = wl[h*64 + s] * Xf[s*132 + h*32 + pp];
        #pragma unroll
        for (int j = 0; j < 4; ++j) accs[j] += wx * Bs[s*37 + n0 + j];
      }
      float4 o; o.x = accs[0]; o.y = accs[1]; o.z = accs[2]; o.w = accs[3];
      *(float4*)&g_cS[(((long)b*NCH + cI)*NHD + h)*(HDD*DSD) + pp*32 + n0] = o;
    }
  }
}

// ---------------- cross-chunk state prefix scan (in place) ----------------
__global__ __launch_bounds__(128) void k_s2()
{
  const int h = blockIdx.x >> 3, seg = blockIdx.x & 7, b = blockIdx.y;
  const int idx = seg*128 + threadIdx.x;
  float H = 0.f;
  for (int c = 0; c < NCH; ++c){
    const long o = (((long)b*NCH + c)*NHD + h)*1024 + idx;
    const float cs = g_cS[o];
    const float lg = g_cL[((long)b*NCH + c)*4 + h];
    g_cS[o] = H;
    H = __expf(lg) * H + cs;
  }
}

// ---------------- y_inter + gate + out_proj (two k-halves) + residual ----------------
__global__ __launch_bounds__(256) void k_s3(
    const float* __restrict__ Wo, const float* __restrict__ bo, int l)
{
  __shared__ float Hl[128*33];
  __shared__ float Cl[64*36];
  __shared__ float pcl[4*64];
  __shared__ float gl[64*68];
  const int tid = threadIdx.x;
  const int cI = blockIdx.x, b = blockIdx.y;
  const long tb = (long)b*LSEQ + (long)cI*QC;
  const long hb = (((long)b*NCH + cI)*NHD)*(long)(HDD*DSD);
  for (int i = tid; i < 4096; i += 256) Hl[(i>>5)*33 + (i&31)] = g_cS[hb + i];
  for (int i = tid; i < 2048; i += 256){
    int t = i >> 5, n = i & 31;
    Cl[t*36 + n] = g_Ca[(tb + t)*32 + n];
  }
  { int t = tid >> 2, h = tid & 3; pcl[h*64 + t] = g_pc[(tb + t)*4 + h]; }
  __syncthreads();
  const int t0 = (tid >> 4) * 4;
  const int q = tid & 15;
  float acc[4][8];
  #pragma unroll
  for (int i = 0; i < 4; ++i)
    #pragma unroll
    for (int j = 0; j < 8; ++j) acc[i][j] = 0.f;
  for (int n = 0; n < 32; ++n){
    float cv[4], hv[8];
    #pragma unroll
    for (int i = 0; i < 4; ++i) cv[i] = Cl[(t0+i)*36 + n];
    #pragma unroll
    for (int j = 0; j < 8; ++j) hv[j] = Hl[(q + 16*j)*33 + n];
    #pragma unroll
    for (int i = 0; i < 4; ++i)
      #pragma unroll
      for (int j = 0; j < 8; ++j) acc[i][j] += cv[i] * hv[j];
  }
  float yg[4][8];
  #pragma unroll
  for (int i = 0; i < 4; ++i){
    const long tok = tb + t0 + i;
    #pragma unroll
    for (int j = 0; j < 8; ++j){
      const int hp = q + 16*j;
      const int h = hp >> 5;
      const float v = pcl[h*64 + t0 + i] * acc[i][j] + g_xy[tok*128 + hp];
      yg[i][j] = v * silu_f(g_za[tok*128 + hp]);
    }
  }
  const int dm0 = (tid & 15) * 4;
  const float* Wol = Wo + (long)l * 128 * 64;
  float a2[4][4];
  #pragma unroll
  for (int i = 0; i < 4; ++i)
    #pragma unroll
    for (int j = 0; j < 4; ++j) a2[i][j] = 0.f;
  #pragma unroll
  for (int half = 0; half < 2; ++half){
    __syncthreads();
    #pragma unroll
    for (int i = 0; i < 4; ++i)
      #pragma unroll
      for (int j = 0; j < 4; ++j){
        const int hp = q + 16*(j + 4*half);
        gl[(t0+i)*68 + (hp - 64*half)] = yg[i][j + 4*half];
      }
    __syncthreads();
    for (int kk = 0; kk < 64; ++kk){
      float4 w4 = *(const float4*)&Wol[(kk + 64*half)*64 + dm0];
      float wv[4] = {w4.x, w4.y, w4.z, w4.w};
      #pragma unroll
      for (int ii = 0; ii < 4; ++ii){
        const float gv = gl[(t0+ii)*68 + kk];
        #pragma unroll
        for (int j = 0; j < 4; ++j) a2[ii][j] += gv * wv[j];
      }
    }
  }
  float4 b4 = *(const float4*)&bo[l*64 + dm0];
  float bv[4] = {b4.x, b4.y, b4.z, b4.w};
  #pragma unroll
  for (int ii = 0; ii < 4; ++ii){
    const long tok = tb + t0 + ii;
    float4 h4 = *(const float4*)&g_h0[tok*64 + dm0];
    float hv[4] = {h4.x, h4.y, h4.z, h4.w};
    float4 o;
    o.x = a2[ii][0] + bv[0] + hv[0];
    o.y = a2[ii][1] + bv[1] + hv[1];
    o.z = a2[ii][2] + bv[2] + hv[2];
    o.w = a2[ii][3] + bv[3] + hv[3];
    *(float4*)&g_h0[tok*64 + dm0] = o;
  }
}

// ---------------- pooling + classifier ----------------
__global__ __launch_bounds__(256) void k_pool1()
{
  __shared__ float red[4*64];
  const int tid = threadIdx.x;
  const int cch = blockIdx.x, b = blockIdx.y;
  const int dm = tid & 63, g = tid >> 6;
  double acc = 0.0;
  const long base = ((long)b*LSEQ + cch*512 + g*128)*64 + dm;
  for (int i = 0; i < 128; ++i) acc += (double)g_h0[base + (long)i*64];
  red[g*64 + dm] = (float)acc;
  __syncthreads();
  if (g == 0){
    float s = red[dm] + red[64 + dm] + red[128 + dm] + red[192 + dm];
    g_pp[((long)b*16 + cch)*64 + dm] = s;
  }
}

__global__ __launch_bounds__(64) void k_pool2(
    const float* __restrict__ cW, const float* __restrict__ cb,
    float* __restrict__ out)
{
  __shared__ float pl[64];
  const int b = blockIdx.x, tid = threadIdx.x;
  float s = 0.f;
  for (int c = 0; c < 16; ++c) s += g_pp[((long)b*16 + c)*64 + tid];
  pl[tid] = s * (1.0f / 8192.0f);
  __syncthreads();
  if (tid < NOUTC){
    float acc = cb[tid];
    for (int dm = 0; dm < 64; ++dm) acc += pl[dm] * cW[dm*NOUTC + tid];
    out[b*NOUTC + tid] = acc;
  }
}

extern "C" void kernel_launch(void* const* d_in, const int* in_sizes, int n_in,
                              void* d_out, int out_size, void* d_ws, size_t ws_size,
                              hipStream_t stream)
{
  const float* x      = (const float*)d_in[0];
  const float* W_in   = (const float*)d_in[1];
  const float* b_in   = (const float*)d_in[2];
  const float* ipW    = (const float*)d_in[3];
  const float* ipb    = (const float*)d_in[4];
  const float* A_log  = (const float*)d_in[5];
  const float* Dp     = (const float*)d_in[6];
  const float* dtb    = (const float*)d_in[7];
  const float* opW    = (const float*)d_in[8];
  const float* opb    = (const float*)d_in[9];
  const float* clsW   = (const float*)d_in[10];
  const float* clsb   = (const float*)d_in[11];
  float* out = (float*)d_out;
  (void)d_ws; (void)ws_size;

  k_linin<<<2048, 256, 0, stream>>>(x, W_in, b_in);
  for (int l = 0; l < NLAY; ++l){
    k_ps1<<<dim3(NCH, BSZ), 256, 0, stream>>>(ipW, ipb, dtb, A_log, Dp, l);
    k_s2<<<dim3(32, BSZ), 128, 0, stream>>>();
    k_s3<<<dim3(NCH, BSZ), 256, 0, stream>>>(opW, opb, l);
  }
  k_pool1<<<dim3(16, BSZ), 256, 0, stream>>>();
  k_pool2<<<BSZ, 64, 0, stream>>>(clsW, clsb, out);
}

// Round 6
// 1498.863 us; speedup vs baseline: 3.8310x; 3.8310x over previous
//
#include <hip/hip_runtime.h>

#define BSZ   16
#define LSEQ  8192
#define DMDL  64
#define DSD   32
#define HDD   32
#define NHD   4
#define DIN   128
#define NLAY  2
#define NOUTC 6
#define DPRJ  324
#define QC    64
#define NCH   128   // LSEQ/QC

// ---- device-global scratch ----
__device__ float g_h0[BSZ*LSEQ*DMDL];
__device__ float g_za[BSZ*LSEQ*DIN];        // silu(z)
__device__ float g_xy[BSZ*LSEQ*DIN];        // y_intra (+D*x)
__device__ float g_Ca[BSZ*LSEQ*DSD];        // silu(C) (needed by k_s3)
__device__ float g_pc[BSZ*LSEQ*NHD];        // exp(S_t)
__device__ float g_cS[BSZ*NCH*NHD*HDD*DSD]; // chunk states, scanned in-place -> H_in
__device__ float g_cL[BSZ*NCH*NHD];
__device__ float g_pp[BSZ*16*DMDL];

__device__ __forceinline__ float silu_f(float v){ return v / (1.0f + __expf(-v)); }
__device__ __forceinline__ float softplus_f(float v){ return (v > 15.0f) ? v : __logf(1.0f + __expf(v)); }

// ---------------- linear_in ----------------
__global__ __launch_bounds__(256) void k_linin(
    const float* __restrict__ x, const float* __restrict__ W,
    const float* __restrict__ bias)
{
  __shared__ float xs[64*60];
  __shared__ float wl[57*64];
  const int tid = threadIdx.x;
  const long tb = (long)blockIdx.x * 64;
  for (int i = tid; i < 64*57; i += 256){
    int t = i / 57, k = i - t*57;
    xs[t*60 + k] = x[tb*57 + i];
  }
  for (int i = tid; i < 57*64; i += 256) wl[i] = W[i];
  __syncthreads();
  const int t0 = (tid >> 4) * 4, d0 = (tid & 15) * 4;
  float acc[4][4];
  #pragma unroll
  for (int i = 0; i < 4; ++i)
    #pragma unroll
    for (int j = 0; j < 4; ++j) acc[i][j] = 0.f;
  for (int k = 0; k < 57; ++k){
    float4 w4 = *(const float4*)&wl[k*64 + d0];
    float wv[4] = {w4.x, w4.y, w4.z, w4.w};
    #pragma unroll
    for (int i = 0; i < 4; ++i){
      float xv = xs[(t0+i)*60 + k];
      #pragma unroll
      for (int j = 0; j < 4; ++j) acc[i][j] += xv * wv[j];
    }
  }
  float4 b4 = *(const float4*)&bias[d0];
  float bv[4] = {b4.x, b4.y, b4.z, b4.w};
  #pragma unroll
  for (int i = 0; i < 4; ++i){
    float4 o;
    o.x = acc[i][0] + bv[0]; o.y = acc[i][1] + bv[1];
    o.z = acc[i][2] + bv[2]; o.w = acc[i][3] + bv[3];
    *(float4*)&g_h0[(tb + t0 + i)*64 + d0] = o;
  }
}

// ---------------- FUSED in_proj GEMM + chunk intra scan (low-reg structure) ----------------
__global__ __launch_bounds__(256,2) void k_ps1(
    const float* __restrict__ W, const float* __restrict__ bias,
    const float* __restrict__ dt_bias, const float* __restrict__ A_log,
    const float* __restrict__ Dp, int l)
{
  __shared__ float u_ab[2*32*68]; // phase A: hst[32][68] + Wt[32][68]; phase B alias: Gl[64][65]
  __shared__ float Xf[64*132];    // silu(x) [t][p=128] pad 132
  __shared__ float Bs[64*37];     // silu(B) [s][n]
  __shared__ float Cs[64*37];     // silu(C) [t][n]
  __shared__ float dtl[4*64];
  __shared__ float Sl[4*64];
  __shared__ float wl[4*64];
  __shared__ float carr[4*64];
  __shared__ float earr[16*64];   // phase B: [h][beta][t]; phase A alias: dtw[64][4]
  __shared__ float Send[4];
  __shared__ float Rb[16];
  const int tid = threadIdx.x;
  const int cI = blockIdx.x, b = blockIdx.y;
  const long tb = (long)b*LSEQ + (long)cI*QC;
  const float* Wl = W + (long)l*64*DPRJ;
  const float* bl = bias + (long)l*DPRJ;
  float* hst = u_ab;            // [32][68]
  float* Wt  = u_ab + 32*68;    // [32][68]
  float* dtw = earr;            // [64][4] alias (earr not yet live)
  const int t0 = (tid >> 4) * 4, c0 = (tid & 15) * 4;

  // stage dt weight columns (64 x 4) once; visible after first in-loop barrier
  { const int k = tid >> 2, hh = tid & 3; dtw[k*4 + hh] = Wl[k*DPRJ + 320 + hh]; }

  float dtacc = 0.f;
  const int dtt = tid >> 2, dth = tid & 3;   // (token, head) for dt

  // ---- Phase A: 5 column tiles, ONE acc[4][4] live at a time (round-3-proven shape) ----
  for (int ct = 0; ct < 5; ++ct){
    float acc[4][4];
    #pragma unroll
    for (int i = 0; i < 4; ++i)
      #pragma unroll
      for (int j = 0; j < 4; ++j) acc[i][j] = 0.f;
    for (int kh = 0; kh < 2; ++kh){
      __syncthreads();          // prior consumers of hst/Wt done (also covers dtw staging)
      for (int i = tid; i < 2048; i += 256){
        int t = i >> 5, k = i & 31;
        hst[k*68 + t] = g_h0[(tb + t)*64 + kh*32 + k];
      }
      for (int i = tid; i < 512; i += 256){
        int k = i >> 4, c4 = (i & 15) * 4;
        *(float4*)&Wt[k*68 + c4] = *(const float4*)&Wl[(kh*32 + k)*DPRJ + ct*64 + c4];
      }
      __syncthreads();
      #pragma unroll 8
      for (int k = 0; k < 32; ++k){
        float4 h4 = *(const float4*)&hst[k*68 + t0];
        float4 w4 = *(const float4*)&Wt[k*68 + c0];
        float hv[4] = {h4.x, h4.y, h4.z, h4.w};
        float wv[4] = {w4.x, w4.y, w4.z, w4.w};
        #pragma unroll
        for (int i = 0; i < 4; ++i)
          #pragma unroll
          for (int j = 0; j < 4; ++j) acc[i][j] += hv[i] * wv[j];
      }
      if (ct == 0){             // dt dot-product rides on hst while this K-half is live
        for (int k = 0; k < 32; ++k)
          dtacc += hst[k*68 + dtt] * dtw[(kh*32 + k)*4 + dth];
      }
    }
    // ---- epilogue for this tile (acc dies here) ----
    const int gc0 = ct*64 + c0;
    float bv[4] = {bl[gc0], bl[gc0+1], bl[gc0+2], bl[gc0+3]};
    if (ct < 2){                // z -> global
      #pragma unroll
      for (int i = 0; i < 4; ++i){
        float4 o;
        o.x = silu_f(acc[i][0] + bv[0]);
        o.y = silu_f(acc[i][1] + bv[1]);
        o.z = silu_f(acc[i][2] + bv[2]);
        o.w = silu_f(acc[i][3] + bv[3]);
        *(float4*)&g_za[(tb + t0 + i)*128 + gc0] = o;
      }
    } else if (ct < 4){         // x -> LDS only
      const int p0 = gc0 - 128;
      #pragma unroll
      for (int i = 0; i < 4; ++i){
        float4 o;
        o.x = silu_f(acc[i][0] + bv[0]);
        o.y = silu_f(acc[i][1] + bv[1]);
        o.z = silu_f(acc[i][2] + bv[2]);
        o.w = silu_f(acc[i][3] + bv[3]);
        *(float4*)&Xf[(t0+i)*132 + p0] = o;
      }
    } else {                    // B -> LDS; C -> LDS + global
      if (c0 < 32){
        #pragma unroll
        for (int i = 0; i < 4; ++i)
          #pragma unroll
          for (int j = 0; j < 4; ++j)
            Bs[(t0+i)*37 + c0 + j] = silu_f(acc[i][j] + bv[j]);
      } else {
        const int n0 = c0 - 32;
        #pragma unroll
        for (int i = 0; i < 4; ++i){
          float4 o;
          o.x = silu_f(acc[i][0] + bv[0]);
          o.y = silu_f(acc[i][1] + bv[1]);
          o.z = silu_f(acc[i][2] + bv[2]);
          o.w = silu_f(acc[i][3] + bv[3]);
          Cs[(t0+i)*37 + n0    ] = o.x;
          Cs[(t0+i)*37 + n0 + 1] = o.y;
          Cs[(t0+i)*37 + n0 + 2] = o.z;
          Cs[(t0+i)*37 + n0 + 3] = o.w;
          *(float4*)&g_Ca[(tb + t0 + i)*32 + n0] = o;
        }
      }
    }
  }
  // dt: every thread owns one (token, head)
  dtl[dth*64 + dtt] = softplus_f(dtacc + bl[320 + dth] + dt_bias[l*4 + dth]);
  __syncthreads();
  // ---- Phase B: chunk-local scan (validated in rounds 2-5) ----
  if (tid < 4){
    const int h = tid;
    const float Ah = -__expf(A_log[l*4 + h]);
    float run = 0.f;
    for (int t = 0; t < 64; ++t){
      if ((t & 15) == 0) Rb[h*4 + (t>>4)] = run;
      run += dtl[h*64 + t] * Ah;
      Sl[h*64 + t] = run;
    }
    Send[h] = run;
    g_cL[((long)b*NCH + cI)*4 + h] = run;
  }
  __syncthreads();
  {
    const int h = tid >> 6, s = tid & 63;
    const float sl = Sl[h*64 + s];
    wl[h*64 + s]   = __expf(Send[h] - sl) * dtl[h*64 + s];
    carr[h*64 + s] = __expf(Rb[h*4 + (s>>4)] - sl) * dtl[h*64 + s];
  }
  { int t = tid >> 2, h = tid & 3; g_pc[(tb + t)*4 + h] = __expf(Sl[h*64 + t]); }
  for (int i = tid; i < 1024; i += 256){
    const int h = i >> 8, bb = (i >> 6) & 3, t = i & 63;
    earr[i] = (t >= bb*16) ? __expf(Sl[h*64 + t] - Rb[h*4 + bb]) : 0.f;
  }
  float* Gl = u_ab;   // [64][65], aliases dead hst/Wt
  if (c0 <= t0 + 3){  // G[t][s] = B_s . C_t (lower-triangle tiles)
    const int s0 = c0;
    float ga[4][4];
    #pragma unroll
    for (int i = 0; i < 4; ++i)
      #pragma unroll
      for (int j = 0; j < 4; ++j) ga[i][j] = 0.f;
    for (int n = 0; n < 32; ++n){
      float bva[4], cva[4];
      #pragma unroll
      for (int j = 0; j < 4; ++j) bva[j] = Bs[(s0+j)*37 + n];
      #pragma unroll
      for (int i = 0; i < 4; ++i) cva[i] = Cs[(t0+i)*37 + n];
      #pragma unroll
      for (int i = 0; i < 4; ++i)
        #pragma unroll
        for (int j = 0; j < 4; ++j) ga[i][j] += cva[i] * bva[j];
    }
    #pragma unroll
    for (int i = 0; i < 4; ++i)
      #pragma unroll
      for (int j = 0; j < 4; ++j) Gl[(t0+i)*65 + s0 + j] = ga[i][j];
  }
  __syncthreads();
  const int tt0 = (tid >> 3) * 2;
  const int p0g = (tid & 7) * 4;
  const int tblk = tt0 >> 4;
  const int pp = tid >> 3;
  const int n0 = (tid & 7) * 4;
  for (int h = 0; h < NHD; ++h){
    const float Dh = Dp[l*4 + h];
    { // y_intra: M[t][s] = e[beta][t]*c[s]*G[t][s], s<=t
      float a0[4] = {0,0,0,0}, a1[4] = {0,0,0,0};
      for (int bb = 0; bb <= tblk; ++bb){
        const float e0 = earr[(h*4 + bb)*64 + tt0];
        const float e1 = earr[(h*4 + bb)*64 + tt0 + 1];
        const int sbase = bb * 16;
        if (bb < tblk){
          #pragma unroll
          for (int ss = 0; ss < 16; ++ss){
            const int s = sbase + ss;
            const float c = carr[h*64 + s];
            const float m0 = e0 * c * Gl[tt0*65 + s];
            const float m1 = e1 * c * Gl[(tt0+1)*65 + s];
            float4 x4 = *(const float4*)&Xf[s*132 + h*32 + p0g];
            float xv[4] = {x4.x, x4.y, x4.z, x4.w};
            #pragma unroll
            for (int j = 0; j < 4; ++j){ a0[j] += m0 * xv[j]; a1[j] += m1 * xv[j]; }
          }
        } else {
          #pragma unroll
          for (int ss = 0; ss < 16; ++ss){
            const int s = sbase + ss;
            const float c = carr[h*64 + s];
            const float m0 = (s <= tt0    ) ? e0 * c * Gl[tt0*65 + s]     : 0.f;
            const float m1 = (s <= tt0 + 1) ? e1 * c * Gl[(tt0+1)*65 + s] : 0.f;
            float4 x4 = *(const float4*)&Xf[s*132 + h*32 + p0g];
            float xv[4] = {x4.x, x4.y, x4.z, x4.w};
            #pragma unroll
            for (int j = 0; j < 4; ++j){ a0[j] += m0 * xv[j]; a1[j] += m1 * xv[j]; }
          }
        }
      }
      float4 xt0 = *(const float4*)&Xf[tt0*132 + h*32 + p0g];
      float4 xt1 = *(const float4*)&Xf[(tt0+1)*132 + h*32 + p0g];
      float4 o0, o1;
      o0.x = a0[0] + Dh*xt0.x; o0.y = a0[1] + Dh*xt0.y; o0.z = a0[2] + Dh*xt0.z; o0.w = a0[3] + Dh*xt0.w;
      o1.x = a1[0] + Dh*xt1.x; o1.y = a1[1] + Dh*xt1.y; o1.z = a1[2] + Dh*xt1.z; o1.w = a1[3] + Dh*xt1.w;
      *(float4*)&g_xy[(tb + tt0    )*128 + h*32 + p0g] = o0;
      *(float4*)&g_xy[(tb + tt0 + 1)*128 + h*32 + p0g] = o1;
    }
    { // chunkS[p][n] = sum_s wl[s] * X[s][p] * B[s][n]
      float accs[4] = {0,0,0,0};
      for (int s = 0; s < 64; ++s){
        const float wx = wl[h*64 + s] * Xf[s*132 + h*32 + pp];
        #pragma unroll
        for (int j = 0; j < 4; ++j) accs[j] += wx * Bs[s*37 + n0 + j];
      }
      float4 o; o.x = accs[0]; o.y = accs[1]; o.z = accs[2]; o.w = accs[3];
      *(float4*)&g_cS[(((long)b*NCH + cI)*NHD + h)*(HDD*DSD) + pp*32 + n0] = o;
    }
  }
}

// ---------------- cross-chunk state prefix scan (in place) ----------------
__global__ __launch_bounds__(128) void k_s2()
{
  const int h = blockIdx.x >> 3, seg = blockIdx.x & 7, b = blockIdx.y;
  const int idx = seg*128 + threadIdx.x;
  float H = 0.f;
  for (int c = 0; c < NCH; ++c){
    const long o = (((long)b*NCH + c)*NHD + h)*1024 + idx;
    const float cs = g_cS[o];
    const float lg = g_cL[((long)b*NCH + c)*4 + h];
    g_cS[o] = H;
    H = __expf(lg) * H + cs;
  }
}

// ---------------- y_inter + gate + out_proj (two k-halves) + residual ----------------
__global__ __launch_bounds__(256) void k_s3(
    const float* __restrict__ Wo, const float* __restrict__ bo, int l)
{
  __shared__ float Hl[128*33];
  __shared__ float Cl[64*36];
  __shared__ float pcl[4*64];
  __shared__ float gl[64*68];
  const int tid = threadIdx.x;
  const int cI = blockIdx.x, b = blockIdx.y;
  const long tb = (long)b*LSEQ + (long)cI*QC;
  const long hb = (((long)b*NCH + cI)*NHD)*(long)(HDD*DSD);
  for (int i = tid; i < 4096; i += 256) Hl[(i>>5)*33 + (i&31)] = g_cS[hb + i];
  for (int i = tid; i < 2048; i += 256){
    int t = i >> 5, n = i & 31;
    Cl[t*36 + n] = g_Ca[(tb + t)*32 + n];
  }
  { int t = tid >> 2, h = tid & 3; pcl[h*64 + t] = g_pc[(tb + t)*4 + h]; }
  __syncthreads();
  const int t0 = (tid >> 4) * 4;
  const int q = tid & 15;
  float acc[4][8];
  #pragma unroll
  for (int i = 0; i < 4; ++i)
    #pragma unroll
    for (int j = 0; j < 8; ++j) acc[i][j] = 0.f;
  for (int n = 0; n < 32; ++n){
    float cv[4], hv[8];
    #pragma unroll
    for (int i = 0; i < 4; ++i) cv[i] = Cl[(t0+i)*36 + n];
    #pragma unroll
    for (int j = 0; j < 8; ++j) hv[j] = Hl[(q + 16*j)*33 + n];
    #pragma unroll
    for (int i = 0; i < 4; ++i)
      #pragma unroll
      for (int j = 0; j < 8; ++j) acc[i][j] += cv[i] * hv[j];
  }
  float yg[4][8];
  #pragma unroll
  for (int i = 0; i < 4; ++i){
    const long tok = tb + t0 + i;
    #pragma unroll
    for (int j = 0; j < 8; ++j){
      const int hp = q + 16*j;
      const int h = hp >> 5;
      const float v = pcl[h*64 + t0 + i] * acc[i][j] + g_xy[tok*128 + hp];
      yg[i][j] = v * silu_f(g_za[tok*128 + hp]);
    }
  }
  const int dm0 = (tid & 15) * 4;
  const float* Wol = Wo + (long)l * 128 * 64;
  float a2[4][4];
  #pragma unroll
  for (int i = 0; i < 4; ++i)
    #pragma unroll
    for (int j = 0; j < 4; ++j) a2[i][j] = 0.f;
  #pragma unroll
  for (int half = 0; half < 2; ++half){
    __syncthreads();
    #pragma unroll
    for (int i = 0; i < 4; ++i)
      #pragma unroll
      for (int j = 0; j < 4; ++j){
        const int hp = q + 16*(j + 4*half);
        gl[(t0+i)*68 + (hp - 64*half)] = yg[i][j + 4*half];
      }
    __syncthreads();
    for (int kk = 0; kk < 64; ++kk){
      float4 w4 = *(const float4*)&Wol[(kk + 64*half)*64 + dm0];
      float wv[4] = {w4.x, w4.y, w4.z, w4.w};
      #pragma unroll
      for (int ii = 0; ii < 4; ++ii){
        const float gv = gl[(t0+ii)*68 + kk];
        #pragma unroll
        for (int j = 0; j < 4; ++j) a2[ii][j] += gv * wv[j];
      }
    }
  }
  float4 b4 = *(const float4*)&bo[l*64 + dm0];
  float bv[4] = {b4.x, b4.y, b4.z, b4.w};
  #pragma unroll
  for (int ii = 0; ii < 4; ++ii){
    const long tok = tb + t0 + ii;
    float4 h4 = *(const float4*)&g_h0[tok*64 + dm0];
    float hv[4] = {h4.x, h4.y, h4.z, h4.w};
    float4 o;
    o.x = a2[ii][0] + bv[0] + hv[0];
    o.y = a2[ii][1] + bv[1] + hv[1];
    o.z = a2[ii][2] + bv[2] + hv[2];
    o.w = a2[ii][3] + bv[3] + hv[3];
    *(float4*)&g_h0[tok*64 + dm0] = o;
  }
}

// ---------------- pooling + classifier ----------------
__global__ __launch_bounds__(256) void k_pool1()
{
  __shared__ float red[4*64];
  const int tid = threadIdx.x;
  const int cch = blockIdx.x, b = blockIdx.y;
  const int dm = tid & 63, g = tid >> 6;
  double acc = 0.0;
  const long base = ((long)b*LSEQ + cch*512 + g*128)*64 + dm;
  for (int i = 0; i < 128; ++i) acc += (double)g_h0[base + (long)i*64];
  red[g*64 + dm] = (float)acc;
  __syncthreads();
  if (g == 0){
    float s = red[dm] + red[64 + dm] + red[128 + dm] + red[192 + dm];
    g_pp[((long)b*16 + cch)*64 + dm] = s;
  }
}

__global__ __launch_bounds__(64) void k_pool2(
    const float* __restrict__ cW, const float* __restrict__ cb,
    float* __restrict__ out)
{
  __shared__ float pl[64];
  const int b = blockIdx.x, tid = threadIdx.x;
  float s = 0.f;
  for (int c = 0; c < 16; ++c) s += g_pp[((long)b*16 + c)*64 + tid];
  pl[tid] = s * (1.0f / 8192.0f);
  __syncthreads();
  if (tid < NOUTC){
    float acc = cb[tid];
    for (int dm = 0; dm < 64; ++dm) acc += pl[dm] * cW[dm*NOUTC + tid];
    out[b*NOUTC + tid] = acc;
  }
}

extern "C" void kernel_launch(void* const* d_in, const int* in_sizes, int n_in,
                              void* d_out, int out_size, void* d_ws, size_t ws_size,
                              hipStream_t stream)
{
  const float* x      = (const float*)d_in[0];
  const float* W_in   = (const float*)d_in[1];
  const float* b_in   = (const float*)d_in[2];
  const float* ipW    = (const float*)d_in[3];
  const float* ipb    = (const float*)d_in[4];
  const float* A_log  = (const float*)d_in[5];
  const float* Dp     = (const float*)d_in[6];
  const float* dtb    = (const float*)d_in[7];
  const float* opW    = (const float*)d_in[8];
  const float* opb    = (const float*)d_in[9];
  const float* clsW   = (const float*)d_in[10];
  const float* clsb   = (const float*)d_in[11];
  float* out = (float*)d_out;
  (void)d_ws; (void)ws_size;

  k_linin<<<2048, 256, 0, stream>>>(x, W_in, b_in);
  for (int l = 0; l < NLAY; ++l){
    k_ps1<<<dim3(NCH, BSZ), 256, 0, stream>>>(ipW, ipb, dtb, A_log, Dp, l);
    k_s2<<<dim3(32, BSZ), 128, 0, stream>>>();
    k_s3<<<dim3(NCH, BSZ), 256, 0, stream>>>(opW, opb, l);
  }
  k_pool1<<<dim3(16, BSZ), 256, 0, stream>>>();
  k_pool2<<<BSZ, 64, 0, stream>>>(clsW, clsb, out);
}

// Round 7
// 737.611 us; speedup vs baseline: 7.7848x; 2.0321x over previous
//
#include <hip/hip_runtime.h>

#define BSZ   16
#define LSEQ  8192
#define DMDL  64
#define DSD   32
#define HDD   32
#define NHD   4
#define DIN   128
#define NLAY  2
#define NOUTC 6
#define DPRJ  324
#define QC    64
#define NCH   128   // LSEQ/QC

// ---- device-global scratch ----
__device__ float          g_h0[BSZ*LSEQ*DMDL];
__device__ unsigned short g_za[BSZ*LSEQ*DIN];   // RAW z, bf16 (silu applied once, in k_s3)
__device__ unsigned short g_xy[BSZ*LSEQ*DIN];   // silu(x), overwritten by y_intra (bf16)
__device__ float          g_Ba[BSZ*LSEQ*DSD];
__device__ float          g_Ca[BSZ*LSEQ*DSD];
__device__ float          g_dt[BSZ*LSEQ*NHD];
__device__ float          g_pc[BSZ*LSEQ*NHD];
__device__ float          g_cS[BSZ*NCH*NHD*HDD*DSD]; // chunk states, scanned in-place -> H_in
__device__ float          g_cL[BSZ*NCH*NHD];
__device__ float          g_ppc[BSZ*NCH*DMDL];       // per-chunk column sums (final layer)

__device__ __forceinline__ float silu_f(float v){ return v / (1.0f + __expf(-v)); }
__device__ __forceinline__ float softplus_f(float v){ return (v > 15.0f) ? v : __logf(1.0f + __expf(v)); }
__device__ __forceinline__ unsigned short f2bf(float f){
  union { float f; unsigned u; } v; v.f = f;
  unsigned r = v.u + 0x7FFFu + ((v.u >> 16) & 1u);
  return (unsigned short)(r >> 16);
}
__device__ __forceinline__ float bf2f(unsigned short h){
  union { unsigned u; float f; } v; v.u = ((unsigned)h) << 16;
  return v.f;
}

// ---------------- linear_in ----------------
__global__ __launch_bounds__(256) void k_linin(
    const float* __restrict__ x, const float* __restrict__ W,
    const float* __restrict__ bias)
{
  __shared__ float xs[64*60];
  __shared__ float wl[57*64];
  const int tid = threadIdx.x;
  const long tb = (long)blockIdx.x * 64;
  for (int i = tid; i < 64*57; i += 256){
    int t = i / 57, k = i - t*57;
    xs[t*60 + k] = x[tb*57 + i];
  }
  for (int i = tid; i < 57*64; i += 256) wl[i] = W[i];
  __syncthreads();
  const int t0 = (tid >> 4) * 4, d0 = (tid & 15) * 4;
  float acc[4][4];
  #pragma unroll
  for (int i = 0; i < 4; ++i)
    #pragma unroll
    for (int j = 0; j < 4; ++j) acc[i][j] = 0.f;
  for (int k = 0; k < 57; ++k){
    float4 w4 = *(const float4*)&wl[k*64 + d0];
    float wv[4] = {w4.x, w4.y, w4.z, w4.w};
    #pragma unroll
    for (int i = 0; i < 4; ++i){
      float xv = xs[(t0+i)*60 + k];
      #pragma unroll
      for (int j = 0; j < 4; ++j) acc[i][j] += xv * wv[j];
    }
  }
  float4 b4 = *(const float4*)&bias[d0];
  float bv[4] = {b4.x, b4.y, b4.z, b4.w};
  #pragma unroll
  for (int i = 0; i < 4; ++i){
    float4 o;
    o.x = acc[i][0] + bv[0]; o.y = acc[i][1] + bv[1];
    o.z = acc[i][2] + bv[2]; o.w = acc[i][3] + bv[3];
    *(float4*)&g_h0[(tb + t0 + i)*64 + d0] = o;
  }
}

// ---------------- in_proj GEMM + activations (128 tokens/block) ----------------
__global__ __launch_bounds__(256) void k_proj(
    const float* __restrict__ W, const float* __restrict__ bias,
    const float* __restrict__ dt_bias, int l)
{
  __shared__ float hst[64*132];  // [k][t] transposed, 128 tokens
  __shared__ float Wt[64*68];    // [k][c]
  const int tid = threadIdx.x;
  const long tb = (long)blockIdx.x * 128;
  for (int i = tid; i < 8192; i += 256){
    int t = i >> 6, k = i & 63;
    hst[k*132 + t] = g_h0[(tb + t)*64 + k];
  }
  const float* Wl = W + (long)l * 64 * DPRJ;
  const float* bl = bias + (long)l * DPRJ;
  const int t0 = (tid >> 4) * 8, c0 = (tid & 15) * 4;
  for (int ct = 0; ct < 6; ++ct){
    const int cbase = ct * 64;
    const int cw = (ct == 5) ? 4 : 64;
    __syncthreads();
    for (int i = tid; i < 64 * cw; i += 256){
      int k = i / cw, cc = i - k * cw;
      Wt[k*68 + cc] = Wl[k*DPRJ + cbase + cc];
    }
    __syncthreads();
    if (c0 < cw){
      float acc[8][4];
      #pragma unroll
      for (int i = 0; i < 8; ++i)
        #pragma unroll
        for (int j = 0; j < 4; ++j) acc[i][j] = 0.f;
      for (int k = 0; k < 64; ++k){
        float4 w4 = *(const float4*)&Wt[k*68 + c0];
        float4 ha = *(const float4*)&hst[k*132 + t0];
        float4 hb = *(const float4*)&hst[k*132 + t0 + 4];
        float wv[4] = {w4.x, w4.y, w4.z, w4.w};
        float hv[8] = {ha.x, ha.y, ha.z, ha.w, hb.x, hb.y, hb.z, hb.w};
        #pragma unroll
        for (int i = 0; i < 8; ++i)
          #pragma unroll
          for (int j = 0; j < 4; ++j) acc[i][j] += hv[i] * wv[j];
      }
      const int gc0 = cbase + c0;
      float bv[4] = {bl[gc0], bl[gc0+1], bl[gc0+2], bl[gc0+3]};
      #pragma unroll
      for (int i = 0; i < 8; ++i){
        const long tok = tb + t0 + i;
        float v[4];
        #pragma unroll
        for (int j = 0; j < 4; ++j) v[j] = acc[i][j] + bv[j];
        if (gc0 < 128){            // RAW z (bf16); silu applied once in k_s3
          ushort4 o;
          o.x = f2bf(v[0]); o.y = f2bf(v[1]); o.z = f2bf(v[2]); o.w = f2bf(v[3]);
          *(ushort4*)&g_za[tok*128 + gc0] = o;
        } else if (gc0 < 256){     // silu(x) (bf16)
          ushort4 o;
          o.x = f2bf(silu_f(v[0])); o.y = f2bf(silu_f(v[1]));
          o.z = f2bf(silu_f(v[2])); o.w = f2bf(silu_f(v[3]));
          *(ushort4*)&g_xy[tok*128 + gc0 - 128] = o;
        } else if (gc0 < 288){
          float4 o; o.x = silu_f(v[0]); o.y = silu_f(v[1]); o.z = silu_f(v[2]); o.w = silu_f(v[3]);
          *(float4*)&g_Ba[tok*32 + gc0 - 256] = o;
        } else if (gc0 < 320){
          float4 o; o.x = silu_f(v[0]); o.y = silu_f(v[1]); o.z = silu_f(v[2]); o.w = silu_f(v[3]);
          *(float4*)&g_Ca[tok*32 + gc0 - 288] = o;
        } else {
          float4 o;
          o.x = softplus_f(v[0] + dt_bias[l*4 + 0]);
          o.y = softplus_f(v[1] + dt_bias[l*4 + 1]);
          o.z = softplus_f(v[2] + dt_bias[l*4 + 2]);
          o.w = softplus_f(v[3] + dt_bias[l*4 + 3]);
          *(float4*)&g_dt[tok*4] = o;
        }
      }
    }
  }
}

// ---------------- chunk intra (no Ml materialization; block-factorized decay) ----------------
__global__ __launch_bounds__(256) void k_s1(
    const float* __restrict__ A_log, const float* __restrict__ Dp, int l)
{
  __shared__ float Bs[64*37];
  __shared__ float Cs[64*37];
  __shared__ float Gl[64*65];
  __shared__ float Xh[64*36];
  __shared__ float dtl[4*64];
  __shared__ float Sl[4*64];
  __shared__ float wl[4*64];
  __shared__ float carr[4*64];   // exp(R_b(s) - Sl[s]) * dt[s]
  __shared__ float earr[16*64];  // [h][beta][t]: exp(Sl[t]-R_beta), 0 if t<16*beta
  __shared__ float Send[4], Rb[16];
  const int tid = threadIdx.x;
  const int cI = blockIdx.x, b = blockIdx.y;
  const long tb = (long)b*LSEQ + (long)cI*QC;
  for (int i = tid; i < 2048; i += 256){
    int s = i >> 5, n = i & 31;
    Bs[s*37 + n] = g_Ba[(tb + s)*32 + n];
    Cs[s*37 + n] = g_Ca[(tb + s)*32 + n];
  }
  { int t = tid >> 2, h = tid & 3; dtl[h*64 + t] = g_dt[(tb + t)*4 + h]; }
  __syncthreads();
  if (tid < 4){
    const int h = tid;
    const float Ah = -__expf(A_log[l*4 + h]);
    float run = 0.f;
    for (int t = 0; t < 64; ++t){
      if ((t & 15) == 0) Rb[h*4 + (t>>4)] = run;
      run += dtl[h*64 + t] * Ah;
      Sl[h*64 + t] = run;
    }
    Send[h] = run;
    g_cL[((long)b*NCH + cI)*4 + h] = run;
  }
  __syncthreads();
  {
    const int h = tid >> 6, s = tid & 63;
    const float sl = Sl[h*64 + s];
    wl[h*64 + s]   = __expf(Send[h] - sl) * dtl[h*64 + s];
    carr[h*64 + s] = __expf(Rb[h*4 + (s>>4)] - sl) * dtl[h*64 + s];
  }
  { int t = tid >> 2, h = tid & 3; g_pc[(tb + t)*4 + h] = __expf(Sl[h*64 + t]); }
  for (int i = tid; i < 1024; i += 256){
    const int h = i >> 8, bb = (i >> 6) & 3, t = i & 63;
    earr[i] = (t >= bb*16) ? __expf(Sl[h*64 + t] - Rb[h*4 + bb]) : 0.f;
  }
  __syncthreads();
  const int t0 = (tid >> 4) * 4, s0 = (tid & 15) * 4;
  if (s0 <= t0 + 3){
    float acc[4][4];
    #pragma unroll
    for (int i = 0; i < 4; ++i)
      #pragma unroll
      for (int j = 0; j < 4; ++j) acc[i][j] = 0.f;
    for (int n = 0; n < 32; ++n){
      float bva[4], cva[4];
      #pragma unroll
      for (int j = 0; j < 4; ++j) bva[j] = Bs[(s0+j)*37 + n];
      #pragma unroll
      for (int i = 0; i < 4; ++i) cva[i] = Cs[(t0+i)*37 + n];
      #pragma unroll
      for (int i = 0; i < 4; ++i)
        #pragma unroll
        for (int j = 0; j < 4; ++j) acc[i][j] += cva[i] * bva[j];
    }
    #pragma unroll
    for (int i = 0; i < 4; ++i)
      #pragma unroll
      for (int j = 0; j < 4; ++j) Gl[(t0+i)*65 + s0 + j] = acc[i][j];
  }
  const int tt0 = (tid >> 3) * 2;
  const int p0g = (tid & 7) * 4;
  const int tblk = tt0 >> 4;
  for (int h = 0; h < NHD; ++h){
    __syncthreads();
    for (int i = tid; i < 512; i += 256){
      int s = i >> 3, p4 = (i & 7) * 4;
      ushort4 u = *(const ushort4*)&g_xy[(tb + s)*128 + h*32 + p4];
      float4 f; f.x = bf2f(u.x); f.y = bf2f(u.y); f.z = bf2f(u.z); f.w = bf2f(u.w);
      *(float4*)&Xh[s*36 + p4] = f;
    }
    __syncthreads();
    const float Dh = Dp[l*4 + h];
    {
      float a0[4] = {0,0,0,0}, a1[4] = {0,0,0,0};
      for (int bb = 0; bb <= tblk; ++bb){
        const float e0 = earr[(h*4 + bb)*64 + tt0];
        const float e1 = earr[(h*4 + bb)*64 + tt0 + 1];
        const int sbase = bb * 16;
        if (bb < tblk){
          #pragma unroll
          for (int ss = 0; ss < 16; ++ss){
            const int s = sbase + ss;
            const float c = carr[h*64 + s];
            const float m0 = e0 * c * Gl[tt0*65 + s];
            const float m1 = e1 * c * Gl[(tt0+1)*65 + s];
            float4 x4 = *(const float4*)&Xh[s*36 + p0g];
            float xv[4] = {x4.x, x4.y, x4.z, x4.w};
            #pragma unroll
            for (int j = 0; j < 4; ++j){ a0[j] += m0 * xv[j]; a1[j] += m1 * xv[j]; }
          }
        } else {
          #pragma unroll
          for (int ss = 0; ss < 16; ++ss){
            const int s = sbase + ss;
            const float c = carr[h*64 + s];
            const float m0 = (s <= tt0    ) ? e0 * c * Gl[tt0*65 + s]     : 0.f;
            const float m1 = (s <= tt0 + 1) ? e1 * c * Gl[(tt0+1)*65 + s] : 0.f;
            float4 x4 = *(const float4*)&Xh[s*36 + p0g];
            float xv[4] = {x4.x, x4.y, x4.z, x4.w};
            #pragma unroll
            for (int j = 0; j < 4; ++j){ a0[j] += m0 * xv[j]; a1[j] += m1 * xv[j]; }
          }
        }
      }
      float4 xt0 = *(const float4*)&Xh[tt0*36 + p0g];
      float4 xt1 = *(const float4*)&Xh[(tt0+1)*36 + p0g];
      ushort4 o0, o1;
      o0.x = f2bf(a0[0] + Dh*xt0.x); o0.y = f2bf(a0[1] + Dh*xt0.y);
      o0.z = f2bf(a0[2] + Dh*xt0.z); o0.w = f2bf(a0[3] + Dh*xt0.w);
      o1.x = f2bf(a1[0] + Dh*xt1.x); o1.y = f2bf(a1[1] + Dh*xt1.y);
      o1.z = f2bf(a1[2] + Dh*xt1.z); o1.w = f2bf(a1[3] + Dh*xt1.w);
      *(ushort4*)&g_xy[(tb + tt0    )*128 + h*32 + p0g] = o0;
      *(ushort4*)&g_xy[(tb + tt0 + 1)*128 + h*32 + p0g] = o1;
    }
    {
      const int pp = tid >> 3;
      const int n0 = (tid & 7) * 4;
      float accs[4] = {0,0,0,0};
      for (int s = 0; s < 64; ++s){
        const float wx = wl[h*64 + s] * Xh[s*36 + pp];
        #pragma unroll
        for (int j = 0; j < 4; ++j) accs[j] += wx * Bs[s*37 + n0 + j];
      }
      float4 o; o.x = accs[0]; o.y = accs[1]; o.z = accs[2]; o.w = accs[3];
      *(float4*)&g_cS[(((long)b*NCH + cI)*NHD + h)*(HDD*DSD) + pp*32 + n0] = o;
    }
  }
}

// ---------------- cross-chunk state prefix scan (in place) ----------------
__global__ __launch_bounds__(128) void k_s2()
{
  const int h = blockIdx.x >> 3, seg = blockIdx.x & 7, b = blockIdx.y;
  const int idx = seg*128 + threadIdx.x;
  float H = 0.f;
  for (int c = 0; c < NCH; ++c){
    const long o = (((long)b*NCH + c)*NHD + h)*1024 + idx;
    const float cs = g_cS[o];
    const float lg = g_cL[((long)b*NCH + c)*4 + h];
    g_cS[o] = H;
    H = __expf(lg) * H + cs;
  }
}

// ---------------- y_inter + gate + out_proj + residual (+ pool on final layer) ----------------
__global__ __launch_bounds__(256) void k_s3(
    const float* __restrict__ Wo, const float* __restrict__ bo, int l, int finalLayer)
{
  __shared__ float Hl[128*33];
  __shared__ float Cl[64*36];   // aliased as csum[16][68] in the pool epilogue
  __shared__ float pcl[4*64];
  __shared__ float gl[64*68];
  const int tid = threadIdx.x;
  const int cI = blockIdx.x, b = blockIdx.y;
  const long tb = (long)b*LSEQ + (long)cI*QC;
  const long hb = (((long)b*NCH + cI)*NHD)*(long)(HDD*DSD);
  for (int i = tid; i < 4096; i += 256) Hl[(i>>5)*33 + (i&31)] = g_cS[hb + i];
  for (int i = tid; i < 2048; i += 256){
    int t = i >> 5, n = i & 31;
    Cl[t*36 + n] = g_Ca[(tb + t)*32 + n];
  }
  { int t = tid >> 2, h = tid & 3; pcl[h*64 + t] = g_pc[(tb + t)*4 + h]; }
  __syncthreads();
  const int t0 = (tid >> 4) * 4;
  const int q = tid & 15;
  float acc[4][8];
  #pragma unroll
  for (int i = 0; i < 4; ++i)
    #pragma unroll
    for (int j = 0; j < 8; ++j) acc[i][j] = 0.f;
  for (int n = 0; n < 32; ++n){
    float cv[4], hv[8];
    #pragma unroll
    for (int i = 0; i < 4; ++i) cv[i] = Cl[(t0+i)*36 + n];
    #pragma unroll
    for (int j = 0; j < 8; ++j) hv[j] = Hl[(q + 16*j)*33 + n];
    #pragma unroll
    for (int i = 0; i < 4; ++i)
      #pragma unroll
      for (int j = 0; j < 8; ++j) acc[i][j] += cv[i] * hv[j];
  }
  float yg[4][8];
  #pragma unroll
  for (int i = 0; i < 4; ++i){
    const long tok = tb + t0 + i;
    #pragma unroll
    for (int j = 0; j < 8; ++j){
      const int hp = q + 16*j;
      const int h = hp >> 5;
      const float v = pcl[h*64 + t0 + i] * acc[i][j] + bf2f(g_xy[tok*128 + hp]);
      yg[i][j] = v * silu_f(bf2f(g_za[tok*128 + hp]));   // single silu (za holds raw z)
    }
  }
  const int dm0 = (tid & 15) * 4;
  const float* Wol = Wo + (long)l * 128 * 64;
  float a2[4][4];
  #pragma unroll
  for (int i = 0; i < 4; ++i)
    #pragma unroll
    for (int j = 0; j < 4; ++j) a2[i][j] = 0.f;
  #pragma unroll
  for (int half = 0; half < 2; ++half){
    __syncthreads();
    #pragma unroll
    for (int i = 0; i < 4; ++i)
      #pragma unroll
      for (int j = 0; j < 4; ++j){
        const int hp = q + 16*(j + 4*half);
        gl[(t0+i)*68 + (hp - 64*half)] = yg[i][j + 4*half];
      }
    __syncthreads();
    for (int kk = 0; kk < 64; ++kk){
      float4 w4 = *(const float4*)&Wol[(kk + 64*half)*64 + dm0];
      float wv[4] = {w4.x, w4.y, w4.z, w4.w};
      #pragma unroll
      for (int ii = 0; ii < 4; ++ii){
        const float gv = gl[(t0+ii)*68 + kk];
        #pragma unroll
        for (int j = 0; j < 4; ++j) a2[ii][j] += gv * wv[j];
      }
    }
  }
  float4 b4 = *(const float4*)&bo[l*64 + dm0];
  float bv[4] = {b4.x, b4.y, b4.z, b4.w};
  float colsum[4] = {0.f, 0.f, 0.f, 0.f};
  #pragma unroll
  for (int ii = 0; ii < 4; ++ii){
    const long tok = tb + t0 + ii;
    float4 h4 = *(const float4*)&g_h0[tok*64 + dm0];
    float hv[4] = {h4.x, h4.y, h4.z, h4.w};
    float4 o;
    o.x = a2[ii][0] + bv[0] + hv[0];
    o.y = a2[ii][1] + bv[1] + hv[1];
    o.z = a2[ii][2] + bv[2] + hv[2];
    o.w = a2[ii][3] + bv[3] + hv[3];
    colsum[0] += o.x; colsum[1] += o.y; colsum[2] += o.z; colsum[3] += o.w;
    *(float4*)&g_h0[tok*64 + dm0] = o;
  }
  if (finalLayer){
    float* csum = Cl;                  // [16][68] alias, Cl dead by now
    const int tg = tid >> 4;
    #pragma unroll
    for (int j = 0; j < 4; ++j) csum[tg*68 + dm0 + j] = colsum[j];
    __syncthreads();
    if (tid < 64){
      float s = 0.f;
      for (int r = 0; r < 16; ++r) s += csum[r*68 + tid];
      g_ppc[((long)b*NCH + cI)*64 + tid] = s;
    }
  }
}

// ---------------- pooling + classifier ----------------
__global__ __launch_bounds__(64) void k_pool2(
    const float* __restrict__ cW, const float* __restrict__ cb,
    float* __restrict__ out)
{
  __shared__ float pl[64];
  const int b = blockIdx.x, tid = threadIdx.x;
  float s = 0.f;
  for (int c = 0; c < NCH; ++c) s += g_ppc[((long)b*NCH + c)*64 + tid];
  pl[tid] = s * (1.0f / 8192.0f);
  __syncthreads();
  if (tid < NOUTC){
    float acc = cb[tid];
    for (int dm = 0; dm < 64; ++dm) acc += pl[dm] * cW[dm*NOUTC + tid];
    out[b*NOUTC + tid] = acc;
  }
}

extern "C" void kernel_launch(void* const* d_in, const int* in_sizes, int n_in,
                              void* d_out, int out_size, void* d_ws, size_t ws_size,
                              hipStream_t stream)
{
  const float* x      = (const float*)d_in[0];
  const float* W_in   = (const float*)d_in[1];
  const float* b_in   = (const float*)d_in[2];
  const float* ipW    = (const float*)d_in[3];
  const float* ipb    = (const float*)d_in[4];
  const float* A_log  = (const float*)d_in[5];
  const float* Dp     = (const float*)d_in[6];
  const float* dtb    = (const float*)d_in[7];
  const float* opW    = (const float*)d_in[8];
  const float* opb    = (const float*)d_in[9];
  const float* clsW   = (const float*)d_in[10];
  const float* clsb   = (const float*)d_in[11];
  float* out = (float*)d_out;
  (void)d_ws; (void)ws_size;

  k_linin<<<2048, 256, 0, stream>>>(x, W_in, b_in);
  for (int l = 0; l < NLAY; ++l){
    k_proj<<<1024, 256, 0, stream>>>(ipW, ipb, dtb, l);
    k_s1<<<dim3(NCH, BSZ), 256, 0, stream>>>(A_log, Dp, l);
    k_s2<<<dim3(32, BSZ), 128, 0, stream>>>();
    k_s3<<<dim3(NCH, BSZ), 256, 0, stream>>>(opW, opb, l, (l == NLAY-1) ? 1 : 0);
  }
  k_pool2<<<BSZ, 64, 0, stream>>>(clsW, clsb, out);
}

// Round 8
// 623.715 us; speedup vs baseline: 9.2063x; 1.1826x over previous
//
#include <hip/hip_runtime.h>

#define BSZ   16
#define LSEQ  8192
#define DMDL  64
#define DSD   32
#define HDD   32
#define NHD   4
#define DIN   128
#define NLAY  2
#define NOUTC 6
#define DPRJ  324
#define QC    64
#define NCH   128   // LSEQ/QC
#define NT21  21    // 21 column tiles of 16 (320 proj cols + 4 dt cols zero-padded)

typedef __attribute__((ext_vector_type(8))) short bf16x8;
typedef __attribute__((ext_vector_type(4))) float f32x4;

// ---- device-global scratch ----
__device__ float          g_h0[BSZ*LSEQ*DMDL];
__device__ unsigned short g_za[BSZ*LSEQ*DIN];   // RAW z, bf16 (silu applied once, in k_s3)
__device__ unsigned short g_xy[BSZ*LSEQ*DIN];   // silu(x), overwritten by y_intra (bf16)
__device__ float          g_Ba[BSZ*LSEQ*DSD];
__device__ float          g_Ca[BSZ*LSEQ*DSD];
__device__ float          g_dt[BSZ*LSEQ*NHD];
__device__ float          g_pc[BSZ*LSEQ*NHD];
__device__ float          g_cS[BSZ*NCH*NHD*HDD*DSD]; // chunk states, scanned in-place -> H_in
__device__ float          g_cL[BSZ*NCH*NHD];
__device__ float          g_ppc[BSZ*NCH*DMDL];       // per-chunk column sums (final layer)
__device__ unsigned short g_wf[NLAY*NT21*2*64*8];    // in_proj W in bf16 MFMA B-fragment layout

__device__ __forceinline__ float silu_f(float v){ return v / (1.0f + __expf(-v)); }
__device__ __forceinline__ float softplus_f(float v){ return (v > 15.0f) ? v : __logf(1.0f + __expf(v)); }
__device__ __forceinline__ unsigned short f2bf(float f){
  union { float f; unsigned u; } v; v.f = f;
  unsigned r = v.u + 0x7FFFu + ((v.u >> 16) & 1u);
  return (unsigned short)(r >> 16);
}
__device__ __forceinline__ float bf2f(unsigned short h){
  union { unsigned u; float f; } v; v.u = ((unsigned)h) << 16;
  return v.f;
}

// ---------------- linear_in ----------------
__global__ __launch_bounds__(256) void k_linin(
    const float* __restrict__ x, const float* __restrict__ W,
    const float* __restrict__ bias)
{
  __shared__ float xs[64*60];
  __shared__ float wl[57*64];
  const int tid = threadIdx.x;
  const long tb = (long)blockIdx.x * 64;
  for (int i = tid; i < 64*57; i += 256){
    int t = i / 57, k = i - t*57;
    xs[t*60 + k] = x[tb*57 + i];
  }
  for (int i = tid; i < 57*64; i += 256) wl[i] = W[i];
  __syncthreads();
  const int t0 = (tid >> 4) * 4, d0 = (tid & 15) * 4;
  float acc[4][4];
  #pragma unroll
  for (int i = 0; i < 4; ++i)
    #pragma unroll
    for (int j = 0; j < 4; ++j) acc[i][j] = 0.f;
  for (int k = 0; k < 57; ++k){
    float4 w4 = *(const float4*)&wl[k*64 + d0];
    float wv[4] = {w4.x, w4.y, w4.z, w4.w};
    #pragma unroll
    for (int i = 0; i < 4; ++i){
      float xv = xs[(t0+i)*60 + k];
      #pragma unroll
      for (int j = 0; j < 4; ++j) acc[i][j] += xv * wv[j];
    }
  }
  float4 b4 = *(const float4*)&bias[d0];
  float bv[4] = {b4.x, b4.y, b4.z, b4.w};
  #pragma unroll
  for (int i = 0; i < 4; ++i){
    float4 o;
    o.x = acc[i][0] + bv[0]; o.y = acc[i][1] + bv[1];
    o.z = acc[i][2] + bv[2]; o.w = acc[i][3] + bv[3];
    *(float4*)&g_h0[(tb + t0 + i)*64 + d0] = o;
  }
}

// ---------------- weight prep: ipW -> bf16 B-fragment layout ----------------
// Fragment mapping (mfma_f32_16x16x32_bf16, m89-verified):
//   B-frag lane l, elem j  <->  B[k = (l>>4)*8 + j + 32*kstep][n = (l&15) + 16*ntile]
__global__ __launch_bounds__(128) void k_wprep(const float* __restrict__ W)
{
  const int nt = blockIdx.x;            // 0..20
  const int l  = blockIdx.y;            // layer
  const int ks = threadIdx.x >> 6, lane = threadIdx.x & 63;
  const float* Wl = W + (long)l*64*DPRJ;
  const int n  = nt*16 + (lane & 15);
  const int k0 = ks*32 + (lane >> 4)*8;
  unsigned short v[8];
  #pragma unroll
  for (int j = 0; j < 8; ++j)
    v[j] = (n < DPRJ) ? f2bf(Wl[(k0 + j)*DPRJ + n]) : (unsigned short)0;
  unsigned short* d = &g_wf[((((long)l*NT21 + nt)*2 + ks)*64 + lane)*8];
  *(ushort4*)&d[0] = make_ushort4(v[0], v[1], v[2], v[3]);
  *(ushort4*)&d[4] = make_ushort4(v[4], v[5], v[6], v[7]);
}

// ---------------- in_proj via MFMA (128 tokens/block) ----------------
__global__ __launch_bounds__(256) void k_proj(
    const float* __restrict__ bias, const float* __restrict__ dt_bias, int l)
{
  __shared__ __align__(16) unsigned short Afr[8*2*64*8];  // [mtile][kstep][lane][8] bf16, 16 KB
  const int tid = threadIdx.x;
  const long tb = (long)blockIdx.x * 128;
  // stage A: h0 fp32 -> bf16 fragments
  #pragma unroll
  for (int r = 0; r < 4; ++r){
    const int c = tid + 256*r;            // 0..1023 = (t 0..127, k8 0..7)
    const int t = c >> 3, k8 = c & 7;
    float4 f0 = *(const float4*)&g_h0[(tb + t)*64 + k8*8];
    float4 f1 = *(const float4*)&g_h0[(tb + t)*64 + k8*8 + 4];
    const int mt = t >> 4, ks = k8 >> 2, q = k8 & 3, ln = (t & 15) + 16*q;
    unsigned short* d = &Afr[(((mt*2 + ks)*64) + ln)*8];
    *(ushort4*)&d[0] = make_ushort4(f2bf(f0.x), f2bf(f0.y), f2bf(f0.z), f2bf(f0.w));
    *(ushort4*)&d[4] = make_ushort4(f2bf(f1.x), f2bf(f1.y), f2bf(f1.z), f2bf(f1.w));
  }
  __syncthreads();
  const int w = tid >> 6, lane = tid & 63;
  const int colq = lane & 15, rowq = lane >> 4;
  bf16x8 a[2][2];
  #pragma unroll
  for (int m = 0; m < 2; ++m)
    #pragma unroll
    for (int ks = 0; ks < 2; ++ks)
      a[m][ks] = *(const bf16x8*)&Afr[((((2*w + m)*2 + ks)*64) + lane)*8];
  const float* bl = bias + (long)l*DPRJ;
  const unsigned short* wf = &g_wf[(long)l*NT21*2*64*8];
  for (int nt = 0; nt < NT21; ++nt){
    bf16x8 b0 = *(const bf16x8*)&wf[((nt*2 + 0)*64 + lane)*8];
    bf16x8 b1 = *(const bf16x8*)&wf[((nt*2 + 1)*64 + lane)*8];
    #pragma unroll
    for (int m = 0; m < 2; ++m){
      f32x4 acc = {0.f, 0.f, 0.f, 0.f};
      acc = __builtin_amdgcn_mfma_f32_16x16x32_bf16(a[m][0], b0, acc, 0, 0, 0);
      acc = __builtin_amdgcn_mfma_f32_16x16x32_bf16(a[m][1], b1, acc, 0, 0, 0);
      const int mt = 2*w + m;
      const int tbase = mt*16 + rowq*4;
      const int gcol = nt*16 + colq;
      if (nt < 8){                       // z raw -> bf16
        const float b = bl[gcol];
        #pragma unroll
        for (int r = 0; r < 4; ++r)
          g_za[(tb + tbase + r)*128 + gcol] = f2bf(acc[r] + b);
      } else if (nt < 16){               // silu(x) -> bf16
        const float b = bl[gcol];
        #pragma unroll
        for (int r = 0; r < 4; ++r)
          g_xy[(tb + tbase + r)*128 + (gcol - 128)] = f2bf(silu_f(acc[r] + b));
      } else if (nt < 18){               // silu(B) -> f32
        const float b = bl[gcol];
        #pragma unroll
        for (int r = 0; r < 4; ++r)
          g_Ba[(tb + tbase + r)*32 + (gcol - 256)] = silu_f(acc[r] + b);
      } else if (nt < 20){               // silu(C) -> f32
        const float b = bl[gcol];
        #pragma unroll
        for (int r = 0; r < 4; ++r)
          g_Ca[(tb + tbase + r)*32 + (gcol - 288)] = silu_f(acc[r] + b);
      } else {                           // dt (cols 320..323)
        if (colq < 4){
          const float b = bl[320 + colq] + dt_bias[l*4 + colq];
          #pragma unroll
          for (int r = 0; r < 4; ++r)
            g_dt[(tb + tbase + r)*4 + colq] = softplus_f(acc[r] + b);
        }
      }
    }
  }
}

// ---------------- chunk intra (no Ml materialization; block-factorized decay) ----------------
__global__ __launch_bounds__(256) void k_s1(
    const float* __restrict__ A_log, const float* __restrict__ Dp, int l)
{
  __shared__ float Bs[64*37];
  __shared__ float Cs[64*37];
  __shared__ float Gl[64*65];
  __shared__ float Xh[64*36];
  __shared__ float dtl[4*64];
  __shared__ float Sl[4*64];
  __shared__ float wl[4*64];
  __shared__ float carr[4*64];   // exp(R_b(s) - Sl[s]) * dt[s]
  __shared__ float earr[16*64];  // [h][beta][t]: exp(Sl[t]-R_beta), 0 if t<16*beta
  __shared__ float Send[4], Rb[16];
  const int tid = threadIdx.x;
  const int cI = blockIdx.x, b = blockIdx.y;
  const long tb = (long)b*LSEQ + (long)cI*QC;
  for (int i = tid; i < 2048; i += 256){
    int s = i >> 5, n = i & 31;
    Bs[s*37 + n] = g_Ba[(tb + s)*32 + n];
    Cs[s*37 + n] = g_Ca[(tb + s)*32 + n];
  }
  { int t = tid >> 2, h = tid & 3; dtl[h*64 + t] = g_dt[(tb + t)*4 + h]; }
  __syncthreads();
  if (tid < 4){
    const int h = tid;
    const float Ah = -__expf(A_log[l*4 + h]);
    float run = 0.f;
    for (int t = 0; t < 64; ++t){
      if ((t & 15) == 0) Rb[h*4 + (t>>4)] = run;
      run += dtl[h*64 + t] * Ah;
      Sl[h*64 + t] = run;
    }
    Send[h] = run;
    g_cL[((long)b*NCH + cI)*4 + h] = run;
  }
  __syncthreads();
  {
    const int h = tid >> 6, s = tid & 63;
    const float sl = Sl[h*64 + s];
    wl[h*64 + s]   = __expf(Send[h] - sl) * dtl[h*64 + s];
    carr[h*64 + s] = __expf(Rb[h*4 + (s>>4)] - sl) * dtl[h*64 + s];
  }
  { int t = tid >> 2, h = tid & 3; g_pc[(tb + t)*4 + h] = __expf(Sl[h*64 + t]); }
  for (int i = tid; i < 1024; i += 256){
    const int h = i >> 8, bb = (i >> 6) & 3, t = i & 63;
    earr[i] = (t >= bb*16) ? __expf(Sl[h*64 + t] - Rb[h*4 + bb]) : 0.f;
  }
  __syncthreads();
  const int t0 = (tid >> 4) * 4, s0 = (tid & 15) * 4;
  if (s0 <= t0 + 3){
    float acc[4][4];
    #pragma unroll
    for (int i = 0; i < 4; ++i)
      #pragma unroll
      for (int j = 0; j < 4; ++j) acc[i][j] = 0.f;
    for (int n = 0; n < 32; ++n){
      float bva[4], cva[4];
      #pragma unroll
      for (int j = 0; j < 4; ++j) bva[j] = Bs[(s0+j)*37 + n];
      #pragma unroll
      for (int i = 0; i < 4; ++i) cva[i] = Cs[(t0+i)*37 + n];
      #pragma unroll
      for (int i = 0; i < 4; ++i)
        #pragma unroll
        for (int j = 0; j < 4; ++j) acc[i][j] += cva[i] * bva[j];
    }
    #pragma unroll
    for (int i = 0; i < 4; ++i)
      #pragma unroll
      for (int j = 0; j < 4; ++j) Gl[(t0+i)*65 + s0 + j] = acc[i][j];
  }
  const int tt0 = (tid >> 3) * 2;
  const int p0g = (tid & 7) * 4;
  const int tblk = tt0 >> 4;
  for (int h = 0; h < NHD; ++h){
    __syncthreads();
    for (int i = tid; i < 512; i += 256){
      int s = i >> 3, p4 = (i & 7) * 4;
      ushort4 u = *(const ushort4*)&g_xy[(tb + s)*128 + h*32 + p4];
      float4 f; f.x = bf2f(u.x); f.y = bf2f(u.y); f.z = bf2f(u.z); f.w = bf2f(u.w);
      *(float4*)&Xh[s*36 + p4] = f;
    }
    __syncthreads();
    const float Dh = Dp[l*4 + h];
    {
      float a0[4] = {0,0,0,0}, a1[4] = {0,0,0,0};
      for (int bb = 0; bb <= tblk; ++bb){
        const float e0 = earr[(h*4 + bb)*64 + tt0];
        const float e1 = earr[(h*4 + bb)*64 + tt0 + 1];
        const int sbase = bb * 16;
        if (bb < tblk){
          #pragma unroll
          for (int ss = 0; ss < 16; ++ss){
            const int s = sbase + ss;
            const float c = carr[h*64 + s];
            const float m0 = e0 * c * Gl[tt0*65 + s];
            const float m1 = e1 * c * Gl[(tt0+1)*65 + s];
            float4 x4 = *(const float4*)&Xh[s*36 + p0g];
            float xv[4] = {x4.x, x4.y, x4.z, x4.w};
            #pragma unroll
            for (int j = 0; j < 4; ++j){ a0[j] += m0 * xv[j]; a1[j] += m1 * xv[j]; }
          }
        } else {
          #pragma unroll
          for (int ss = 0; ss < 16; ++ss){
            const int s = sbase + ss;
            const float c = carr[h*64 + s];
            const float m0 = (s <= tt0    ) ? e0 * c * Gl[tt0*65 + s]     : 0.f;
            const float m1 = (s <= tt0 + 1) ? e1 * c * Gl[(tt0+1)*65 + s] : 0.f;
            float4 x4 = *(const float4*)&Xh[s*36 + p0g];
            float xv[4] = {x4.x, x4.y, x4.z, x4.w};
            #pragma unroll
            for (int j = 0; j < 4; ++j){ a0[j] += m0 * xv[j]; a1[j] += m1 * xv[j]; }
          }
        }
      }
      float4 xt0 = *(const float4*)&Xh[tt0*36 + p0g];
      float4 xt1 = *(const float4*)&Xh[(tt0+1)*36 + p0g];
      ushort4 o0, o1;
      o0.x = f2bf(a0[0] + Dh*xt0.x); o0.y = f2bf(a0[1] + Dh*xt0.y);
      o0.z = f2bf(a0[2] + Dh*xt0.z); o0.w = f2bf(a0[3] + Dh*xt0.w);
      o1.x = f2bf(a1[0] + Dh*xt1.x); o1.y = f2bf(a1[1] + Dh*xt1.y);
      o1.z = f2bf(a1[2] + Dh*xt1.z); o1.w = f2bf(a1[3] + Dh*xt1.w);
      *(ushort4*)&g_xy[(tb + tt0    )*128 + h*32 + p0g] = o0;
      *(ushort4*)&g_xy[(tb + tt0 + 1)*128 + h*32 + p0g] = o1;
    }
    {
      const int pp = tid >> 3;
      const int n0 = (tid & 7) * 4;
      float accs[4] = {0,0,0,0};
      for (int s = 0; s < 64; ++s){
        const float wx = wl[h*64 + s] * Xh[s*36 + pp];
        #pragma unroll
        for (int j = 0; j < 4; ++j) accs[j] += wx * Bs[s*37 + n0 + j];
      }
      float4 o; o.x = accs[0]; o.y = accs[1]; o.z = accs[2]; o.w = accs[3];
      *(float4*)&g_cS[(((long)b*NCH + cI)*NHD + h)*(HDD*DSD) + pp*32 + n0] = o;
    }
  }
}

// ---------------- cross-chunk state prefix scan (in place) ----------------
__global__ __launch_bounds__(128) void k_s2()
{
  const int h = blockIdx.x >> 3, seg = blockIdx.x & 7, b = blockIdx.y;
  const int idx = seg*128 + threadIdx.x;
  float H = 0.f;
  for (int c = 0; c < NCH; ++c){
    const long o = (((long)b*NCH + c)*NHD + h)*1024 + idx;
    const float cs = g_cS[o];
    const float lg = g_cL[((long)b*NCH + c)*4 + h];
    g_cS[o] = H;
    H = __expf(lg) * H + cs;
  }
}

// ---------------- y_inter + gate + out_proj + residual (+ pool on final layer) ----------------
__global__ __launch_bounds__(256) void k_s3(
    const float* __restrict__ Wo, const float* __restrict__ bo, int l, int finalLayer)
{
  __shared__ float Hl[128*33];
  __shared__ float Cl[64*36];   // aliased as csum[16][68] in the pool epilogue
  __shared__ float pcl[4*64];
  __shared__ float gl[64*68];
  const int tid = threadIdx.x;
  const int cI = blockIdx.x, b = blockIdx.y;
  const long tb = (long)b*LSEQ + (long)cI*QC;
  const long hb = (((long)b*NCH + cI)*NHD)*(long)(HDD*DSD);
  for (int i = tid; i < 4096; i += 256) Hl[(i>>5)*33 + (i&31)] = g_cS[hb + i];
  for (int i = tid; i < 2048; i += 256){
    int t = i >> 5, n = i & 31;
    Cl[t*36 + n] = g_Ca[(tb + t)*32 + n];
  }
  { int t = tid >> 2, h = tid & 3; pcl[h*64 + t] = g_pc[(tb + t)*4 + h]; }
  __syncthreads();
  const int t0 = (tid >> 4) * 4;
  const int q = tid & 15;
  float acc[4][8];
  #pragma unroll
  for (int i = 0; i < 4; ++i)
    #pragma unroll
    for (int j = 0; j < 8; ++j) acc[i][j] = 0.f;
  for (int n = 0; n < 32; ++n){
    float cv[4], hv[8];
    #pragma unroll
    for (int i = 0; i < 4; ++i) cv[i] = Cl[(t0+i)*36 + n];
    #pragma unroll
    for (int j = 0; j < 8; ++j) hv[j] = Hl[(q + 16*j)*33 + n];
    #pragma unroll
    for (int i = 0; i < 4; ++i)
      #pragma unroll
      for (int j = 0; j < 8; ++j) acc[i][j] += cv[i] * hv[j];
  }
  float yg[4][8];
  #pragma unroll
  for (int i = 0; i < 4; ++i){
    const long tok = tb + t0 + i;
    #pragma unroll
    for (int j = 0; j < 8; ++j){
      const int hp = q + 16*j;
      const int h = hp >> 5;
      const float v = pcl[h*64 + t0 + i] * acc[i][j] + bf2f(g_xy[tok*128 + hp]);
      yg[i][j] = v * silu_f(bf2f(g_za[tok*128 + hp]));   // single silu (za holds raw z)
    }
  }
  const int dm0 = (tid & 15) * 4;
  const float* Wol = Wo + (long)l * 128 * 64;
  float a2[4][4];
  #pragma unroll
  for (int i = 0; i < 4; ++i)
    #pragma unroll
    for (int j = 0; j < 4; ++j) a2[i][j] = 0.f;
  #pragma unroll
  for (int half = 0; half < 2; ++half){
    __syncthreads();
    #pragma unroll
    for (int i = 0; i < 4; ++i)
      #pragma unroll
      for (int j = 0; j < 4; ++j){
        const int hp = q + 16*(j + 4*half);
        gl[(t0+i)*68 + (hp - 64*half)] = yg[i][j + 4*half];
      }
    __syncthreads();
    for (int kk = 0; kk < 64; ++kk){
      float4 w4 = *(const float4*)&Wol[(kk + 64*half)*64 + dm0];
      float wv[4] = {w4.x, w4.y, w4.z, w4.w};
      #pragma unroll
      for (int ii = 0; ii < 4; ++ii){
        const float gv = gl[(t0+ii)*68 + kk];
        #pragma unroll
        for (int j = 0; j < 4; ++j) a2[ii][j] += gv * wv[j];
      }
    }
  }
  float4 b4 = *(const float4*)&bo[l*64 + dm0];
  float bv[4] = {b4.x, b4.y, b4.z, b4.w};
  float colsum[4] = {0.f, 0.f, 0.f, 0.f};
  #pragma unroll
  for (int ii = 0; ii < 4; ++ii){
    const long tok = tb + t0 + ii;
    float4 h4 = *(const float4*)&g_h0[tok*64 + dm0];
    float hv[4] = {h4.x, h4.y, h4.z, h4.w};
    float4 o;
    o.x = a2[ii][0] + bv[0] + hv[0];
    o.y = a2[ii][1] + bv[1] + hv[1];
    o.z = a2[ii][2] + bv[2] + hv[2];
    o.w = a2[ii][3] + bv[3] + hv[3];
    colsum[0] += o.x; colsum[1] += o.y; colsum[2] += o.z; colsum[3] += o.w;
    *(float4*)&g_h0[tok*64 + dm0] = o;
  }
  if (finalLayer){
    float* csum = Cl;                  // [16][68] alias, Cl dead by now
    const int tg = tid >> 4;
    #pragma unroll
    for (int j = 0; j < 4; ++j) csum[tg*68 + dm0 + j] = colsum[j];
    __syncthreads();
    if (tid < 64){
      float s = 0.f;
      for (int r = 0; r < 16; ++r) s += csum[r*68 + tid];
      g_ppc[((long)b*NCH + cI)*64 + tid] = s;
    }
  }
}

// ---------------- pooling + classifier ----------------
__global__ __launch_bounds__(64) void k_pool2(
    const float* __restrict__ cW, const float* __restrict__ cb,
    float* __restrict__ out)
{
  __shared__ float pl[64];
  const int b = blockIdx.x, tid = threadIdx.x;
  float s = 0.f;
  for (int c = 0; c < NCH; ++c) s += g_ppc[((long)b*NCH + c)*64 + tid];
  pl[tid] = s * (1.0f / 8192.0f);
  __syncthreads();
  if (tid < NOUTC){
    float acc = cb[tid];
    for (int dm = 0; dm < 64; ++dm) acc += pl[dm] * cW[dm*NOUTC + tid];
    out[b*NOUTC + tid] = acc;
  }
}

extern "C" void kernel_launch(void* const* d_in, const int* in_sizes, int n_in,
                              void* d_out, int out_size, void* d_ws, size_t ws_size,
                              hipStream_t stream)
{
  const float* x      = (const float*)d_in[0];
  const float* W_in   = (const float*)d_in[1];
  const float* b_in   = (const float*)d_in[2];
  const float* ipW    = (const float*)d_in[3];
  const float* ipb    = (const float*)d_in[4];
  const float* A_log  = (const float*)d_in[5];
  const float* Dp     = (const float*)d_in[6];
  const float* dtb    = (const float*)d_in[7];
  const float* opW    = (const float*)d_in[8];
  const float* opb    = (const float*)d_in[9];
  const float* clsW   = (const float*)d_in[10];
  const float* clsb   = (const float*)d_in[11];
  float* out = (float*)d_out;
  (void)d_ws; (void)ws_size;

  k_wprep<<<dim3(NT21, NLAY), 128, 0, stream>>>(ipW);
  k_linin<<<2048, 256, 0, stream>>>(x, W_in, b_in);
  for (int l = 0; l < NLAY; ++l){
    k_proj<<<1024, 256, 0, stream>>>(ipb, dtb, l);
    k_s1<<<dim3(NCH, BSZ), 256, 0, stream>>>(A_log, Dp, l);
    k_s2<<<dim3(32, BSZ), 128, 0, stream>>>();
    k_s3<<<dim3(NCH, BSZ), 256, 0, stream>>>(opW, opb, l, (l == NLAY-1) ? 1 : 0);
  }
  k_pool2<<<BSZ, 64, 0, stream>>>(clsW, clsb, out);
}

// Round 9
// 620.089 us; speedup vs baseline: 9.2602x; 1.0058x over previous
//
#include <hip/hip_runtime.h>

#define BSZ   16
#define LSEQ  8192
#define DMDL  64
#define DSD   32
#define HDD   32
#define NHD   4
#define DIN   128
#define NLAY  2
#define NOUTC 6
#define DPRJ  324
#define QC    64
#define NCH   128   // LSEQ/QC
#define NT21  21    // 21 column tiles of 16 (320 proj cols + 4 dt cols zero-padded)

typedef __attribute__((ext_vector_type(8))) short bf16x8;
typedef __attribute__((ext_vector_type(4))) float f32x4;

// ---- device-global scratch ----
__device__ float          g_h0[BSZ*LSEQ*DMDL];
__device__ unsigned short g_za[BSZ*LSEQ*DIN];   // RAW z, bf16 (silu applied once, in k_s3)
__device__ unsigned short g_xy[BSZ*LSEQ*DIN];   // silu(x), overwritten by y_intra (bf16)
__device__ float          g_Ba[BSZ*LSEQ*DSD];
__device__ float          g_Ca[BSZ*LSEQ*DSD];
__device__ float          g_dt[BSZ*LSEQ*NHD];
__device__ float          g_pc[BSZ*LSEQ*NHD];
__device__ float          g_cS[BSZ*NCH*NHD*HDD*DSD]; // chunk states, scanned in-place -> H_in
__device__ float          g_cL[BSZ*NCH*NHD];
__device__ float          g_ppc[BSZ*NCH*DMDL];       // per-chunk column sums (final layer)
__device__ unsigned short g_wf[NLAY*NT21*2*64*8];    // in_proj W in bf16 MFMA B-fragment layout

__device__ __forceinline__ float silu_f(float v){ return v / (1.0f + __expf(-v)); }
__device__ __forceinline__ float softplus_f(float v){ return (v > 15.0f) ? v : __logf(1.0f + __expf(v)); }
__device__ __forceinline__ unsigned short f2bf(float f){
  union { float f; unsigned u; } v; v.f = f;
  unsigned r = v.u + 0x7FFFu + ((v.u >> 16) & 1u);
  return (unsigned short)(r >> 16);
}
__device__ __forceinline__ float bf2f(unsigned short h){
  union { unsigned u; float f; } v; v.u = ((unsigned)h) << 16;
  return v.f;
}

// ---------------- linear_in ----------------
__global__ __launch_bounds__(256) void k_linin(
    const float* __restrict__ x, const float* __restrict__ W,
    const float* __restrict__ bias)
{
  __shared__ float xs[64*60];
  __shared__ float wl[57*64];
  const int tid = threadIdx.x;
  const long tb = (long)blockIdx.x * 64;
  for (int i = tid; i < 64*57; i += 256){
    int t = i / 57, k = i - t*57;
    xs[t*60 + k] = x[tb*57 + i];
  }
  for (int i = tid; i < 57*64; i += 256) wl[i] = W[i];
  __syncthreads();
  const int t0 = (tid >> 4) * 4, d0 = (tid & 15) * 4;
  float acc[4][4];
  #pragma unroll
  for (int i = 0; i < 4; ++i)
    #pragma unroll
    for (int j = 0; j < 4; ++j) acc[i][j] = 0.f;
  for (int k = 0; k < 57; ++k){
    float4 w4 = *(const float4*)&wl[k*64 + d0];
    float wv[4] = {w4.x, w4.y, w4.z, w4.w};
    #pragma unroll
    for (int i = 0; i < 4; ++i){
      float xv = xs[(t0+i)*60 + k];
      #pragma unroll
      for (int j = 0; j < 4; ++j) acc[i][j] += xv * wv[j];
    }
  }
  float4 b4 = *(const float4*)&bias[d0];
  float bv[4] = {b4.x, b4.y, b4.z, b4.w};
  #pragma unroll
  for (int i = 0; i < 4; ++i){
    float4 o;
    o.x = acc[i][0] + bv[0]; o.y = acc[i][1] + bv[1];
    o.z = acc[i][2] + bv[2]; o.w = acc[i][3] + bv[3];
    *(float4*)&g_h0[(tb + t0 + i)*64 + d0] = o;
  }
}

// ---------------- weight prep: ipW -> bf16 B-fragment layout ----------------
__global__ __launch_bounds__(128) void k_wprep(const float* __restrict__ W)
{
  const int nt = blockIdx.x;            // 0..20
  const int l  = blockIdx.y;            // layer
  const int ks = threadIdx.x >> 6, lane = threadIdx.x & 63;
  const float* Wl = W + (long)l*64*DPRJ;
  const int n  = nt*16 + (lane & 15);
  const int k0 = ks*32 + (lane >> 4)*8;
  unsigned short v[8];
  #pragma unroll
  for (int j = 0; j < 8; ++j)
    v[j] = (n < DPRJ) ? f2bf(Wl[(k0 + j)*DPRJ + n]) : (unsigned short)0;
  unsigned short* d = &g_wf[((((long)l*NT21 + nt)*2 + ks)*64 + lane)*8];
  *(ushort4*)&d[0] = make_ushort4(v[0], v[1], v[2], v[3]);
  *(ushort4*)&d[4] = make_ushort4(v[4], v[5], v[6], v[7]);
}

// ---------------- in_proj via MFMA (128 tokens/block) ----------------
__global__ __launch_bounds__(256) void k_proj(
    const float* __restrict__ bias, const float* __restrict__ dt_bias, int l)
{
  __shared__ __align__(16) unsigned short Afr[8*2*64*8];  // [mtile][kstep][lane][8] bf16, 16 KB
  const int tid = threadIdx.x;
  const long tb = (long)blockIdx.x * 128;
  #pragma unroll
  for (int r = 0; r < 4; ++r){
    const int c = tid + 256*r;
    const int t = c >> 3, k8 = c & 7;
    float4 f0 = *(const float4*)&g_h0[(tb + t)*64 + k8*8];
    float4 f1 = *(const float4*)&g_h0[(tb + t)*64 + k8*8 + 4];
    const int mt = t >> 4, ks = k8 >> 2, q = k8 & 3, ln = (t & 15) + 16*q;
    unsigned short* d = &Afr[(((mt*2 + ks)*64) + ln)*8];
    *(ushort4*)&d[0] = make_ushort4(f2bf(f0.x), f2bf(f0.y), f2bf(f0.z), f2bf(f0.w));
    *(ushort4*)&d[4] = make_ushort4(f2bf(f1.x), f2bf(f1.y), f2bf(f1.z), f2bf(f1.w));
  }
  __syncthreads();
  const int w = tid >> 6, lane = tid & 63;
  const int colq = lane & 15, rowq = lane >> 4;
  bf16x8 a[2][2];
  #pragma unroll
  for (int m = 0; m < 2; ++m)
    #pragma unroll
    for (int ks = 0; ks < 2; ++ks)
      a[m][ks] = *(const bf16x8*)&Afr[((((2*w + m)*2 + ks)*64) + lane)*8];
  const float* bl = bias + (long)l*DPRJ;
  const unsigned short* wf = &g_wf[(long)l*NT21*2*64*8];
  for (int nt = 0; nt < NT21; ++nt){
    bf16x8 b0 = *(const bf16x8*)&wf[((nt*2 + 0)*64 + lane)*8];
    bf16x8 b1 = *(const bf16x8*)&wf[((nt*2 + 1)*64 + lane)*8];
    #pragma unroll
    for (int m = 0; m < 2; ++m){
      f32x4 acc = {0.f, 0.f, 0.f, 0.f};
      acc = __builtin_amdgcn_mfma_f32_16x16x32_bf16(a[m][0], b0, acc, 0, 0, 0);
      acc = __builtin_amdgcn_mfma_f32_16x16x32_bf16(a[m][1], b1, acc, 0, 0, 0);
      const int mt = 2*w + m;
      const int tbase = mt*16 + rowq*4;
      const int gcol = nt*16 + colq;
      if (nt < 8){
        const float b = bl[gcol];
        #pragma unroll
        for (int r = 0; r < 4; ++r)
          g_za[(tb + tbase + r)*128 + gcol] = f2bf(acc[r] + b);
      } else if (nt < 16){
        const float b = bl[gcol];
        #pragma unroll
        for (int r = 0; r < 4; ++r)
          g_xy[(tb + tbase + r)*128 + (gcol - 128)] = f2bf(silu_f(acc[r] + b));
      } else if (nt < 18){
        const float b = bl[gcol];
        #pragma unroll
        for (int r = 0; r < 4; ++r)
          g_Ba[(tb + tbase + r)*32 + (gcol - 256)] = silu_f(acc[r] + b);
      } else if (nt < 20){
        const float b = bl[gcol];
        #pragma unroll
        for (int r = 0; r < 4; ++r)
          g_Ca[(tb + tbase + r)*32 + (gcol - 288)] = silu_f(acc[r] + b);
      } else {
        if (colq < 4){
          const float b = bl[320 + colq] + dt_bias[l*4 + colq];
          #pragma unroll
          for (int r = 0; r < 4; ++r)
            g_dt[(tb + tbase + r)*4 + colq] = softplus_f(acc[r] + b);
        }
      }
    }
  }
}

// ---------------- chunk intra: wave-parallel scan + on-the-fly decay exps ----------------
__global__ __launch_bounds__(256) void k_s1(
    const float* __restrict__ A_log, const float* __restrict__ Dp, int l)
{
  __shared__ __align__(16) float Bs[64*37];
  __shared__ __align__(16) float Cs[64*37];   // dead after G GEMM; aliased as Xh[64*36]
  __shared__ float Gl[64*65];
  __shared__ float Sl[4*64];
  __shared__ float wl[4*64];
  __shared__ float carr[4*64];   // exp(R_b(s) - Sl[s]) * dt[s]
  __shared__ float Rb[16];
  const int tid = threadIdx.x;
  const int cI = blockIdx.x, b = blockIdx.y;
  const long tb = (long)b*LSEQ + (long)cI*QC;
  for (int i = tid; i < 2048; i += 256){
    int s = i >> 5, n = i & 31;
    Bs[s*37 + n] = g_Ba[(tb + s)*32 + n];
    Cs[s*37 + n] = g_Ca[(tb + s)*32 + n];
  }
  // ---- wave-parallel scan: wave = head, lane = token ----
  {
    const int h = tid >> 6, t = tid & 63;
    const float Ah = -__expf(A_log[l*4 + h]);
    const float v = g_dt[(tb + t)*4 + h];
    float x = v * Ah;
    #pragma unroll
    for (int d = 1; d < 64; d <<= 1){
      float y = __shfl_up(x, d);
      if (t >= d) x += y;
    }
    Sl[h*64 + t] = x;
    const float send = __shfl(x, 63);
    wl[h*64 + t] = __expf(send - x) * v;
    int srcl = (t & 0x30) - 1; if (srcl < 0) srcl = 0;
    float rb = __shfl(x, srcl);
    if (t < 16) rb = 0.f;
    carr[h*64 + t] = __expf(rb - x) * v;
    if ((t & 15) == 15 && t < 63) Rb[h*4 + ((t+1) >> 4)] = x;
    if (t == 0) Rb[h*4] = 0.f;
    if (t == 63) g_cL[((long)b*NCH + cI)*4 + h] = x;
    g_pc[(tb + t)*4 + h] = __expf(x);
  }
  __syncthreads();
  // ---- G[t][s] = B_s . C_t (lower-triangle tiles) ----
  const int t0 = (tid >> 4) * 4, s0 = (tid & 15) * 4;
  if (s0 <= t0 + 3){
    float acc[4][4];
    #pragma unroll
    for (int i = 0; i < 4; ++i)
      #pragma unroll
      for (int j = 0; j < 4; ++j) acc[i][j] = 0.f;
    for (int n = 0; n < 32; ++n){
      float bva[4], cva[4];
      #pragma unroll
      for (int j = 0; j < 4; ++j) bva[j] = Bs[(s0+j)*37 + n];
      #pragma unroll
      for (int i = 0; i < 4; ++i) cva[i] = Cs[(t0+i)*37 + n];
      #pragma unroll
      for (int i = 0; i < 4; ++i)
        #pragma unroll
        for (int j = 0; j < 4; ++j) acc[i][j] += cva[i] * bva[j];
    }
    #pragma unroll
    for (int i = 0; i < 4; ++i)
      #pragma unroll
      for (int j = 0; j < 4; ++j) Gl[(t0+i)*65 + s0 + j] = acc[i][j];
  }
  float* Xh = Cs;   // alias: Cs dead after G (head-loop barrier orders the reuse)
  const int tt0 = (tid >> 3) * 2;
  const int p0g = (tid & 7) * 4;
  const int tblk = tt0 >> 4;
  for (int h = 0; h < NHD; ++h){
    __syncthreads();
    for (int i = tid; i < 512; i += 256){
      int s = i >> 3, p4 = (i & 7) * 4;
      ushort4 u = *(const ushort4*)&g_xy[(tb + s)*128 + h*32 + p4];
      float4 f; f.x = bf2f(u.x); f.y = bf2f(u.y); f.z = bf2f(u.z); f.w = bf2f(u.w);
      *(float4*)&Xh[s*36 + p4] = f;
    }
    __syncthreads();
    const float Dh = Dp[l*4 + h];
    {
      const float sl0 = Sl[h*64 + tt0];
      const float sl1 = Sl[h*64 + tt0 + 1];
      float a0[4] = {0,0,0,0}, a1[4] = {0,0,0,0};
      for (int bb = 0; bb <= tblk; ++bb){
        const float rbv = Rb[h*4 + bb];
        const float e0 = __expf(sl0 - rbv);
        const float e1 = __expf(sl1 - rbv);
        const int sbase = bb * 16;
        if (bb < tblk){
          #pragma unroll
          for (int ss = 0; ss < 16; ++ss){
            const int s = sbase + ss;
            const float c = carr[h*64 + s];
            const float m0 = e0 * c * Gl[tt0*65 + s];
            const float m1 = e1 * c * Gl[(tt0+1)*65 + s];
            float4 x4 = *(const float4*)&Xh[s*36 + p0g];
            float xv[4] = {x4.x, x4.y, x4.z, x4.w};
            #pragma unroll
            for (int j = 0; j < 4; ++j){ a0[j] += m0 * xv[j]; a1[j] += m1 * xv[j]; }
          }
        } else {
          #pragma unroll
          for (int ss = 0; ss < 16; ++ss){
            const int s = sbase + ss;
            const float c = carr[h*64 + s];
            const float m0 = (s <= tt0    ) ? e0 * c * Gl[tt0*65 + s]     : 0.f;
            const float m1 = (s <= tt0 + 1) ? e1 * c * Gl[(tt0+1)*65 + s] : 0.f;
            float4 x4 = *(const float4*)&Xh[s*36 + p0g];
            float xv[4] = {x4.x, x4.y, x4.z, x4.w};
            #pragma unroll
            for (int j = 0; j < 4; ++j){ a0[j] += m0 * xv[j]; a1[j] += m1 * xv[j]; }
          }
        }
      }
      float4 xt0 = *(const float4*)&Xh[tt0*36 + p0g];
      float4 xt1 = *(const float4*)&Xh[(tt0+1)*36 + p0g];
      ushort4 o0, o1;
      o0.x = f2bf(a0[0] + Dh*xt0.x); o0.y = f2bf(a0[1] + Dh*xt0.y);
      o0.z = f2bf(a0[2] + Dh*xt0.z); o0.w = f2bf(a0[3] + Dh*xt0.w);
      o1.x = f2bf(a1[0] + Dh*xt1.x); o1.y = f2bf(a1[1] + Dh*xt1.y);
      o1.z = f2bf(a1[2] + Dh*xt1.z); o1.w = f2bf(a1[3] + Dh*xt1.w);
      *(ushort4*)&g_xy[(tb + tt0    )*128 + h*32 + p0g] = o0;
      *(ushort4*)&g_xy[(tb + tt0 + 1)*128 + h*32 + p0g] = o1;
    }
    {
      const int pp = tid >> 3;
      const int n0 = (tid & 7) * 4;
      float accs[4] = {0,0,0,0};
      for (int s = 0; s < 64; ++s){
        const float wx = wl[h*64 + s] * Xh[s*36 + pp];
        #pragma unroll
        for (int j = 0; j < 4; ++j) accs[j] += wx * Bs[s*37 + n0 + j];
      }
      float4 o; o.x = accs[0]; o.y = accs[1]; o.z = accs[2]; o.w = accs[3];
      *(float4*)&g_cS[(((long)b*NCH + cI)*NHD + h)*(HDD*DSD) + pp*32 + n0] = o;
    }
  }
}

// ---------------- cross-chunk state prefix scan (in place) ----------------
__global__ __launch_bounds__(128) void k_s2()
{
  const int h = blockIdx.x >> 3, seg = blockIdx.x & 7, b = blockIdx.y;
  const int idx = seg*128 + threadIdx.x;
  float H = 0.f;
  for (int c = 0; c < NCH; ++c){
    const long o = (((long)b*NCH + c)*NHD + h)*1024 + idx;
    const float cs = g_cS[o];
    const float lg = g_cL[((long)b*NCH + c)*4 + h];
    g_cS[o] = H;
    H = __expf(lg) * H + cs;
  }
}

// ---------------- y_inter + gate + out_proj + residual (+ pool on final layer) ----------------
__global__ __launch_bounds__(256) void k_s3(
    const float* __restrict__ Wo, const float* __restrict__ bo, int l, int finalLayer)
{
  __shared__ float Hl[128*33];
  __shared__ float Cl[64*36];   // aliased as csum[16][68] in the pool epilogue
  __shared__ float pcl[4*64];
  __shared__ float gl[64*68];
  const int tid = threadIdx.x;
  const int cI = blockIdx.x, b = blockIdx.y;
  const long tb = (long)b*LSEQ + (long)cI*QC;
  const long hb = (((long)b*NCH + cI)*NHD)*(long)(HDD*DSD);
  for (int i = tid; i < 4096; i += 256) Hl[(i>>5)*33 + (i&31)] = g_cS[hb + i];
  for (int i = tid; i < 2048; i += 256){
    int t = i >> 5, n = i & 31;
    Cl[t*36 + n] = g_Ca[(tb + t)*32 + n];
  }
  { int t = tid >> 2, h = tid & 3; pcl[h*64 + t] = g_pc[(tb + t)*4 + h]; }
  __syncthreads();
  const int t0 = (tid >> 4) * 4;
  const int q = tid & 15;
  float acc[4][8];
  #pragma unroll
  for (int i = 0; i < 4; ++i)
    #pragma unroll
    for (int j = 0; j < 8; ++j) acc[i][j] = 0.f;
  for (int n = 0; n < 32; ++n){
    float cv[4], hv[8];
    #pragma unroll
    for (int i = 0; i < 4; ++i) cv[i] = Cl[(t0+i)*36 + n];
    #pragma unroll
    for (int j = 0; j < 8; ++j) hv[j] = Hl[(q + 16*j)*33 + n];
    #pragma unroll
    for (int i = 0; i < 4; ++i)
      #pragma unroll
      for (int j = 0; j < 8; ++j) acc[i][j] += cv[i] * hv[j];
  }
  float yg[4][8];
  #pragma unroll
  for (int i = 0; i < 4; ++i){
    const long tok = tb + t0 + i;
    #pragma unroll
    for (int j = 0; j < 8; ++j){
      const int hp = q + 16*j;
      const int h = hp >> 5;
      const float v = pcl[h*64 + t0 + i] * acc[i][j] + bf2f(g_xy[tok*128 + hp]);
      yg[i][j] = v * silu_f(bf2f(g_za[tok*128 + hp]));   // single silu (za holds raw z)
    }
  }
  const int dm0 = (tid & 15) * 4;
  const float* Wol = Wo + (long)l * 128 * 64;
  float a2[4][4];
  #pragma unroll
  for (int i = 0; i < 4; ++i)
    #pragma unroll
    for (int j = 0; j < 4; ++j) a2[i][j] = 0.f;
  #pragma unroll
  for (int half = 0; half < 2; ++half){
    __syncthreads();
    #pragma unroll
    for (int i = 0; i < 4; ++i)
      #pragma unroll
      for (int j = 0; j < 4; ++j){
        const int hp = q + 16*(j + 4*half);
        gl[(t0+i)*68 + (hp - 64*half)] = yg[i][j + 4*half];
      }
    __syncthreads();
    for (int kk = 0; kk < 64; ++kk){
      float4 w4 = *(const float4*)&Wol[(kk + 64*half)*64 + dm0];
      float wv[4] = {w4.x, w4.y, w4.z, w4.w};
      #pragma unroll
      for (int ii = 0; ii < 4; ++ii){
        const float gv = gl[(t0+ii)*68 + kk];
        #pragma unroll
        for (int j = 0; j < 4; ++j) a2[ii][j] += gv * wv[j];
      }
    }
  }
  float4 b4 = *(const float4*)&bo[l*64 + dm0];
  float bv[4] = {b4.x, b4.y, b4.z, b4.w};
  float colsum[4] = {0.f, 0.f, 0.f, 0.f};
  #pragma unroll
  for (int ii = 0; ii < 4; ++ii){
    const long tok = tb + t0 + ii;
    float4 h4 = *(const float4*)&g_h0[tok*64 + dm0];
    float hv[4] = {h4.x, h4.y, h4.z, h4.w};
    float4 o;
    o.x = a2[ii][0] + bv[0] + hv[0];
    o.y = a2[ii][1] + bv[1] + hv[1];
    o.z = a2[ii][2] + bv[2] + hv[2];
    o.w = a2[ii][3] + bv[3] + hv[3];
    colsum[0] += o.x; colsum[1] += o.y; colsum[2] += o.z; colsum[3] += o.w;
    *(float4*)&g_h0[tok*64 + dm0] = o;
  }
  if (finalLayer){
    float* csum = Cl;                  // [16][68] alias, Cl dead by now
    const int tg = tid >> 4;
    #pragma unroll
    for (int j = 0; j < 4; ++j) csum[tg*68 + dm0 + j] = colsum[j];
    __syncthreads();
    if (tid < 64){
      float s = 0.f;
      for (int r = 0; r < 16; ++r) s += csum[r*68 + tid];
      g_ppc[((long)b*NCH + cI)*64 + tid] = s;
    }
  }
}

// ---------------- pooling + classifier ----------------
__global__ __launch_bounds__(64) void k_pool2(
    const float* __restrict__ cW, const float* __restrict__ cb,
    float* __restrict__ out)
{
  __shared__ float pl[64];
  const int b = blockIdx.x, tid = threadIdx.x;
  float s = 0.f;
  for (int c = 0; c < NCH; ++c) s += g_ppc[((long)b*NCH + c)*64 + tid];
  pl[tid] = s * (1.0f / 8192.0f);
  __syncthreads();
  if (tid < NOUTC){
    float acc = cb[tid];
    for (int dm = 0; dm < 64; ++dm) acc += pl[dm] * cW[dm*NOUTC + tid];
    out[b*NOUTC + tid] = acc;
  }
}

extern "C" void kernel_launch(void* const* d_in, const int* in_sizes, int n_in,
                              void* d_out, int out_size, void* d_ws, size_t ws_size,
                              hipStream_t stream)
{
  const float* x      = (const float*)d_in[0];
  const float* W_in   = (const float*)d_in[1];
  const float* b_in   = (const float*)d_in[2];
  const float* ipW    = (const float*)d_in[3];
  const float* ipb    = (const float*)d_in[4];
  const float* A_log  = (const float*)d_in[5];
  const float* Dp     = (const float*)d_in[6];
  const float* dtb    = (const float*)d_in[7];
  const float* opW    = (const float*)d_in[8];
  const float* opb    = (const float*)d_in[9];
  const float* clsW   = (const float*)d_in[10];
  const float* clsb   = (const float*)d_in[11];
  float* out = (float*)d_out;
  (void)d_ws; (void)ws_size;

  k_wprep<<<dim3(NT21, NLAY), 128, 0, stream>>>(ipW);
  k_linin<<<2048, 256, 0, stream>>>(x, W_in, b_in);
  for (int l = 0; l < NLAY; ++l){
    k_proj<<<1024, 256, 0, stream>>>(ipb, dtb, l);
    k_s1<<<dim3(NCH, BSZ), 256, 0, stream>>>(A_log, Dp, l);
    k_s2<<<dim3(32, BSZ), 128, 0, stream>>>();
    k_s3<<<dim3(NCH, BSZ), 256, 0, stream>>>(opW, opb, l, (l == NLAY-1) ? 1 : 0);
  }
  k_pool2<<<BSZ, 64, 0, stream>>>(clsW, clsb, out);
}

// Round 10
// 492.691 us; speedup vs baseline: 11.6546x; 1.2586x over previous
//
#include <hip/hip_runtime.h>

#define BSZ   16
#define LSEQ  8192
#define DMDL  64
#define DSD   32
#define HDD   32
#define NHD   4
#define DIN   128
#define NLAY  2
#define NOUTC 6
#define DPRJ  324
#define QC    64
#define NCH   128   // LSEQ/QC
#define NT21  21    // 21 column tiles of 16 (320 proj cols + 4 dt cols zero-padded)

typedef __attribute__((ext_vector_type(8))) short bf16x8;
typedef __attribute__((ext_vector_type(4))) float f32x4;

// ---- device-global scratch ----
__device__ float          g_h0[BSZ*LSEQ*DMDL];
__device__ unsigned short g_za[BSZ*LSEQ*DIN];   // RAW z, bf16 (silu applied once, in k_s3)
__device__ unsigned short g_xy[BSZ*LSEQ*DIN];   // silu(x), overwritten by y_intra (bf16)
__device__ float          g_Ba[BSZ*LSEQ*DSD];
__device__ float          g_Ca[BSZ*LSEQ*DSD];
__device__ float          g_dt[BSZ*LSEQ*NHD];
__device__ float          g_pc[BSZ*LSEQ*NHD];
__device__ float          g_cS[BSZ*NCH*NHD*HDD*DSD]; // chunk states, scanned in-place -> H_in
__device__ float          g_cL[BSZ*NCH*NHD];
__device__ float          g_ppc[BSZ*NCH*DMDL];       // per-chunk column sums (final layer)
__device__ unsigned short g_wf[NLAY*NT21*2*64*8];    // in_proj W in bf16 MFMA B-fragment layout

__device__ __forceinline__ float silu_f(float v){ return v / (1.0f + __expf(-v)); }
__device__ __forceinline__ float softplus_f(float v){ return (v > 15.0f) ? v : __logf(1.0f + __expf(v)); }
__device__ __forceinline__ unsigned short f2bf(float f){
  union { float f; unsigned u; } v; v.f = f;
  unsigned r = v.u + 0x7FFFu + ((v.u >> 16) & 1u);
  return (unsigned short)(r >> 16);
}
__device__ __forceinline__ float bf2f(unsigned short h){
  union { unsigned u; float f; } v; v.u = ((unsigned)h) << 16;
  return v.f;
}

// ---------------- linear_in ----------------
__global__ __launch_bounds__(256) void k_linin(
    const float* __restrict__ x, const float* __restrict__ W,
    const float* __restrict__ bias)
{
  __shared__ float xs[64*60];
  __shared__ float wl[57*64];
  const int tid = threadIdx.x;
  const long tb = (long)blockIdx.x * 64;
  for (int i = tid; i < 64*57; i += 256){
    int t = i / 57, k = i - t*57;
    xs[t*60 + k] = x[tb*57 + i];
  }
  for (int i = tid; i < 57*64; i += 256) wl[i] = W[i];
  __syncthreads();
  const int t0 = (tid >> 4) * 4, d0 = (tid & 15) * 4;
  float acc[4][4];
  #pragma unroll
  for (int i = 0; i < 4; ++i)
    #pragma unroll
    for (int j = 0; j < 4; ++j) acc[i][j] = 0.f;
  for (int k = 0; k < 57; ++k){
    float4 w4 = *(const float4*)&wl[k*64 + d0];
    float wv[4] = {w4.x, w4.y, w4.z, w4.w};
    #pragma unroll
    for (int i = 0; i < 4; ++i){
      float xv = xs[(t0+i)*60 + k];
      #pragma unroll
      for (int j = 0; j < 4; ++j) acc[i][j] += xv * wv[j];
    }
  }
  float4 b4 = *(const float4*)&bias[d0];
  float bv[4] = {b4.x, b4.y, b4.z, b4.w};
  #pragma unroll
  for (int i = 0; i < 4; ++i){
    float4 o;
    o.x = acc[i][0] + bv[0]; o.y = acc[i][1] + bv[1];
    o.z = acc[i][2] + bv[2]; o.w = acc[i][3] + bv[3];
    *(float4*)&g_h0[(tb + t0 + i)*64 + d0] = o;
  }
}

// ---------------- weight prep: ipW -> bf16 B-fragment layout ----------------
__global__ __launch_bounds__(128) void k_wprep(const float* __restrict__ W)
{
  const int nt = blockIdx.x;            // 0..20
  const int l  = blockIdx.y;            // layer
  const int ks = threadIdx.x >> 6, lane = threadIdx.x & 63;
  const float* Wl = W + (long)l*64*DPRJ;
  const int n  = nt*16 + (lane & 15);
  const int k0 = ks*32 + (lane >> 4)*8;
  unsigned short v[8];
  #pragma unroll
  for (int j = 0; j < 8; ++j)
    v[j] = (n < DPRJ) ? f2bf(Wl[(k0 + j)*DPRJ + n]) : (unsigned short)0;
  unsigned short* d = &g_wf[((((long)l*NT21 + nt)*2 + ks)*64 + lane)*8];
  *(ushort4*)&d[0] = make_ushort4(v[0], v[1], v[2], v[3]);
  *(ushort4*)&d[4] = make_ushort4(v[4], v[5], v[6], v[7]);
}

// ---------------- in_proj via MFMA (128 tokens/block) ----------------
__global__ __launch_bounds__(256) void k_proj(
    const float* __restrict__ bias, const float* __restrict__ dt_bias, int l)
{
  __shared__ __align__(16) unsigned short Afr[8*2*64*8];  // [mtile][kstep][lane][8] bf16, 16 KB
  const int tid = threadIdx.x;
  const long tb = (long)blockIdx.x * 128;
  #pragma unroll
  for (int r = 0; r < 4; ++r){
    const int c = tid + 256*r;
    const int t = c >> 3, k8 = c & 7;
    float4 f0 = *(const float4*)&g_h0[(tb + t)*64 + k8*8];
    float4 f1 = *(const float4*)&g_h0[(tb + t)*64 + k8*8 + 4];
    const int mt = t >> 4, ks = k8 >> 2, q = k8 & 3, ln = (t & 15) + 16*q;
    unsigned short* d = &Afr[(((mt*2 + ks)*64) + ln)*8];
    *(ushort4*)&d[0] = make_ushort4(f2bf(f0.x), f2bf(f0.y), f2bf(f0.z), f2bf(f0.w));
    *(ushort4*)&d[4] = make_ushort4(f2bf(f1.x), f2bf(f1.y), f2bf(f1.z), f2bf(f1.w));
  }
  __syncthreads();
  const int w = tid >> 6, lane = tid & 63;
  const int colq = lane & 15, rowq = lane >> 4;
  bf16x8 a[2][2];
  #pragma unroll
  for (int m = 0; m < 2; ++m)
    #pragma unroll
    for (int ks = 0; ks < 2; ++ks)
      a[m][ks] = *(const bf16x8*)&Afr[((((2*w + m)*2 + ks)*64) + lane)*8];
  const float* bl = bias + (long)l*DPRJ;
  const unsigned short* wf = &g_wf[(long)l*NT21*2*64*8];
  for (int nt = 0; nt < NT21; ++nt){
    bf16x8 b0 = *(const bf16x8*)&wf[((nt*2 + 0)*64 + lane)*8];
    bf16x8 b1 = *(const bf16x8*)&wf[((nt*2 + 1)*64 + lane)*8];
    #pragma unroll
    for (int m = 0; m < 2; ++m){
      f32x4 acc = {0.f, 0.f, 0.f, 0.f};
      acc = __builtin_amdgcn_mfma_f32_16x16x32_bf16(a[m][0], b0, acc, 0, 0, 0);
      acc = __builtin_amdgcn_mfma_f32_16x16x32_bf16(a[m][1], b1, acc, 0, 0, 0);
      const int mt = 2*w + m;
      const int tbase = mt*16 + rowq*4;
      const int gcol = nt*16 + colq;
      if (nt < 8){
        const float b = bl[gcol];
        #pragma unroll
        for (int r = 0; r < 4; ++r)
          g_za[(tb + tbase + r)*128 + gcol] = f2bf(acc[r] + b);
      } else if (nt < 16){
        const float b = bl[gcol];
        #pragma unroll
        for (int r = 0; r < 4; ++r)
          g_xy[(tb + tbase + r)*128 + (gcol - 128)] = f2bf(silu_f(acc[r] + b));
      } else if (nt < 18){
        const float b = bl[gcol];
        #pragma unroll
        for (int r = 0; r < 4; ++r)
          g_Ba[(tb + tbase + r)*32 + (gcol - 256)] = silu_f(acc[r] + b);
      } else if (nt < 20){
        const float b = bl[gcol];
        #pragma unroll
        for (int r = 0; r < 4; ++r)
          g_Ca[(tb + tbase + r)*32 + (gcol - 288)] = silu_f(acc[r] + b);
      } else {
        if (colq < 4){
          const float b = bl[320 + colq] + dt_bias[l*4 + colq];
          #pragma unroll
          for (int r = 0; r < 4; ++r)
            g_dt[(tb + tbase + r)*4 + colq] = softplus_f(acc[r] + b);
        }
      }
    }
  }
}

// ---------------- chunk intra: all-MFMA (G, y_intra, chunkS) ----------------
// Strides (in ushorts) are multiples of 8 so every bf16x8 LDS load is 16B-aligned.
#define SB 40   // Bb/Cb row stride
#define ST 72   // Mb/Xt/Xwt/Bbt row stride
__global__ __launch_bounds__(256) void k_s1(
    const float* __restrict__ A_log, const float* __restrict__ Dp, int l)
{
  __shared__ __align__(16) unsigned short u_bc[2*64*SB]; // phase A: Bb[64][SB] + Cb[64][SB]; head loop: Xt[32][ST] + Xwt[32][ST]
  __shared__ __align__(16) unsigned short Bbt[32*ST];    // B transposed [n][s]
  __shared__ __align__(16) unsigned short Mb[64*ST];     // per-head decay-scaled M [t][s]
  __shared__ float Sl[4*64];
  __shared__ float dts[4*64];
  __shared__ float wls[4*64];
  const int tid = threadIdx.x;
  const int cI = blockIdx.x, b = blockIdx.y;
  const long tb = (long)b*LSEQ + (long)cI*QC;
  unsigned short* Bb = u_bc;
  unsigned short* Cb = u_bc + 64*SB;
  // ---- stage B, C (bf16) + Bbt (transposed) ----
  for (int i = tid; i < 512; i += 256){
    const int s = i >> 3, n0 = (i & 7) * 4;
    float4 bv = *(const float4*)&g_Ba[(tb + s)*32 + n0];
    float4 cv = *(const float4*)&g_Ca[(tb + s)*32 + n0];
    ushort4 bu = make_ushort4(f2bf(bv.x), f2bf(bv.y), f2bf(bv.z), f2bf(bv.w));
    ushort4 cu = make_ushort4(f2bf(cv.x), f2bf(cv.y), f2bf(cv.z), f2bf(cv.w));
    *(ushort4*)&Bb[s*SB + n0] = bu;
    *(ushort4*)&Cb[s*SB + n0] = cu;
    Bbt[(n0    )*ST + s] = bu.x;
    Bbt[(n0 + 1)*ST + s] = bu.y;
    Bbt[(n0 + 2)*ST + s] = bu.z;
    Bbt[(n0 + 3)*ST + s] = bu.w;
  }
  // ---- wave-parallel scan: wave = head, lane = token ----
  {
    const int h = tid >> 6, t = tid & 63;
    const float Ah = -__expf(A_log[l*4 + h]);
    const float v = g_dt[(tb + t)*4 + h];
    float x = v * Ah;
    #pragma unroll
    for (int d = 1; d < 64; d <<= 1){
      float y = __shfl_up(x, d);
      if (t >= d) x += y;
    }
    Sl[h*64 + t] = x;
    dts[h*64 + t] = v;
    const float send = __shfl(x, 63);
    wls[h*64 + t] = __expf(send - x) * v;
    if (t == 63) g_cL[((long)b*NCH + cI)*4 + h] = x;
    g_pc[(tb + t)*4 + h] = __expf(x);
  }
  __syncthreads();
  const int w = tid >> 6, lane = tid & 63;
  const int colq = lane & 15, rowq = lane >> 4;
  // ---- G = C . B^T via MFMA: 10 lower-triangle tiles round-robin over waves ----
  float Greg[3][4];
  int Gmt[3], Gst[3];
  #pragma unroll
  for (int rep = 0; rep < 3; ++rep){
    const int k = w + rep*4;
    if (k < 10){
      const int mt = (k >= 6) ? 3 : ((k >= 3) ? 2 : ((k >= 1) ? 1 : 0));
      const int st = k - mt*(mt+1)/2;
      Gmt[rep] = mt; Gst[rep] = st;
      bf16x8 af = *(const bf16x8*)&Cb[(mt*16 + colq)*SB + rowq*8];
      bf16x8 bf = *(const bf16x8*)&Bb[(st*16 + colq)*SB + rowq*8];
      f32x4 acc = {0.f, 0.f, 0.f, 0.f};
      acc = __builtin_amdgcn_mfma_f32_16x16x32_bf16(af, bf, acc, 0, 0, 0);
      #pragma unroll
      for (int r = 0; r < 4; ++r) Greg[rep][r] = acc[r];
    } else { Gmt[rep] = -1; Gst[rep] = 0; }
  }
  // zero the 6 upper tiles of Mb once (stay zero across heads)
  #pragma unroll
  for (int rep = 0; rep < 2; ++rep){
    const int k = w + rep*4;
    if (k < 6){
      const int mt = (k < 3) ? 0 : ((k < 5) ? 1 : 2);
      const int st = (k < 3) ? (k + 1) : ((k < 5) ? (k - 1) : 3);
      #pragma unroll
      for (int r = 0; r < 4; ++r)
        Mb[(mt*16 + rowq*4 + r)*ST + st*16 + colq] = 0;
    }
  }
  unsigned short* Xt  = u_bc;             // alias: Bb/Cb dead after G
  unsigned short* Xwt = u_bc + 32*ST;
  for (int h = 0; h < NHD; ++h){
    __syncthreads();   // prior head's MFMA reads done (h=0: G reads of Bb/Cb done)
    // stage Xt[p][s] (raw bf16) and Xwt[p][s] = wl[s]*x (bf16)
    for (int i = tid; i < 512; i += 256){
      const int s = i >> 3, p0 = (i & 7) * 4;
      ushort4 u = *(const ushort4*)&g_xy[(tb + s)*128 + h*32 + p0];
      const float wv = wls[h*64 + s];
      Xt[(p0    )*ST + s] = u.x;  Xwt[(p0    )*ST + s] = f2bf(wv * bf2f(u.x));
      Xt[(p0 + 1)*ST + s] = u.y;  Xwt[(p0 + 1)*ST + s] = f2bf(wv * bf2f(u.y));
      Xt[(p0 + 2)*ST + s] = u.z;  Xwt[(p0 + 2)*ST + s] = f2bf(wv * bf2f(u.z));
      Xt[(p0 + 3)*ST + s] = u.w;  Xwt[(p0 + 3)*ST + s] = f2bf(wv * bf2f(u.w));
    }
    // write Mb lower tiles with head-h decay: M = (s<=t) ? exp(Sl[t]-Sl[s])*dt[s]*G : 0
    #pragma unroll
    for (int rep = 0; rep < 3; ++rep){
      if (Gmt[rep] >= 0){
        const int mt = Gmt[rep], st = Gst[rep];
        const int s = st*16 + colq;
        const float sls = Sl[h*64 + s];
        const float dv = dts[h*64 + s];
        #pragma unroll
        for (int r = 0; r < 4; ++r){
          const int t = mt*16 + rowq*4 + r;
          const float m = (s <= t) ? __expf(Sl[h*64 + t] - sls) * dv * Greg[rep][r] : 0.f;
          Mb[t*ST + s] = f2bf(m);
        }
      }
    }
    __syncthreads();
    const float Dh = Dp[l*4 + h];
    // y_intra = M @ X : wave w owns mtile w, ntiles 0..1 (K=64 -> 2 MFMA)
    {
      bf16x8 a0 = *(const bf16x8*)&Mb[(w*16 + colq)*ST + rowq*8];
      bf16x8 a1 = *(const bf16x8*)&Mb[(w*16 + colq)*ST + 32 + rowq*8];
      #pragma unroll
      for (int nt = 0; nt < 2; ++nt){
        bf16x8 b0 = *(const bf16x8*)&Xt[(nt*16 + colq)*ST + rowq*8];
        bf16x8 b1 = *(const bf16x8*)&Xt[(nt*16 + colq)*ST + 32 + rowq*8];
        f32x4 acc = {0.f, 0.f, 0.f, 0.f};
        acc = __builtin_amdgcn_mfma_f32_16x16x32_bf16(a0, b0, acc, 0, 0, 0);
        acc = __builtin_amdgcn_mfma_f32_16x16x32_bf16(a1, b1, acc, 0, 0, 0);
        const int p = nt*16 + colq;
        #pragma unroll
        for (int r = 0; r < 4; ++r){
          const int t = w*16 + rowq*4 + r;
          const float xv = bf2f(Xt[p*ST + t]);
          g_xy[(tb + t)*128 + h*32 + p] = f2bf(acc[r] + Dh*xv);
        }
      }
    }
    // chunkS = (wl*X)^T @ B : wave w owns tile (mt = w&1, nt = w>>1), K=64 -> 2 MFMA
    {
      const int mt = w & 1, nt = w >> 1;
      bf16x8 a0 = *(const bf16x8*)&Xwt[(mt*16 + colq)*ST + rowq*8];
      bf16x8 a1 = *(const bf16x8*)&Xwt[(mt*16 + colq)*ST + 32 + rowq*8];
      bf16x8 b0 = *(const bf16x8*)&Bbt[(nt*16 + colq)*ST + rowq*8];
      bf16x8 b1 = *(const bf16x8*)&Bbt[(nt*16 + colq)*ST + 32 + rowq*8];
      f32x4 acc = {0.f, 0.f, 0.f, 0.f};
      acc = __builtin_amdgcn_mfma_f32_16x16x32_bf16(a0, b0, acc, 0, 0, 0);
      acc = __builtin_amdgcn_mfma_f32_16x16x32_bf16(a1, b1, acc, 0, 0, 0);
      const long base = (((long)b*NCH + cI)*NHD + h)*(HDD*DSD);
      const int n = nt*16 + colq;
      #pragma unroll
      for (int r = 0; r < 4; ++r){
        const int p = mt*16 + rowq*4 + r;
        g_cS[base + p*32 + n] = acc[r];
      }
    }
  }
}

// ---------------- cross-chunk state prefix scan (in place) ----------------
__global__ __launch_bounds__(128) void k_s2()
{
  const int h = blockIdx.x >> 3, seg = blockIdx.x & 7, b = blockIdx.y;
  const int idx = seg*128 + threadIdx.x;
  float H = 0.f;
  for (int c = 0; c < NCH; ++c){
    const long o = (((long)b*NCH + c)*NHD + h)*1024 + idx;
    const float cs = g_cS[o];
    const float lg = g_cL[((long)b*NCH + c)*4 + h];
    g_cS[o] = H;
    H = __expf(lg) * H + cs;
  }
}

// ---------------- y_inter + gate + out_proj + residual (+ pool on final layer) ----------------
__global__ __launch_bounds__(256) void k_s3(
    const float* __restrict__ Wo, const float* __restrict__ bo, int l, int finalLayer)
{
  __shared__ float Hl[128*33];
  __shared__ float Cl[64*36];   // aliased as csum[16][68] in the pool epilogue
  __shared__ float pcl[4*64];
  __shared__ float gl[64*68];
  const int tid = threadIdx.x;
  const int cI = blockIdx.x, b = blockIdx.y;
  const long tb = (long)b*LSEQ + (long)cI*QC;
  const long hb = (((long)b*NCH + cI)*NHD)*(long)(HDD*DSD);
  for (int i = tid; i < 4096; i += 256) Hl[(i>>5)*33 + (i&31)] = g_cS[hb + i];
  for (int i = tid; i < 2048; i += 256){
    int t = i >> 5, n = i & 31;
    Cl[t*36 + n] = g_Ca[(tb + t)*32 + n];
  }
  { int t = tid >> 2, h = tid & 3; pcl[h*64 + t] = g_pc[(tb + t)*4 + h]; }
  __syncthreads();
  const int t0 = (tid >> 4) * 4;
  const int q = tid & 15;
  float acc[4][8];
  #pragma unroll
  for (int i = 0; i < 4; ++i)
    #pragma unroll
    for (int j = 0; j < 8; ++j) acc[i][j] = 0.f;
  for (int n = 0; n < 32; ++n){
    float cv[4], hv[8];
    #pragma unroll
    for (int i = 0; i < 4; ++i) cv[i] = Cl[(t0+i)*36 + n];
    #pragma unroll
    for (int j = 0; j < 8; ++j) hv[j] = Hl[(q + 16*j)*33 + n];
    #pragma unroll
    for (int i = 0; i < 4; ++i)
      #pragma unroll
      for (int j = 0; j < 8; ++j) acc[i][j] += cv[i] * hv[j];
  }
  float yg[4][8];
  #pragma unroll
  for (int i = 0; i < 4; ++i){
    const long tok = tb + t0 + i;
    #pragma unroll
    for (int j = 0; j < 8; ++j){
      const int hp = q + 16*j;
      const int h = hp >> 5;
      const float v = pcl[h*64 + t0 + i] * acc[i][j] + bf2f(g_xy[tok*128 + hp]);
      yg[i][j] = v * silu_f(bf2f(g_za[tok*128 + hp]));   // single silu (za holds raw z)
    }
  }
  const int dm0 = (tid & 15) * 4;
  const float* Wol = Wo + (long)l * 128 * 64;
  float a2[4][4];
  #pragma unroll
  for (int i = 0; i < 4; ++i)
    #pragma unroll
    for (int j = 0; j < 4; ++j) a2[i][j] = 0.f;
  #pragma unroll
  for (int half = 0; half < 2; ++half){
    __syncthreads();
    #pragma unroll
    for (int i = 0; i < 4; ++i)
      #pragma unroll
      for (int j = 0; j < 4; ++j){
        const int hp = q + 16*(j + 4*half);
        gl[(t0+i)*68 + (hp - 64*half)] = yg[i][j + 4*half];
      }
    __syncthreads();
    for (int kk = 0; kk < 64; ++kk){
      float4 w4 = *(const float4*)&Wol[(kk + 64*half)*64 + dm0];
      float wv[4] = {w4.x, w4.y, w4.z, w4.w};
      #pragma unroll
      for (int ii = 0; ii < 4; ++ii){
        const float gv = gl[(t0+ii)*68 + kk];
        #pragma unroll
        for (int j = 0; j < 4; ++j) a2[ii][j] += gv * wv[j];
      }
    }
  }
  float4 b4 = *(const float4*)&bo[l*64 + dm0];
  float bv[4] = {b4.x, b4.y, b4.z, b4.w};
  float colsum[4] = {0.f, 0.f, 0.f, 0.f};
  #pragma unroll
  for (int ii = 0; ii < 4; ++ii){
    const long tok = tb + t0 + ii;
    float4 h4 = *(const float4*)&g_h0[tok*64 + dm0];
    float hv[4] = {h4.x, h4.y, h4.z, h4.w};
    float4 o;
    o.x = a2[ii][0] + bv[0] + hv[0];
    o.y = a2[ii][1] + bv[1] + hv[1];
    o.z = a2[ii][2] + bv[2] + hv[2];
    o.w = a2[ii][3] + bv[3] + hv[3];
    colsum[0] += o.x; colsum[1] += o.y; colsum[2] += o.z; colsum[3] += o.w;
    *(float4*)&g_h0[tok*64 + dm0] = o;
  }
  if (finalLayer){
    float* csum = Cl;                  // [16][68] alias, Cl dead by now
    const int tg = tid >> 4;
    #pragma unroll
    for (int j = 0; j < 4; ++j) csum[tg*68 + dm0 + j] = colsum[j];
    __syncthreads();
    if (tid < 64){
      float s = 0.f;
      for (int r = 0; r < 16; ++r) s += csum[r*68 + tid];
      g_ppc[((long)b*NCH + cI)*64 + tid] = s;
    }
  }
}

// ---------------- pooling + classifier ----------------
__global__ __launch_bounds__(64) void k_pool2(
    const float* __restrict__ cW, const float* __restrict__ cb,
    float* __restrict__ out)
{
  __shared__ float pl[64];
  const int b = blockIdx.x, tid = threadIdx.x;
  float s = 0.f;
  for (int c = 0; c < NCH; ++c) s += g_ppc[((long)b*NCH + c)*64 + tid];
  pl[tid] = s * (1.0f / 8192.0f);
  __syncthreads();
  if (tid < NOUTC){
    float acc = cb[tid];
    for (int dm = 0; dm < 64; ++dm) acc += pl[dm] * cW[dm*NOUTC + tid];
    out[b*NOUTC + tid] = acc;
  }
}

extern "C" void kernel_launch(void* const* d_in, const int* in_sizes, int n_in,
                              void* d_out, int out_size, void* d_ws, size_t ws_size,
                              hipStream_t stream)
{
  const float* x      = (const float*)d_in[0];
  const float* W_in   = (const float*)d_in[1];
  const float* b_in   = (const float*)d_in[2];
  const float* ipW    = (const float*)d_in[3];
  const float* ipb    = (const float*)d_in[4];
  const float* A_log  = (const float*)d_in[5];
  const float* Dp     = (const float*)d_in[6];
  const float* dtb    = (const float*)d_in[7];
  const float* opW    = (const float*)d_in[8];
  const float* opb    = (const float*)d_in[9];
  const float* clsW   = (const float*)d_in[10];
  const float* clsb   = (const float*)d_in[11];
  float* out = (float*)d_out;
  (void)d_ws; (void)ws_size;

  k_wprep<<<dim3(NT21, NLAY), 128, 0, stream>>>(ipW);
  k_linin<<<2048, 256, 0, stream>>>(x, W_in, b_in);
  for (int l = 0; l < NLAY; ++l){
    k_proj<<<1024, 256, 0, stream>>>(ipb, dtb, l);
    k_s1<<<dim3(NCH, BSZ), 256, 0, stream>>>(A_log, Dp, l);
    k_s2<<<dim3(32, BSZ), 128, 0, stream>>>();
    k_s3<<<dim3(NCH, BSZ), 256, 0, stream>>>(opW, opb, l, (l == NLAY-1) ? 1 : 0);
  }
  k_pool2<<<BSZ, 64, 0, stream>>>(clsW, clsb, out);
}

// Round 11
// 413.574 us; speedup vs baseline: 13.8841x; 1.1913x over previous
//
#include <hip/hip_runtime.h>

#define BSZ   16
#define LSEQ  8192
#define DMDL  64
#define DSD   32
#define HDD   32
#define NHD   4
#define DIN   128
#define NLAY  2
#define NOUTC 6
#define DPRJ  324
#define QC    64
#define NCH   128   // LSEQ/QC
#define NT21  21    // 21 column tiles of 16 (320 proj cols + 4 dt cols zero-padded)

typedef __attribute__((ext_vector_type(8))) short bf16x8;
typedef __attribute__((ext_vector_type(4))) float f32x4;

// ---- device-global scratch ----
__device__ float          g_h0[BSZ*LSEQ*DMDL];
__device__ unsigned short g_za[BSZ*LSEQ*DIN];   // RAW z, bf16 (silu applied once, in k_s3)
__device__ unsigned short g_xy[BSZ*LSEQ*DIN];   // silu(x), overwritten by y_intra (bf16)
__device__ unsigned short g_Ba[BSZ*LSEQ*DSD];   // silu(B), bf16
__device__ unsigned short g_Ca[BSZ*LSEQ*DSD];   // silu(C), bf16
__device__ float          g_dt[BSZ*LSEQ*NHD];
__device__ float          g_pc[BSZ*LSEQ*NHD];
__device__ float          g_cS[BSZ*NCH*NHD*HDD*DSD]; // chunk states, scanned in-place -> H_in
__device__ float          g_cL[BSZ*NCH*NHD];
__device__ float          g_ppc[BSZ*NCH*DMDL];       // per-chunk column sums (final layer)
__device__ unsigned short g_wf[NLAY*NT21*2*64*8];    // in_proj W, bf16 MFMA B-fragment layout
__device__ unsigned short g_wo[NLAY*4*4*64*8];       // out_proj W, bf16 MFMA B-fragment layout

__device__ __forceinline__ float silu_f(float v){ return v / (1.0f + __expf(-v)); }
__device__ __forceinline__ float softplus_f(float v){ return (v > 15.0f) ? v : __logf(1.0f + __expf(v)); }
__device__ __forceinline__ unsigned short f2bf(float f){
  union { float f; unsigned u; } v; v.f = f;
  unsigned r = v.u + 0x7FFFu + ((v.u >> 16) & 1u);
  return (unsigned short)(r >> 16);
}
__device__ __forceinline__ float bf2f(unsigned short h){
  union { unsigned u; float f; } v; v.u = ((unsigned)h) << 16;
  return v.f;
}

// ---------------- linear_in ----------------
__global__ __launch_bounds__(256) void k_linin(
    const float* __restrict__ x, const float* __restrict__ W,
    const float* __restrict__ bias)
{
  __shared__ float xs[64*60];
  __shared__ float wl[57*64];
  const int tid = threadIdx.x;
  const long tb = (long)blockIdx.x * 64;
  for (int i = tid; i < 64*57; i += 256){
    int t = i / 57, k = i - t*57;
    xs[t*60 + k] = x[tb*57 + i];
  }
  for (int i = tid; i < 57*64; i += 256) wl[i] = W[i];
  __syncthreads();
  const int t0 = (tid >> 4) * 4, d0 = (tid & 15) * 4;
  float acc[4][4];
  #pragma unroll
  for (int i = 0; i < 4; ++i)
    #pragma unroll
    for (int j = 0; j < 4; ++j) acc[i][j] = 0.f;
  for (int k = 0; k < 57; ++k){
    float4 w4 = *(const float4*)&wl[k*64 + d0];
    float wv[4] = {w4.x, w4.y, w4.z, w4.w};
    #pragma unroll
    for (int i = 0; i < 4; ++i){
      float xv = xs[(t0+i)*60 + k];
      #pragma unroll
      for (int j = 0; j < 4; ++j) acc[i][j] += xv * wv[j];
    }
  }
  float4 b4 = *(const float4*)&bias[d0];
  float bv[4] = {b4.x, b4.y, b4.z, b4.w};
  #pragma unroll
  for (int i = 0; i < 4; ++i){
    float4 o;
    o.x = acc[i][0] + bv[0]; o.y = acc[i][1] + bv[1];
    o.z = acc[i][2] + bv[2]; o.w = acc[i][3] + bv[3];
    *(float4*)&g_h0[(tb + t0 + i)*64 + d0] = o;
  }
}

// ---------------- weight prep: ipW -> bf16 B-fragment layout ----------------
__global__ __launch_bounds__(128) void k_wprep(const float* __restrict__ W)
{
  const int nt = blockIdx.x;            // 0..20
  const int l  = blockIdx.y;            // layer
  const int ks = threadIdx.x >> 6, lane = threadIdx.x & 63;
  const float* Wl = W + (long)l*64*DPRJ;
  const int n  = nt*16 + (lane & 15);
  const int k0 = ks*32 + (lane >> 4)*8;
  unsigned short v[8];
  #pragma unroll
  for (int j = 0; j < 8; ++j)
    v[j] = (n < DPRJ) ? f2bf(Wl[(k0 + j)*DPRJ + n]) : (unsigned short)0;
  unsigned short* d = &g_wf[((((long)l*NT21 + nt)*2 + ks)*64 + lane)*8];
  *(ushort4*)&d[0] = make_ushort4(v[0], v[1], v[2], v[3]);
  *(ushort4*)&d[4] = make_ushort4(v[4], v[5], v[6], v[7]);
}

// ---------------- weight prep: out_proj W -> bf16 B-fragment layout ----------------
__global__ __launch_bounds__(64) void k_wprep2(const float* __restrict__ Wo)
{
  const int nt = blockIdx.x >> 2, ks = blockIdx.x & 3, l = blockIdx.y;
  const int lane = threadIdx.x;
  const int n  = nt*16 + (lane & 15);
  const int k0 = ks*32 + (lane >> 4)*8;
  const float* Wl = Wo + (long)l*128*64;
  unsigned short* d = &g_wo[((((long)l*4 + nt)*4 + ks)*64 + lane)*8];
  unsigned short v[8];
  #pragma unroll
  for (int j = 0; j < 8; ++j) v[j] = f2bf(Wl[(k0 + j)*64 + n]);
  *(ushort4*)&d[0] = make_ushort4(v[0], v[1], v[2], v[3]);
  *(ushort4*)&d[4] = make_ushort4(v[4], v[5], v[6], v[7]);
}

// ---------------- in_proj via MFMA (128 tokens/block) ----------------
__global__ __launch_bounds__(256) void k_proj(
    const float* __restrict__ bias, const float* __restrict__ dt_bias, int l)
{
  __shared__ __align__(16) unsigned short Afr[8*2*64*8];  // [mtile][kstep][lane][8] bf16, 16 KB
  const int tid = threadIdx.x;
  const long tb = (long)blockIdx.x * 128;
  #pragma unroll
  for (int r = 0; r < 4; ++r){
    const int c = tid + 256*r;
    const int t = c >> 3, k8 = c & 7;
    float4 f0 = *(const float4*)&g_h0[(tb + t)*64 + k8*8];
    float4 f1 = *(const float4*)&g_h0[(tb + t)*64 + k8*8 + 4];
    const int mt = t >> 4, ks = k8 >> 2, q = k8 & 3, ln = (t & 15) + 16*q;
    unsigned short* d = &Afr[(((mt*2 + ks)*64) + ln)*8];
    *(ushort4*)&d[0] = make_ushort4(f2bf(f0.x), f2bf(f0.y), f2bf(f0.z), f2bf(f0.w));
    *(ushort4*)&d[4] = make_ushort4(f2bf(f1.x), f2bf(f1.y), f2bf(f1.z), f2bf(f1.w));
  }
  __syncthreads();
  const int w = tid >> 6, lane = tid & 63;
  const int colq = lane & 15, rowq = lane >> 4;
  bf16x8 a[2][2];
  #pragma unroll
  for (int m = 0; m < 2; ++m)
    #pragma unroll
    for (int ks = 0; ks < 2; ++ks)
      a[m][ks] = *(const bf16x8*)&Afr[((((2*w + m)*2 + ks)*64) + lane)*8];
  const float* bl = bias + (long)l*DPRJ;
  const unsigned short* wf = &g_wf[(long)l*NT21*2*64*8];
  for (int nt = 0; nt < NT21; ++nt){
    bf16x8 b0 = *(const bf16x8*)&wf[((nt*2 + 0)*64 + lane)*8];
    bf16x8 b1 = *(const bf16x8*)&wf[((nt*2 + 1)*64 + lane)*8];
    #pragma unroll
    for (int m = 0; m < 2; ++m){
      f32x4 acc = {0.f, 0.f, 0.f, 0.f};
      acc = __builtin_amdgcn_mfma_f32_16x16x32_bf16(a[m][0], b0, acc, 0, 0, 0);
      acc = __builtin_amdgcn_mfma_f32_16x16x32_bf16(a[m][1], b1, acc, 0, 0, 0);
      const int mt = 2*w + m;
      const int tbase = mt*16 + rowq*4;
      const int gcol = nt*16 + colq;
      if (nt < 8){
        const float b = bl[gcol];
        #pragma unroll
        for (int r = 0; r < 4; ++r)
          g_za[(tb + tbase + r)*128 + gcol] = f2bf(acc[r] + b);
      } else if (nt < 16){
        const float b = bl[gcol];
        #pragma unroll
        for (int r = 0; r < 4; ++r)
          g_xy[(tb + tbase + r)*128 + (gcol - 128)] = f2bf(silu_f(acc[r] + b));
      } else if (nt < 18){
        const float b = bl[gcol];
        #pragma unroll
        for (int r = 0; r < 4; ++r)
          g_Ba[(tb + tbase + r)*32 + (gcol - 256)] = f2bf(silu_f(acc[r] + b));
      } else if (nt < 20){
        const float b = bl[gcol];
        #pragma unroll
        for (int r = 0; r < 4; ++r)
          g_Ca[(tb + tbase + r)*32 + (gcol - 288)] = f2bf(silu_f(acc[r] + b));
      } else {
        if (colq < 4){
          const float b = bl[320 + colq] + dt_bias[l*4 + colq];
          #pragma unroll
          for (int r = 0; r < 4; ++r)
            g_dt[(tb + tbase + r)*4 + colq] = softplus_f(acc[r] + b);
        }
      }
    }
  }
}

// ---------------- chunk intra: all-MFMA (G, y_intra, chunkS) ----------------
#define SB 40   // Bb/Cb row stride (ushorts)
#define ST 72   // Mb/Xt/Xwt/Bbt row stride (ushorts)
__global__ __launch_bounds__(256) void k_s1(
    const float* __restrict__ A_log, const float* __restrict__ Dp, int l)
{
  __shared__ __align__(16) unsigned short u_bc[2*64*SB]; // Bb[64][SB]+Cb[64][SB]; later Xt[32][ST]+Xwt[32][ST]
  __shared__ __align__(16) unsigned short Bbt[32*ST];    // B transposed [n][s]
  __shared__ __align__(16) unsigned short Mb[64*ST];     // per-head decay-scaled M [t][s]
  __shared__ float Sl[4*64];
  __shared__ float dts[4*64];
  __shared__ float wls[4*64];
  const int tid = threadIdx.x;
  const int cI = blockIdx.x, b = blockIdx.y;
  const long tb = (long)b*LSEQ + (long)cI*QC;
  unsigned short* Bb = u_bc;
  unsigned short* Cb = u_bc + 64*SB;
  for (int i = tid; i < 512; i += 256){
    const int s = i >> 3, n0 = (i & 7) * 4;
    ushort4 bu = *(const ushort4*)&g_Ba[(tb + s)*32 + n0];
    ushort4 cu = *(const ushort4*)&g_Ca[(tb + s)*32 + n0];
    *(ushort4*)&Bb[s*SB + n0] = bu;
    *(ushort4*)&Cb[s*SB + n0] = cu;
    Bbt[(n0    )*ST + s] = bu.x;
    Bbt[(n0 + 1)*ST + s] = bu.y;
    Bbt[(n0 + 2)*ST + s] = bu.z;
    Bbt[(n0 + 3)*ST + s] = bu.w;
  }
  // ---- wave-parallel scan: wave = head, lane = token ----
  {
    const int h = tid >> 6, t = tid & 63;
    const float Ah = -__expf(A_log[l*4 + h]);
    const float v = g_dt[(tb + t)*4 + h];
    float x = v * Ah;
    #pragma unroll
    for (int d = 1; d < 64; d <<= 1){
      float y = __shfl_up(x, d);
      if (t >= d) x += y;
    }
    Sl[h*64 + t] = x;
    dts[h*64 + t] = v;
    const float send = __shfl(x, 63);
    wls[h*64 + t] = __expf(send - x) * v;
    if (t == 63) g_cL[((long)b*NCH + cI)*4 + h] = x;
    g_pc[(tb + t)*4 + h] = __expf(x);
  }
  __syncthreads();
  const int w = tid >> 6, lane = tid & 63;
  const int colq = lane & 15, rowq = lane >> 4;
  // ---- G = C . B^T via MFMA: 10 lower-triangle tiles round-robin over waves ----
  float Greg[3][4];
  int Gmt[3], Gst[3];
  #pragma unroll
  for (int rep = 0; rep < 3; ++rep){
    const int k = w + rep*4;
    if (k < 10){
      const int mt = (k >= 6) ? 3 : ((k >= 3) ? 2 : ((k >= 1) ? 1 : 0));
      const int st = k - mt*(mt+1)/2;
      Gmt[rep] = mt; Gst[rep] = st;
      bf16x8 af = *(const bf16x8*)&Cb[(mt*16 + colq)*SB + rowq*8];
      bf16x8 bf = *(const bf16x8*)&Bb[(st*16 + colq)*SB + rowq*8];
      f32x4 acc = {0.f, 0.f, 0.f, 0.f};
      acc = __builtin_amdgcn_mfma_f32_16x16x32_bf16(af, bf, acc, 0, 0, 0);
      #pragma unroll
      for (int r = 0; r < 4; ++r) Greg[rep][r] = acc[r];
    } else { Gmt[rep] = -1; Gst[rep] = 0; }
  }
  #pragma unroll
  for (int rep = 0; rep < 2; ++rep){
    const int k = w + rep*4;
    if (k < 6){
      const int mt = (k < 3) ? 0 : ((k < 5) ? 1 : 2);
      const int st = (k < 3) ? (k + 1) : ((k < 5) ? (k - 1) : 3);
      #pragma unroll
      for (int r = 0; r < 4; ++r)
        Mb[(mt*16 + rowq*4 + r)*ST + st*16 + colq] = 0;
    }
  }
  unsigned short* Xt  = u_bc;             // alias: Bb/Cb dead after G
  unsigned short* Xwt = u_bc + 32*ST;
  for (int h = 0; h < NHD; ++h){
    __syncthreads();
    for (int i = tid; i < 512; i += 256){
      const int s = i >> 3, p0 = (i & 7) * 4;
      ushort4 u = *(const ushort4*)&g_xy[(tb + s)*128 + h*32 + p0];
      const float wv = wls[h*64 + s];
      Xt[(p0    )*ST + s] = u.x;  Xwt[(p0    )*ST + s] = f2bf(wv * bf2f(u.x));
      Xt[(p0 + 1)*ST + s] = u.y;  Xwt[(p0 + 1)*ST + s] = f2bf(wv * bf2f(u.y));
      Xt[(p0 + 2)*ST + s] = u.z;  Xwt[(p0 + 2)*ST + s] = f2bf(wv * bf2f(u.z));
      Xt[(p0 + 3)*ST + s] = u.w;  Xwt[(p0 + 3)*ST + s] = f2bf(wv * bf2f(u.w));
    }
    #pragma unroll
    for (int rep = 0; rep < 3; ++rep){
      if (Gmt[rep] >= 0){
        const int mt = Gmt[rep], st = Gst[rep];
        const int s = st*16 + colq;
        const float sls = Sl[h*64 + s];
        const float dv = dts[h*64 + s];
        #pragma unroll
        for (int r = 0; r < 4; ++r){
          const int t = mt*16 + rowq*4 + r;
          const float m = (s <= t) ? __expf(Sl[h*64 + t] - sls) * dv * Greg[rep][r] : 0.f;
          Mb[t*ST + s] = f2bf(m);
        }
      }
    }
    __syncthreads();
    const float Dh = Dp[l*4 + h];
    {
      bf16x8 a0 = *(const bf16x8*)&Mb[(w*16 + colq)*ST + rowq*8];
      bf16x8 a1 = *(const bf16x8*)&Mb[(w*16 + colq)*ST + 32 + rowq*8];
      #pragma unroll
      for (int nt = 0; nt < 2; ++nt){
        bf16x8 b0 = *(const bf16x8*)&Xt[(nt*16 + colq)*ST + rowq*8];
        bf16x8 b1 = *(const bf16x8*)&Xt[(nt*16 + colq)*ST + 32 + rowq*8];
        f32x4 acc = {0.f, 0.f, 0.f, 0.f};
        acc = __builtin_amdgcn_mfma_f32_16x16x32_bf16(a0, b0, acc, 0, 0, 0);
        acc = __builtin_amdgcn_mfma_f32_16x16x32_bf16(a1, b1, acc, 0, 0, 0);
        const int p = nt*16 + colq;
        #pragma unroll
        for (int r = 0; r < 4; ++r){
          const int t = w*16 + rowq*4 + r;
          const float xv = bf2f(Xt[p*ST + t]);
          g_xy[(tb + t)*128 + h*32 + p] = f2bf(acc[r] + Dh*xv);
        }
      }
    }
    {
      const int mt = w & 1, nt = w >> 1;
      bf16x8 a0 = *(const bf16x8*)&Xwt[(mt*16 + colq)*ST + rowq*8];
      bf16x8 a1 = *(const bf16x8*)&Xwt[(mt*16 + colq)*ST + 32 + rowq*8];
      bf16x8 b0 = *(const bf16x8*)&Bbt[(nt*16 + colq)*ST + rowq*8];
      bf16x8 b1 = *(const bf16x8*)&Bbt[(nt*16 + colq)*ST + 32 + rowq*8];
      f32x4 acc = {0.f, 0.f, 0.f, 0.f};
      acc = __builtin_amdgcn_mfma_f32_16x16x32_bf16(a0, b0, acc, 0, 0, 0);
      acc = __builtin_amdgcn_mfma_f32_16x16x32_bf16(a1, b1, acc, 0, 0, 0);
      const long base = (((long)b*NCH + cI)*NHD + h)*(HDD*DSD);
      const int n = nt*16 + colq;
      #pragma unroll
      for (int r = 0; r < 4; ++r){
        const int p = mt*16 + rowq*4 + r;
        g_cS[base + p*32 + n] = acc[r];
      }
    }
  }
}

// ---------------- cross-chunk state prefix scan (in place) ----------------
__global__ __launch_bounds__(128) void k_s2()
{
  const int h = blockIdx.x >> 3, seg = blockIdx.x & 7, b = blockIdx.y;
  const int idx = seg*128 + threadIdx.x;
  float H = 0.f;
  for (int c = 0; c < NCH; ++c){
    const long o = (((long)b*NCH + c)*NHD + h)*1024 + idx;
    const float cs = g_cS[o];
    const float lg = g_cL[((long)b*NCH + c)*4 + h];
    g_cS[o] = H;
    H = __expf(lg) * H + cs;
  }
}

// ---------------- y_inter + gate + out_proj + residual (+ pool), all-MFMA ----------------
__global__ __launch_bounds__(256) void k_s3(
    const float* __restrict__ bo, int l, int finalLayer)
{
  __shared__ __align__(16) unsigned short Hb[128*40];  // H_in bf16 [hp][n]
  __shared__ __align__(16) unsigned short Cb[64*40];   // C bf16 [t][n]
  __shared__ __align__(16) unsigned short gl[64*136];  // gated y bf16 [t][hp]
  __shared__ float pcl[4*64];
  __shared__ float csum[4*64];
  const int tid = threadIdx.x;
  const int cI = blockIdx.x, b = blockIdx.y;
  const long tb = (long)b*LSEQ + (long)cI*QC;
  const long hbase = (((long)b*NCH + cI)*NHD)*(long)(HDD*DSD);
  for (int i = tid; i < 1024; i += 256){
    const int hp = i >> 2, n0 = (i & 3) * 8;
    float4 f0 = *(const float4*)&g_cS[hbase + hp*32 + n0];
    float4 f1 = *(const float4*)&g_cS[hbase + hp*32 + n0 + 4];
    *(ushort4*)&Hb[hp*40 + n0]     = make_ushort4(f2bf(f0.x), f2bf(f0.y), f2bf(f0.z), f2bf(f0.w));
    *(ushort4*)&Hb[hp*40 + n0 + 4] = make_ushort4(f2bf(f1.x), f2bf(f1.y), f2bf(f1.z), f2bf(f1.w));
  }
  for (int i = tid; i < 512; i += 256){
    const int t = i >> 3, n0 = (i & 7) * 4;
    *(ushort4*)&Cb[t*40 + n0] = *(const ushort4*)&g_Ca[(tb + t)*32 + n0];
  }
  { int t = tid >> 2, h = tid & 3; pcl[h*64 + t] = g_pc[(tb + t)*4 + h]; }
  __syncthreads();
  const int w = tid >> 6, lane = tid & 63;
  const int colq = lane & 15, rowq = lane >> 4;
  // ---- phase 1: y_inter = C @ H^T (MFMA), gate with silu(z), -> gl ----
  {
    bf16x8 a = *(const bf16x8*)&Cb[(w*16 + colq)*40 + rowq*8];
    #pragma unroll
    for (int nt = 0; nt < 8; ++nt){
      bf16x8 bfr = *(const bf16x8*)&Hb[(nt*16 + colq)*40 + rowq*8];
      f32x4 acc = {0.f, 0.f, 0.f, 0.f};
      acc = __builtin_amdgcn_mfma_f32_16x16x32_bf16(a, bfr, acc, 0, 0, 0);
      const int hp = nt*16 + colq;
      const int h = hp >> 5;
      #pragma unroll
      for (int r = 0; r < 4; ++r){
        const int t = w*16 + rowq*4 + r;
        const long tok = tb + t;
        const float v = pcl[h*64 + t] * acc[r] + bf2f(g_xy[tok*128 + hp]);
        gl[t*136 + hp] = f2bf(v * silu_f(bf2f(g_za[tok*128 + hp])));
      }
    }
  }
  __syncthreads();
  // ---- phase 2: out = gl @ Wo (MFMA) + bias + residual, colsum for pool ----
  const unsigned short* wo = &g_wo[(long)l*4*4*512];
  #pragma unroll
  for (int nt2 = 0; nt2 < 4; ++nt2){
    f32x4 acc = {0.f, 0.f, 0.f, 0.f};
    #pragma unroll
    for (int ks = 0; ks < 4; ++ks){
      bf16x8 a = *(const bf16x8*)&gl[(w*16 + colq)*136 + ks*32 + rowq*8];
      bf16x8 bfr = *(const bf16x8*)&wo[(nt2*4 + ks)*512 + lane*8];
      acc = __builtin_amdgcn_mfma_f32_16x16x32_bf16(a, bfr, acc, 0, 0, 0);
    }
    const int dm = nt2*16 + colq;
    const float bb = bo[l*64 + dm];
    float part = 0.f;
    #pragma unroll
    for (int r = 0; r < 4; ++r){
      const int t = w*16 + rowq*4 + r;
      const long tok = tb + t;
      const float o = acc[r] + bb + g_h0[tok*64 + dm];
      g_h0[tok*64 + dm] = o;
      part += o;
    }
    if (finalLayer){
      part += __shfl_xor(part, 16);
      part += __shfl_xor(part, 32);
      if (rowq == 0) csum[w*64 + dm] = part;
    }
  }
  if (finalLayer){
    __syncthreads();
    if (tid < 64){
      g_ppc[((long)b*NCH + cI)*64 + tid] =
        csum[tid] + csum[64 + tid] + csum[128 + tid] + csum[192 + tid];
    }
  }
}

// ---------------- pooling + classifier ----------------
__global__ __launch_bounds__(64) void k_pool2(
    const float* __restrict__ cW, const float* __restrict__ cb,
    float* __restrict__ out)
{
  __shared__ float pl[64];
  const int b = blockIdx.x, tid = threadIdx.x;
  float s = 0.f;
  for (int c = 0; c < NCH; ++c) s += g_ppc[((long)b*NCH + c)*64 + tid];
  pl[tid] = s * (1.0f / 8192.0f);
  __syncthreads();
  if (tid < NOUTC){
    float acc = cb[tid];
    for (int dm = 0; dm < 64; ++dm) acc += pl[dm] * cW[dm*NOUTC + tid];
    out[b*NOUTC + tid] = acc;
  }
}

extern "C" void kernel_launch(void* const* d_in, const int* in_sizes, int n_in,
                              void* d_out, int out_size, void* d_ws, size_t ws_size,
                              hipStream_t stream)
{
  const float* x      = (const float*)d_in[0];
  const float* W_in   = (const float*)d_in[1];
  const float* b_in   = (const float*)d_in[2];
  const float* ipW    = (const float*)d_in[3];
  const float* ipb    = (const float*)d_in[4];
  const float* A_log  = (const float*)d_in[5];
  const float* Dp     = (const float*)d_in[6];
  const float* dtb    = (const float*)d_in[7];
  const float* opW    = (const float*)d_in[8];
  const float* opb    = (const float*)d_in[9];
  const float* clsW   = (const float*)d_in[10];
  const float* clsb   = (const float*)d_in[11];
  float* out = (float*)d_out;
  (void)d_ws; (void)ws_size;

  k_wprep<<<dim3(NT21, NLAY), 128, 0, stream>>>(ipW);
  k_wprep2<<<dim3(16, NLAY), 64, 0, stream>>>(opW);
  k_linin<<<2048, 256, 0, stream>>>(x, W_in, b_in);
  for (int l = 0; l < NLAY; ++l){
    k_proj<<<1024, 256, 0, stream>>>(ipb, dtb, l);
    k_s1<<<dim3(NCH, BSZ), 256, 0, stream>>>(A_log, Dp, l);
    k_s2<<<dim3(32, BSZ), 128, 0, stream>>>();
    k_s3<<<dim3(NCH, BSZ), 256, 0, stream>>>(opb, l, (l == NLAY-1) ? 1 : 0);
  }
  k_pool2<<<BSZ, 64, 0, stream>>>(clsW, clsb, out);
}

// Round 12
// 393.045 us; speedup vs baseline: 14.6093x; 1.0522x over previous
//
#include <hip/hip_runtime.h>

#define BSZ   16
#define LSEQ  8192
#define DMDL  64
#define DSD   32
#define HDD   32
#define NHD   4
#define DIN   128
#define NLAY  2
#define NOUTC 6
#define DPRJ  324
#define QC    64
#define NCH   128   // LSEQ/QC
#define NT21  21    // 21 column tiles of 16 (320 proj cols + 4 dt cols zero-padded)

typedef __attribute__((ext_vector_type(8))) short bf16x8;
typedef __attribute__((ext_vector_type(4))) float f32x4;

// ---- device-global scratch ----
__device__ float          g_h0[BSZ*LSEQ*DMDL];
__device__ unsigned short g_za[BSZ*LSEQ*DIN];   // RAW z, bf16 (silu applied once, in k_s3)
__device__ unsigned short g_xy[BSZ*LSEQ*DIN];   // silu(x), overwritten by y_intra (bf16)
__device__ unsigned short g_Ba[BSZ*LSEQ*DSD];   // silu(B), bf16
__device__ unsigned short g_Ca[BSZ*LSEQ*DSD];   // silu(C), bf16
__device__ float          g_dt[BSZ*LSEQ*NHD];
__device__ float          g_pc[BSZ*LSEQ*NHD];
__device__ float          g_cS[BSZ*NCH*NHD*HDD*DSD]; // chunk states, scanned in-place -> H_in
__device__ float          g_cL[BSZ*NCH*NHD];
__device__ float          g_ppc[BSZ*NCH*DMDL];       // per-chunk column sums (final layer)
__device__ unsigned short g_wf[NLAY*NT21*2*64*8];    // in_proj W, bf16 MFMA B-fragment layout
__device__ unsigned short g_wo[NLAY*4*4*64*8];       // out_proj W, bf16 MFMA B-fragment layout

__device__ __forceinline__ float silu_f(float v){ return v / (1.0f + __expf(-v)); }
__device__ __forceinline__ float softplus_f(float v){ return (v > 15.0f) ? v : __logf(1.0f + __expf(v)); }
__device__ __forceinline__ unsigned short f2bf(float f){
  union { float f; unsigned u; } v; v.f = f;
  unsigned r = v.u + 0x7FFFu + ((v.u >> 16) & 1u);
  return (unsigned short)(r >> 16);
}
__device__ __forceinline__ float bf2f(unsigned short h){
  union { unsigned u; float f; } v; v.u = ((unsigned)h) << 16;
  return v.f;
}

// ---------------- linear_in ----------------
__global__ __launch_bounds__(256) void k_linin(
    const float* __restrict__ x, const float* __restrict__ W,
    const float* __restrict__ bias)
{
  __shared__ float xs[64*60];
  __shared__ float wl[57*64];
  const int tid = threadIdx.x;
  const long tb = (long)blockIdx.x * 64;
  for (int i = tid; i < 64*57; i += 256){
    int t = i / 57, k = i - t*57;
    xs[t*60 + k] = x[tb*57 + i];
  }
  for (int i = tid; i < 57*64; i += 256) wl[i] = W[i];
  __syncthreads();
  const int t0 = (tid >> 4) * 4, d0 = (tid & 15) * 4;
  float acc[4][4];
  #pragma unroll
  for (int i = 0; i < 4; ++i)
    #pragma unroll
    for (int j = 0; j < 4; ++j) acc[i][j] = 0.f;
  for (int k = 0; k < 57; ++k){
    float4 w4 = *(const float4*)&wl[k*64 + d0];
    float wv[4] = {w4.x, w4.y, w4.z, w4.w};
    #pragma unroll
    for (int i = 0; i < 4; ++i){
      float xv = xs[(t0+i)*60 + k];
      #pragma unroll
      for (int j = 0; j < 4; ++j) acc[i][j] += xv * wv[j];
    }
  }
  float4 b4 = *(const float4*)&bias[d0];
  float bv[4] = {b4.x, b4.y, b4.z, b4.w};
  #pragma unroll
  for (int i = 0; i < 4; ++i){
    float4 o;
    o.x = acc[i][0] + bv[0]; o.y = acc[i][1] + bv[1];
    o.z = acc[i][2] + bv[2]; o.w = acc[i][3] + bv[3];
    *(float4*)&g_h0[(tb + t0 + i)*64 + d0] = o;
  }
}

// ---------------- weight prep: ipW -> bf16 B-fragment layout ----------------
__global__ __launch_bounds__(128) void k_wprep(const float* __restrict__ W)
{
  const int nt = blockIdx.x;            // 0..20
  const int l  = blockIdx.y;            // layer
  const int ks = threadIdx.x >> 6, lane = threadIdx.x & 63;
  const float* Wl = W + (long)l*64*DPRJ;
  const int n  = nt*16 + (lane & 15);
  const int k0 = ks*32 + (lane >> 4)*8;
  unsigned short v[8];
  #pragma unroll
  for (int j = 0; j < 8; ++j)
    v[j] = (n < DPRJ) ? f2bf(Wl[(k0 + j)*DPRJ + n]) : (unsigned short)0;
  unsigned short* d = &g_wf[((((long)l*NT21 + nt)*2 + ks)*64 + lane)*8];
  *(ushort4*)&d[0] = make_ushort4(v[0], v[1], v[2], v[3]);
  *(ushort4*)&d[4] = make_ushort4(v[4], v[5], v[6], v[7]);
}

// ---------------- weight prep: out_proj W -> bf16 B-fragment layout ----------------
__global__ __launch_bounds__(64) void k_wprep2(const float* __restrict__ Wo)
{
  const int nt = blockIdx.x >> 2, ks = blockIdx.x & 3, l = blockIdx.y;
  const int lane = threadIdx.x;
  const int n  = nt*16 + (lane & 15);
  const int k0 = ks*32 + (lane >> 4)*8;
  const float* Wl = Wo + (long)l*128*64;
  unsigned short* d = &g_wo[((((long)l*4 + nt)*4 + ks)*64 + lane)*8];
  unsigned short v[8];
  #pragma unroll
  for (int j = 0; j < 8; ++j) v[j] = f2bf(Wl[(k0 + j)*64 + n]);
  *(ushort4*)&d[0] = make_ushort4(v[0], v[1], v[2], v[3]);
  *(ushort4*)&d[4] = make_ushort4(v[4], v[5], v[6], v[7]);
}

// ---------------- in_proj via MFMA, LDS-staged coalesced outputs ----------------
#define OP 136   // Obuf row stride (ushorts); 136*2=272B: 16B-aligned rows, rowq bank shift 16
__global__ __launch_bounds__(256) void k_proj(
    const float* __restrict__ bias, const float* __restrict__ dt_bias, int l)
{
  __shared__ __align__(16) unsigned short Afr[8*2*64*8];  // A fragments, 16 KB
  __shared__ __align__(16) unsigned short Obuf[128*OP];   // output staging, 34.8 KB
  const int tid = threadIdx.x;
  const long tb = (long)blockIdx.x * 128;
  #pragma unroll
  for (int r = 0; r < 4; ++r){
    const int c = tid + 256*r;
    const int t = c >> 3, k8 = c & 7;
    float4 f0 = *(const float4*)&g_h0[(tb + t)*64 + k8*8];
    float4 f1 = *(const float4*)&g_h0[(tb + t)*64 + k8*8 + 4];
    const int mt = t >> 4, ks = k8 >> 2, q = k8 & 3, ln = (t & 15) + 16*q;
    unsigned short* d = &Afr[(((mt*2 + ks)*64) + ln)*8];
    *(ushort4*)&d[0] = make_ushort4(f2bf(f0.x), f2bf(f0.y), f2bf(f0.z), f2bf(f0.w));
    *(ushort4*)&d[4] = make_ushort4(f2bf(f1.x), f2bf(f1.y), f2bf(f1.z), f2bf(f1.w));
  }
  __syncthreads();
  const int w = tid >> 6, lane = tid & 63;
  const int colq = lane & 15, rowq = lane >> 4;
  bf16x8 a[2][2];
  #pragma unroll
  for (int m = 0; m < 2; ++m)
    #pragma unroll
    for (int ks = 0; ks < 2; ++ks)
      a[m][ks] = *(const bf16x8*)&Afr[((((2*w + m)*2 + ks)*64) + lane)*8];
  const float* bl = bias + (long)l*DPRJ;
  const unsigned short* wf = &g_wf[(long)l*NT21*2*64*8];
  // ---- group 0: z (raw), group 1: x (silu) -> Obuf -> coalesced 16B stores ----
  for (int g = 0; g < 2; ++g){
    #pragma unroll
    for (int nti = 0; nti < 8; ++nti){
      const int nt = g*8 + nti;
      bf16x8 b0 = *(const bf16x8*)&wf[((nt*2 + 0)*64 + lane)*8];
      bf16x8 b1 = *(const bf16x8*)&wf[((nt*2 + 1)*64 + lane)*8];
      const float b = bl[nt*16 + colq];
      #pragma unroll
      for (int m = 0; m < 2; ++m){
        f32x4 acc = {0.f, 0.f, 0.f, 0.f};
        acc = __builtin_amdgcn_mfma_f32_16x16x32_bf16(a[m][0], b0, acc, 0, 0, 0);
        acc = __builtin_amdgcn_mfma_f32_16x16x32_bf16(a[m][1], b1, acc, 0, 0, 0);
        const int tbase = (2*w + m)*16 + rowq*4;
        const int ocol = nti*16 + colq;
        #pragma unroll
        for (int r = 0; r < 4; ++r){
          const float v = acc[r] + b;
          Obuf[(tbase + r)*OP + ocol] = f2bf(g ? silu_f(v) : v);
        }
      }
    }
    __syncthreads();
    unsigned short* dst = g ? g_xy : g_za;
    #pragma unroll
    for (int it = 0; it < 8; ++it){
      const int i = tid + 256*it;            // 2048 chunks of 16B
      const int t = i >> 4, c0 = (i & 15) * 8;
      *(uint4*)&dst[(tb + t)*128 + c0] = *(const uint4*)&Obuf[t*OP + c0];
    }
    __syncthreads();
  }
  // ---- B (nt16,17 -> Obuf cols 0..31), C (nt18,19 -> cols 32..63), both silu ----
  #pragma unroll
  for (int nti = 0; nti < 4; ++nti){
    const int nt = 16 + nti;
    bf16x8 b0 = *(const bf16x8*)&wf[((nt*2 + 0)*64 + lane)*8];
    bf16x8 b1 = *(const bf16x8*)&wf[((nt*2 + 1)*64 + lane)*8];
    const float b = bl[nt*16 + colq];
    #pragma unroll
    for (int m = 0; m < 2; ++m){
      f32x4 acc = {0.f, 0.f, 0.f, 0.f};
      acc = __builtin_amdgcn_mfma_f32_16x16x32_bf16(a[m][0], b0, acc, 0, 0, 0);
      acc = __builtin_amdgcn_mfma_f32_16x16x32_bf16(a[m][1], b1, acc, 0, 0, 0);
      const int tbase = (2*w + m)*16 + rowq*4;
      const int ocol = nti*16 + colq;       // 0..63 = B|C
      #pragma unroll
      for (int r = 0; r < 4; ++r)
        Obuf[(tbase + r)*OP + ocol] = f2bf(silu_f(acc[r] + b));
    }
  }
  // ---- dt (nt 20, cols 320..323) direct (2 MB total, negligible) ----
  {
    bf16x8 b0 = *(const bf16x8*)&wf[((20*2 + 0)*64 + lane)*8];
    bf16x8 b1 = *(const bf16x8*)&wf[((20*2 + 1)*64 + lane)*8];
    #pragma unroll
    for (int m = 0; m < 2; ++m){
      f32x4 acc = {0.f, 0.f, 0.f, 0.f};
      acc = __builtin_amdgcn_mfma_f32_16x16x32_bf16(a[m][0], b0, acc, 0, 0, 0);
      acc = __builtin_amdgcn_mfma_f32_16x16x32_bf16(a[m][1], b1, acc, 0, 0, 0);
      if (colq < 4){
        const int tbase = (2*w + m)*16 + rowq*4;
        const float b = bl[320 + colq] + dt_bias[l*4 + colq];
        #pragma unroll
        for (int r = 0; r < 4; ++r)
          g_dt[(tb + tbase + r)*4 + colq] = softplus_f(acc[r] + b);
      }
    }
  }
  __syncthreads();
  #pragma unroll
  for (int it = 0; it < 4; ++it){
    const int i = tid + 256*it;              // 1024 chunks of 16B: 4 Ba + 4 Ca per row
    const int t = i >> 3, k = i & 7;
    const int c0 = (k & 3) * 8;
    if (k < 4){
      *(uint4*)&g_Ba[(tb + t)*32 + c0] = *(const uint4*)&Obuf[t*OP + c0];
    } else {
      *(uint4*)&g_Ca[(tb + t)*32 + c0] = *(const uint4*)&Obuf[t*OP + 32 + c0];
    }
  }
}

// ---------------- chunk intra: all-MFMA (G, y_intra, chunkS) ----------------
#define SB 40   // Bb/Cb row stride (ushorts)
#define ST 72   // Mb/Xt/Xwt/Bbt row stride (ushorts)
__global__ __launch_bounds__(256) void k_s1(
    const float* __restrict__ A_log, const float* __restrict__ Dp, int l)
{
  __shared__ __align__(16) unsigned short u_bc[2*64*SB]; // Bb[64][SB]+Cb[64][SB]; later Xt[32][ST]+Xwt[32][ST]
  __shared__ __align__(16) unsigned short Bbt[32*ST];    // B transposed [n][s]
  __shared__ __align__(16) unsigned short Mb[64*ST];     // per-head decay-scaled M [t][s]
  __shared__ float Sl[4*64];
  __shared__ float dts[4*64];
  __shared__ float wls[4*64];
  const int tid = threadIdx.x;
  const int cI = blockIdx.x, b = blockIdx.y;
  const long tb = (long)b*LSEQ + (long)cI*QC;
  unsigned short* Bb = u_bc;
  unsigned short* Cb = u_bc + 64*SB;
  for (int i = tid; i < 512; i += 256){
    const int s = i >> 3, n0 = (i & 7) * 4;
    ushort4 bu = *(const ushort4*)&g_Ba[(tb + s)*32 + n0];
    ushort4 cu = *(const ushort4*)&g_Ca[(tb + s)*32 + n0];
    *(ushort4*)&Bb[s*SB + n0] = bu;
    *(ushort4*)&Cb[s*SB + n0] = cu;
    Bbt[(n0    )*ST + s] = bu.x;
    Bbt[(n0 + 1)*ST + s] = bu.y;
    Bbt[(n0 + 2)*ST + s] = bu.z;
    Bbt[(n0 + 3)*ST + s] = bu.w;
  }
  // ---- wave-parallel scan: wave = head, lane = token ----
  {
    const int h = tid >> 6, t = tid & 63;
    const float Ah = -__expf(A_log[l*4 + h]);
    const float v = g_dt[(tb + t)*4 + h];
    float x = v * Ah;
    #pragma unroll
    for (int d = 1; d < 64; d <<= 1){
      float y = __shfl_up(x, d);
      if (t >= d) x += y;
    }
    Sl[h*64 + t] = x;
    dts[h*64 + t] = v;
    const float send = __shfl(x, 63);
    wls[h*64 + t] = __expf(send - x) * v;
    if (t == 63) g_cL[((long)b*NCH + cI)*4 + h] = x;
    g_pc[(tb + t)*4 + h] = __expf(x);
  }
  __syncthreads();
  const int w = tid >> 6, lane = tid & 63;
  const int colq = lane & 15, rowq = lane >> 4;
  // ---- G = C . B^T via MFMA: 10 lower-triangle tiles round-robin over waves ----
  float Greg[3][4];
  int Gmt[3], Gst[3];
  #pragma unroll
  for (int rep = 0; rep < 3; ++rep){
    const int k = w + rep*4;
    if (k < 10){
      const int mt = (k >= 6) ? 3 : ((k >= 3) ? 2 : ((k >= 1) ? 1 : 0));
      const int st = k - mt*(mt+1)/2;
      Gmt[rep] = mt; Gst[rep] = st;
      bf16x8 af = *(const bf16x8*)&Cb[(mt*16 + colq)*SB + rowq*8];
      bf16x8 bf = *(const bf16x8*)&Bb[(st*16 + colq)*SB + rowq*8];
      f32x4 acc = {0.f, 0.f, 0.f, 0.f};
      acc = __builtin_amdgcn_mfma_f32_16x16x32_bf16(af, bf, acc, 0, 0, 0);
      #pragma unroll
      for (int r = 0; r < 4; ++r) Greg[rep][r] = acc[r];
    } else { Gmt[rep] = -1; Gst[rep] = 0; }
  }
  #pragma unroll
  for (int rep = 0; rep < 2; ++rep){
    const int k = w + rep*4;
    if (k < 6){
      const int mt = (k < 3) ? 0 : ((k < 5) ? 1 : 2);
      const int st = (k < 3) ? (k + 1) : ((k < 5) ? (k - 1) : 3);
      #pragma unroll
      for (int r = 0; r < 4; ++r)
        Mb[(mt*16 + rowq*4 + r)*ST + st*16 + colq] = 0;
    }
  }
  unsigned short* Xt  = u_bc;             // alias: Bb/Cb dead after G
  unsigned short* Xwt = u_bc + 32*ST;
  for (int h = 0; h < NHD; ++h){
    __syncthreads();
    for (int i = tid; i < 512; i += 256){
      const int s = i >> 3, p0 = (i & 7) * 4;
      ushort4 u = *(const ushort4*)&g_xy[(tb + s)*128 + h*32 + p0];
      const float wv = wls[h*64 + s];
      Xt[(p0    )*ST + s] = u.x;  Xwt[(p0    )*ST + s] = f2bf(wv * bf2f(u.x));
      Xt[(p0 + 1)*ST + s] = u.y;  Xwt[(p0 + 1)*ST + s] = f2bf(wv * bf2f(u.y));
      Xt[(p0 + 2)*ST + s] = u.z;  Xwt[(p0 + 2)*ST + s] = f2bf(wv * bf2f(u.z));
      Xt[(p0 + 3)*ST + s] = u.w;  Xwt[(p0 + 3)*ST + s] = f2bf(wv * bf2f(u.w));
    }
    #pragma unroll
    for (int rep = 0; rep < 3; ++rep){
      if (Gmt[rep] >= 0){
        const int mt = Gmt[rep], st = Gst[rep];
        const int s = st*16 + colq;
        const float sls = Sl[h*64 + s];
        const float dv = dts[h*64 + s];
        #pragma unroll
        for (int r = 0; r < 4; ++r){
          const int t = mt*16 + rowq*4 + r;
          const float m = (s <= t) ? __expf(Sl[h*64 + t] - sls) * dv * Greg[rep][r] : 0.f;
          Mb[t*ST + s] = f2bf(m);
        }
      }
    }
    __syncthreads();
    const float Dh = Dp[l*4 + h];
    {
      bf16x8 a0 = *(const bf16x8*)&Mb[(w*16 + colq)*ST + rowq*8];
      bf16x8 a1 = *(const bf16x8*)&Mb[(w*16 + colq)*ST + 32 + rowq*8];
      #pragma unroll
      for (int nt = 0; nt < 2; ++nt){
        bf16x8 b0 = *(const bf16x8*)&Xt[(nt*16 + colq)*ST + rowq*8];
        bf16x8 b1 = *(const bf16x8*)&Xt[(nt*16 + colq)*ST + 32 + rowq*8];
        f32x4 acc = {0.f, 0.f, 0.f, 0.f};
        acc = __builtin_amdgcn_mfma_f32_16x16x32_bf16(a0, b0, acc, 0, 0, 0);
        acc = __builtin_amdgcn_mfma_f32_16x16x32_bf16(a1, b1, acc, 0, 0, 0);
        const int p = nt*16 + colq;
        #pragma unroll
        for (int r = 0; r < 4; ++r){
          const int t = w*16 + rowq*4 + r;
          const float xv = bf2f(Xt[p*ST + t]);
          g_xy[(tb + t)*128 + h*32 + p] = f2bf(acc[r] + Dh*xv);
        }
      }
    }
    {
      const int mt = w & 1, nt = w >> 1;
      bf16x8 a0 = *(const bf16x8*)&Xwt[(mt*16 + colq)*ST + rowq*8];
      bf16x8 a1 = *(const bf16x8*)&Xwt[(mt*16 + colq)*ST + 32 + rowq*8];
      bf16x8 b0 = *(const bf16x8*)&Bbt[(nt*16 + colq)*ST + rowq*8];
      bf16x8 b1 = *(const bf16x8*)&Bbt[(nt*16 + colq)*ST + 32 + rowq*8];
      f32x4 acc = {0.f, 0.f, 0.f, 0.f};
      acc = __builtin_amdgcn_mfma_f32_16x16x32_bf16(a0, b0, acc, 0, 0, 0);
      acc = __builtin_amdgcn_mfma_f32_16x16x32_bf16(a1, b1, acc, 0, 0, 0);
      const long base = (((long)b*NCH + cI)*NHD + h)*(HDD*DSD);
      const int n = nt*16 + colq;
      #pragma unroll
      for (int r = 0; r < 4; ++r){
        const int p = mt*16 + rowq*4 + r;
        g_cS[base + p*32 + n] = acc[r];
      }
    }
  }
}

// ---------------- cross-chunk state prefix scan (in place) ----------------
__global__ __launch_bounds__(128) void k_s2()
{
  const int h = blockIdx.x >> 3, seg = blockIdx.x & 7, b = blockIdx.y;
  const int idx = seg*128 + threadIdx.x;
  float H = 0.f;
  for (int c = 0; c < NCH; ++c){
    const long o = (((long)b*NCH + c)*NHD + h)*1024 + idx;
    const float cs = g_cS[o];
    const float lg = g_cL[((long)b*NCH + c)*4 + h];
    g_cS[o] = H;
    H = __expf(lg) * H + cs;
  }
}

// ---------------- y_inter + gate + out_proj + residual (+ pool), all-MFMA ----------------
__global__ __launch_bounds__(256) void k_s3(
    const float* __restrict__ bo, int l, int finalLayer)
{
  __shared__ __align__(16) unsigned short Hb[128*40];  // H_in bf16 [hp][n]
  __shared__ __align__(16) unsigned short Cb[64*40];   // C bf16 [t][n]
  __shared__ __align__(16) unsigned short gl[64*136];  // gated y bf16 [t][hp]
  __shared__ float pcl[4*64];
  __shared__ float csum[4*64];
  const int tid = threadIdx.x;
  const int cI = blockIdx.x, b = blockIdx.y;
  const long tb = (long)b*LSEQ + (long)cI*QC;
  const long hbase = (((long)b*NCH + cI)*NHD)*(long)(HDD*DSD);
  for (int i = tid; i < 1024; i += 256){
    const int hp = i >> 2, n0 = (i & 3) * 8;
    float4 f0 = *(const float4*)&g_cS[hbase + hp*32 + n0];
    float4 f1 = *(const float4*)&g_cS[hbase + hp*32 + n0 + 4];
    *(ushort4*)&Hb[hp*40 + n0]     = make_ushort4(f2bf(f0.x), f2bf(f0.y), f2bf(f0.z), f2bf(f0.w));
    *(ushort4*)&Hb[hp*40 + n0 + 4] = make_ushort4(f2bf(f1.x), f2bf(f1.y), f2bf(f1.z), f2bf(f1.w));
  }
  for (int i = tid; i < 512; i += 256){
    const int t = i >> 3, n0 = (i & 7) * 4;
    *(ushort4*)&Cb[t*40 + n0] = *(const ushort4*)&g_Ca[(tb + t)*32 + n0];
  }
  { int t = tid >> 2, h = tid & 3; pcl[h*64 + t] = g_pc[(tb + t)*4 + h]; }
  __syncthreads();
  const int w = tid >> 6, lane = tid & 63;
  const int colq = lane & 15, rowq = lane >> 4;
  // ---- phase 1: y_inter = C @ H^T (MFMA), gate with silu(z), -> gl ----
  {
    bf16x8 a = *(const bf16x8*)&Cb[(w*16 + colq)*40 + rowq*8];
    #pragma unroll
    for (int nt = 0; nt < 8; ++nt){
      bf16x8 bfr = *(const bf16x8*)&Hb[(nt*16 + colq)*40 + rowq*8];
      f32x4 acc = {0.f, 0.f, 0.f, 0.f};
      acc = __builtin_amdgcn_mfma_f32_16x16x32_bf16(a, bfr, acc, 0, 0, 0);
      const int hp = nt*16 + colq;
      const int h = hp >> 5;
      #pragma unroll
      for (int r = 0; r < 4; ++r){
        const int t = w*16 + rowq*4 + r;
        const long tok = tb + t;
        const float v = pcl[h*64 + t] * acc[r] + bf2f(g_xy[tok*128 + hp]);
        gl[t*136 + hp] = f2bf(v * silu_f(bf2f(g_za[tok*128 + hp])));
      }
    }
  }
  __syncthreads();
  // ---- phase 2: out = gl @ Wo (MFMA) + bias + residual, colsum for pool ----
  const unsigned short* wo = &g_wo[(long)l*4*4*512];
  #pragma unroll
  for (int nt2 = 0; nt2 < 4; ++nt2){
    f32x4 acc = {0.f, 0.f, 0.f, 0.f};
    #pragma unroll
    for (int ks = 0; ks < 4; ++ks){
      bf16x8 a = *(const bf16x8*)&gl[(w*16 + colq)*136 + ks*32 + rowq*8];
      bf16x8 bfr = *(const bf16x8*)&wo[(nt2*4 + ks)*512 + lane*8];
      acc = __builtin_amdgcn_mfma_f32_16x16x32_bf16(a, bfr, acc, 0, 0, 0);
    }
    const int dm = nt2*16 + colq;
    const float bb = bo[l*64 + dm];
    float part = 0.f;
    #pragma unroll
    for (int r = 0; r < 4; ++r){
      const int t = w*16 + rowq*4 + r;
      const long tok = tb + t;
      const float o = acc[r] + bb + g_h0[tok*64 + dm];
      g_h0[tok*64 + dm] = o;
      part += o;
    }
    if (finalLayer){
      part += __shfl_xor(part, 16);
      part += __shfl_xor(part, 32);
      if (rowq == 0) csum[w*64 + dm] = part;
    }
  }
  if (finalLayer){
    __syncthreads();
    if (tid < 64){
      g_ppc[((long)b*NCH + cI)*64 + tid] =
        csum[tid] + csum[64 + tid] + csum[128 + tid] + csum[192 + tid];
    }
  }
}

// ---------------- pooling + classifier ----------------
__global__ __launch_bounds__(64) void k_pool2(
    const float* __restrict__ cW, const float* __restrict__ cb,
    float* __restrict__ out)
{
  __shared__ float pl[64];
  const int b = blockIdx.x, tid = threadIdx.x;
  float s = 0.f;
  for (int c = 0; c < NCH; ++c) s += g_ppc[((long)b*NCH + c)*64 + tid];
  pl[tid] = s * (1.0f / 8192.0f);
  __syncthreads();
  if (tid < NOUTC){
    float acc = cb[tid];
    for (int dm = 0; dm < 64; ++dm) acc += pl[dm] * cW[dm*NOUTC + tid];
    out[b*NOUTC + tid] = acc;
  }
}

extern "C" void kernel_launch(void* const* d_in, const int* in_sizes, int n_in,
                              void* d_out, int out_size, void* d_ws, size_t ws_size,
                              hipStream_t stream)
{
  const float* x      = (const float*)d_in[0];
  const float* W_in   = (const float*)d_in[1];
  const float* b_in   = (const float*)d_in[2];
  const float* ipW    = (const float*)d_in[3];
  const float* ipb    = (const float*)d_in[4];
  const float* A_log  = (const float*)d_in[5];
  const float* Dp     = (const float*)d_in[6];
  const float* dtb    = (const float*)d_in[7];
  const float* opW    = (const float*)d_in[8];
  const float* opb    = (const float*)d_in[9];
  const float* clsW   = (const float*)d_in[10];
  const float* clsb   = (const float*)d_in[11];
  float* out = (float*)d_out;
  (void)d_ws; (void)ws_size;

  k_wprep<<<dim3(NT21, NLAY), 128, 0, stream>>>(ipW);
  k_wprep2<<<dim3(16, NLAY), 64, 0, stream>>>(opW);
  k_linin<<<2048, 256, 0, stream>>>(x, W_in, b_in);
  for (int l = 0; l < NLAY; ++l){
    k_proj<<<1024, 256, 0, stream>>>(ipb, dtb, l);
    k_s1<<<dim3(NCH, BSZ), 256, 0, stream>>>(A_log, Dp, l);
    k_s2<<<dim3(32, BSZ), 128, 0, stream>>>();
    k_s3<<<dim3(NCH, BSZ), 256, 0, stream>>>(opb, l, (l == NLAY-1) ? 1 : 0);
  }
  k_pool2<<<BSZ, 64, 0, stream>>>(clsW, clsb, out);
}

// Round 13
// 361.949 us; speedup vs baseline: 15.8645x; 1.0859x over previous
//
#include <hip/hip_runtime.h>

#define BSZ   16
#define LSEQ  8192
#define DMDL  64
#define DSD   32
#define HDD   32
#define NHD   4
#define DIN   128
#define NLAY  2
#define NOUTC 6
#define DPRJ  324
#define QC    64
#define NCH   128   // LSEQ/QC
#define NT21  21    // 21 column tiles of 16 (320 proj cols + 4 dt cols zero-padded)

typedef __attribute__((ext_vector_type(8))) short bf16x8;
typedef __attribute__((ext_vector_type(4))) float f32x4;

// ---- device-global scratch ----
__device__ float          g_h0[BSZ*LSEQ*DMDL];
__device__ unsigned short g_xy[BSZ*LSEQ*DIN];   // silu(x), overwritten by y_intra (bf16)
__device__ unsigned short g_Ba[BSZ*LSEQ*DSD];   // silu(B), bf16
__device__ unsigned short g_Ca[BSZ*LSEQ*DSD];   // silu(C), bf16
__device__ float          g_dt[BSZ*LSEQ*NHD];
__device__ float          g_pc[BSZ*LSEQ*NHD];
__device__ float          g_cS[BSZ*NCH*NHD*HDD*DSD]; // chunk states, scanned in-place -> H_in
__device__ float          g_cL[BSZ*NCH*NHD];
__device__ float          g_ppc[BSZ*NCH*DMDL];       // per-chunk column sums (final layer)
__device__ unsigned short g_wf[NLAY*NT21*2*64*8];    // in_proj W, bf16 MFMA B-fragment layout
__device__ unsigned short g_wo[NLAY*4*4*64*8];       // out_proj W, bf16 MFMA B-fragment layout

__device__ __forceinline__ float silu_f(float v){ return v / (1.0f + __expf(-v)); }
__device__ __forceinline__ float softplus_f(float v){ return (v > 15.0f) ? v : __logf(1.0f + __expf(v)); }
__device__ __forceinline__ unsigned short f2bf(float f){
  union { float f; unsigned u; } v; v.f = f;
  unsigned r = v.u + 0x7FFFu + ((v.u >> 16) & 1u);
  return (unsigned short)(r >> 16);
}
__device__ __forceinline__ float bf2f(unsigned short h){
  union { unsigned u; float f; } v; v.u = ((unsigned)h) << 16;
  return v.f;
}

// ---------------- linear_in ----------------
__global__ __launch_bounds__(256) void k_linin(
    const float* __restrict__ x, const float* __restrict__ W,
    const float* __restrict__ bias)
{
  __shared__ float xs[64*60];
  __shared__ float wl[57*64];
  const int tid = threadIdx.x;
  const long tb = (long)blockIdx.x * 64;
  for (int i = tid; i < 64*57; i += 256){
    int t = i / 57, k = i - t*57;
    xs[t*60 + k] = x[tb*57 + i];
  }
  for (int i = tid; i < 57*64; i += 256) wl[i] = W[i];
  __syncthreads();
  const int t0 = (tid >> 4) * 4, d0 = (tid & 15) * 4;
  float acc[4][4];
  #pragma unroll
  for (int i = 0; i < 4; ++i)
    #pragma unroll
    for (int j = 0; j < 4; ++j) acc[i][j] = 0.f;
  for (int k = 0; k < 57; ++k){
    float4 w4 = *(const float4*)&wl[k*64 + d0];
    float wv[4] = {w4.x, w4.y, w4.z, w4.w};
    #pragma unroll
    for (int i = 0; i < 4; ++i){
      float xv = xs[(t0+i)*60 + k];
      #pragma unroll
      for (int j = 0; j < 4; ++j) acc[i][j] += xv * wv[j];
    }
  }
  float4 b4 = *(const float4*)&bias[d0];
  float bv[4] = {b4.x, b4.y, b4.z, b4.w};
  #pragma unroll
  for (int i = 0; i < 4; ++i){
    float4 o;
    o.x = acc[i][0] + bv[0]; o.y = acc[i][1] + bv[1];
    o.z = acc[i][2] + bv[2]; o.w = acc[i][3] + bv[3];
    *(float4*)&g_h0[(tb + t0 + i)*64 + d0] = o;
  }
}

// ---------------- weight prep: ipW -> bf16 B-fragment layout ----------------
__global__ __launch_bounds__(128) void k_wprep(const float* __restrict__ W)
{
  const int nt = blockIdx.x;            // 0..20
  const int l  = blockIdx.y;            // layer
  const int ks = threadIdx.x >> 6, lane = threadIdx.x & 63;
  const float* Wl = W + (long)l*64*DPRJ;
  const int n  = nt*16 + (lane & 15);
  const int k0 = ks*32 + (lane >> 4)*8;
  unsigned short v[8];
  #pragma unroll
  for (int j = 0; j < 8; ++j)
    v[j] = (n < DPRJ) ? f2bf(Wl[(k0 + j)*DPRJ + n]) : (unsigned short)0;
  unsigned short* d = &g_wf[((((long)l*NT21 + nt)*2 + ks)*64 + lane)*8];
  *(ushort4*)&d[0] = make_ushort4(v[0], v[1], v[2], v[3]);
  *(ushort4*)&d[4] = make_ushort4(v[4], v[5], v[6], v[7]);
}

// ---------------- weight prep: out_proj W -> bf16 B-fragment layout ----------------
__global__ __launch_bounds__(64) void k_wprep2(const float* __restrict__ Wo)
{
  const int nt = blockIdx.x >> 2, ks = blockIdx.x & 3, l = blockIdx.y;
  const int lane = threadIdx.x;
  const int n  = nt*16 + (lane & 15);
  const int k0 = ks*32 + (lane >> 4)*8;
  const float* Wl = Wo + (long)l*128*64;
  unsigned short* d = &g_wo[((((long)l*4 + nt)*4 + ks)*64 + lane)*8];
  unsigned short v[8];
  #pragma unroll
  for (int j = 0; j < 8; ++j) v[j] = f2bf(Wl[(k0 + j)*64 + n]);
  *(ushort4*)&d[0] = make_ushort4(v[0], v[1], v[2], v[3]);
  *(ushort4*)&d[4] = make_ushort4(v[4], v[5], v[6], v[7]);
}

// ---------------- in_proj via MFMA (x/B/C/dt only; z computed in k_s3) ----------------
#define OP 136   // Obuf row stride (ushorts)
__global__ __launch_bounds__(256) void k_proj(
    const float* __restrict__ bias, const float* __restrict__ dt_bias, int l)
{
  __shared__ __align__(16) unsigned short Afr[8*2*64*8];  // A fragments, 16 KB
  __shared__ __align__(16) unsigned short Obuf[128*OP];   // output staging, 34.8 KB
  const int tid = threadIdx.x;
  const long tb = (long)blockIdx.x * 128;
  #pragma unroll
  for (int r = 0; r < 4; ++r){
    const int c = tid + 256*r;
    const int t = c >> 3, k8 = c & 7;
    float4 f0 = *(const float4*)&g_h0[(tb + t)*64 + k8*8];
    float4 f1 = *(const float4*)&g_h0[(tb + t)*64 + k8*8 + 4];
    const int mt = t >> 4, ks = k8 >> 2, q = k8 & 3, ln = (t & 15) + 16*q;
    unsigned short* d = &Afr[(((mt*2 + ks)*64) + ln)*8];
    *(ushort4*)&d[0] = make_ushort4(f2bf(f0.x), f2bf(f0.y), f2bf(f0.z), f2bf(f0.w));
    *(ushort4*)&d[4] = make_ushort4(f2bf(f1.x), f2bf(f1.y), f2bf(f1.z), f2bf(f1.w));
  }
  __syncthreads();
  const int w = tid >> 6, lane = tid & 63;
  const int colq = lane & 15, rowq = lane >> 4;
  bf16x8 a[2][2];
  #pragma unroll
  for (int m = 0; m < 2; ++m)
    #pragma unroll
    for (int ks = 0; ks < 2; ++ks)
      a[m][ks] = *(const bf16x8*)&Afr[((((2*w + m)*2 + ks)*64) + lane)*8];
  const float* bl = bias + (long)l*DPRJ;
  const unsigned short* wf = &g_wf[(long)l*NT21*2*64*8];
  // ---- x tiles (nt 8..15, silu) -> Obuf -> coalesced 16B stores ----
  #pragma unroll
  for (int nti = 0; nti < 8; ++nti){
    const int nt = 8 + nti;
    bf16x8 b0 = *(const bf16x8*)&wf[((nt*2 + 0)*64 + lane)*8];
    bf16x8 b1 = *(const bf16x8*)&wf[((nt*2 + 1)*64 + lane)*8];
    const float b = bl[nt*16 + colq];
    #pragma unroll
    for (int m = 0; m < 2; ++m){
      f32x4 acc = {0.f, 0.f, 0.f, 0.f};
      acc = __builtin_amdgcn_mfma_f32_16x16x32_bf16(a[m][0], b0, acc, 0, 0, 0);
      acc = __builtin_amdgcn_mfma_f32_16x16x32_bf16(a[m][1], b1, acc, 0, 0, 0);
      const int tbase = (2*w + m)*16 + rowq*4;
      const int ocol = nti*16 + colq;
      #pragma unroll
      for (int r = 0; r < 4; ++r)
        Obuf[(tbase + r)*OP + ocol] = f2bf(silu_f(acc[r] + b));
    }
  }
  __syncthreads();
  #pragma unroll
  for (int it = 0; it < 8; ++it){
    const int i = tid + 256*it;            // 2048 chunks of 16B
    const int t = i >> 4, c0 = (i & 15) * 8;
    *(uint4*)&g_xy[(tb + t)*128 + c0] = *(const uint4*)&Obuf[t*OP + c0];
  }
  __syncthreads();
  // ---- B (nt16,17 -> Obuf cols 0..31), C (nt18,19 -> cols 32..63), both silu ----
  #pragma unroll
  for (int nti = 0; nti < 4; ++nti){
    const int nt = 16 + nti;
    bf16x8 b0 = *(const bf16x8*)&wf[((nt*2 + 0)*64 + lane)*8];
    bf16x8 b1 = *(const bf16x8*)&wf[((nt*2 + 1)*64 + lane)*8];
    const float b = bl[nt*16 + colq];
    #pragma unroll
    for (int m = 0; m < 2; ++m){
      f32x4 acc = {0.f, 0.f, 0.f, 0.f};
      acc = __builtin_amdgcn_mfma_f32_16x16x32_bf16(a[m][0], b0, acc, 0, 0, 0);
      acc = __builtin_amdgcn_mfma_f32_16x16x32_bf16(a[m][1], b1, acc, 0, 0, 0);
      const int tbase = (2*w + m)*16 + rowq*4;
      const int ocol = nti*16 + colq;       // 0..63 = B|C
      #pragma unroll
      for (int r = 0; r < 4; ++r)
        Obuf[(tbase + r)*OP + ocol] = f2bf(silu_f(acc[r] + b));
    }
  }
  // ---- dt (nt 20, cols 320..323) direct ----
  {
    bf16x8 b0 = *(const bf16x8*)&wf[((20*2 + 0)*64 + lane)*8];
    bf16x8 b1 = *(const bf16x8*)&wf[((20*2 + 1)*64 + lane)*8];
    #pragma unroll
    for (int m = 0; m < 2; ++m){
      f32x4 acc = {0.f, 0.f, 0.f, 0.f};
      acc = __builtin_amdgcn_mfma_f32_16x16x32_bf16(a[m][0], b0, acc, 0, 0, 0);
      acc = __builtin_amdgcn_mfma_f32_16x16x32_bf16(a[m][1], b1, acc, 0, 0, 0);
      if (colq < 4){
        const int tbase = (2*w + m)*16 + rowq*4;
        const float b = bl[320 + colq] + dt_bias[l*4 + colq];
        #pragma unroll
        for (int r = 0; r < 4; ++r)
          g_dt[(tb + tbase + r)*4 + colq] = softplus_f(acc[r] + b);
      }
    }
  }
  __syncthreads();
  #pragma unroll
  for (int it = 0; it < 4; ++it){
    const int i = tid + 256*it;              // 1024 chunks of 16B: 4 Ba + 4 Ca per row
    const int t = i >> 3, k = i & 7;
    const int c0 = (k & 3) * 8;
    if (k < 4){
      *(uint4*)&g_Ba[(tb + t)*32 + c0] = *(const uint4*)&Obuf[t*OP + c0];
    } else {
      *(uint4*)&g_Ca[(tb + t)*32 + c0] = *(const uint4*)&Obuf[t*OP + 32 + c0];
    }
  }
}

// ---------------- chunk intra: all-MFMA (G, y_intra, chunkS) ----------------
#define SB 40   // Bb/Cb row stride (ushorts)
#define ST 72   // Mb/Xt/Xwt/Bbt row stride (ushorts)
__global__ __launch_bounds__(256) void k_s1(
    const float* __restrict__ A_log, const float* __restrict__ Dp, int l)
{
  __shared__ __align__(16) unsigned short u_bc[2*64*SB]; // Bb[64][SB]+Cb[64][SB]; later Xt[32][ST]+Xwt[32][ST]
  __shared__ __align__(16) unsigned short Bbt[32*ST];    // B transposed [n][s]
  __shared__ __align__(16) unsigned short Mb[64*ST];     // per-head decay-scaled M [t][s]
  __shared__ float Sl[4*64];
  __shared__ float dts[4*64];
  __shared__ float wls[4*64];
  const int tid = threadIdx.x;
  const int cI = blockIdx.x, b = blockIdx.y;
  const long tb = (long)b*LSEQ + (long)cI*QC;
  unsigned short* Bb = u_bc;
  unsigned short* Cb = u_bc + 64*SB;
  for (int i = tid; i < 512; i += 256){
    const int s = i >> 3, n0 = (i & 7) * 4;
    ushort4 bu = *(const ushort4*)&g_Ba[(tb + s)*32 + n0];
    ushort4 cu = *(const ushort4*)&g_Ca[(tb + s)*32 + n0];
    *(ushort4*)&Bb[s*SB + n0] = bu;
    *(ushort4*)&Cb[s*SB + n0] = cu;
    Bbt[(n0    )*ST + s] = bu.x;
    Bbt[(n0 + 1)*ST + s] = bu.y;
    Bbt[(n0 + 2)*ST + s] = bu.z;
    Bbt[(n0 + 3)*ST + s] = bu.w;
  }
  // ---- wave-parallel scan: wave = head, lane = token ----
  {
    const int h = tid >> 6, t = tid & 63;
    const float Ah = -__expf(A_log[l*4 + h]);
    const float v = g_dt[(tb + t)*4 + h];
    float x = v * Ah;
    #pragma unroll
    for (int d = 1; d < 64; d <<= 1){
      float y = __shfl_up(x, d);
      if (t >= d) x += y;
    }
    Sl[h*64 + t] = x;
    dts[h*64 + t] = v;
    const float send = __shfl(x, 63);
    wls[h*64 + t] = __expf(send - x) * v;
    if (t == 63) g_cL[((long)b*NCH + cI)*4 + h] = x;
    g_pc[(tb + t)*4 + h] = __expf(x);
  }
  __syncthreads();
  const int w = tid >> 6, lane = tid & 63;
  const int colq = lane & 15, rowq = lane >> 4;
  // ---- G = C . B^T via MFMA: 10 lower-triangle tiles round-robin over waves ----
  float Greg[3][4];
  int Gmt[3], Gst[3];
  #pragma unroll
  for (int rep = 0; rep < 3; ++rep){
    const int k = w + rep*4;
    if (k < 10){
      const int mt = (k >= 6) ? 3 : ((k >= 3) ? 2 : ((k >= 1) ? 1 : 0));
      const int st = k - mt*(mt+1)/2;
      Gmt[rep] = mt; Gst[rep] = st;
      bf16x8 af = *(const bf16x8*)&Cb[(mt*16 + colq)*SB + rowq*8];
      bf16x8 bf = *(const bf16x8*)&Bb[(st*16 + colq)*SB + rowq*8];
      f32x4 acc = {0.f, 0.f, 0.f, 0.f};
      acc = __builtin_amdgcn_mfma_f32_16x16x32_bf16(af, bf, acc, 0, 0, 0);
      #pragma unroll
      for (int r = 0; r < 4; ++r) Greg[rep][r] = acc[r];
    } else { Gmt[rep] = -1; Gst[rep] = 0; }
  }
  #pragma unroll
  for (int rep = 0; rep < 2; ++rep){
    const int k = w + rep*4;
    if (k < 6){
      const int mt = (k < 3) ? 0 : ((k < 5) ? 1 : 2);
      const int st = (k < 3) ? (k + 1) : ((k < 5) ? (k - 1) : 3);
      #pragma unroll
      for (int r = 0; r < 4; ++r)
        Mb[(mt*16 + rowq*4 + r)*ST + st*16 + colq] = 0;
    }
  }
  unsigned short* Xt  = u_bc;             // alias: Bb/Cb dead after G
  unsigned short* Xwt = u_bc + 32*ST;
  for (int h = 0; h < NHD; ++h){
    __syncthreads();
    for (int i = tid; i < 512; i += 256){
      const int s = i >> 3, p0 = (i & 7) * 4;
      ushort4 u = *(const ushort4*)&g_xy[(tb + s)*128 + h*32 + p0];
      const float wv = wls[h*64 + s];
      Xt[(p0    )*ST + s] = u.x;  Xwt[(p0    )*ST + s] = f2bf(wv * bf2f(u.x));
      Xt[(p0 + 1)*ST + s] = u.y;  Xwt[(p0 + 1)*ST + s] = f2bf(wv * bf2f(u.y));
      Xt[(p0 + 2)*ST + s] = u.z;  Xwt[(p0 + 2)*ST + s] = f2bf(wv * bf2f(u.z));
      Xt[(p0 + 3)*ST + s] = u.w;  Xwt[(p0 + 3)*ST + s] = f2bf(wv * bf2f(u.w));
    }
    #pragma unroll
    for (int rep = 0; rep < 3; ++rep){
      if (Gmt[rep] >= 0){
        const int mt = Gmt[rep], st = Gst[rep];
        const int s = st*16 + colq;
        const float sls = Sl[h*64 + s];
        const float dv = dts[h*64 + s];
        #pragma unroll
        for (int r = 0; r < 4; ++r){
          const int t = mt*16 + rowq*4 + r;
          const float m = (s <= t) ? __expf(Sl[h*64 + t] - sls) * dv * Greg[rep][r] : 0.f;
          Mb[t*ST + s] = f2bf(m);
        }
      }
    }
    __syncthreads();
    const float Dh = Dp[l*4 + h];
    {
      bf16x8 a0 = *(const bf16x8*)&Mb[(w*16 + colq)*ST + rowq*8];
      bf16x8 a1 = *(const bf16x8*)&Mb[(w*16 + colq)*ST + 32 + rowq*8];
      #pragma unroll
      for (int nt = 0; nt < 2; ++nt){
        bf16x8 b0 = *(const bf16x8*)&Xt[(nt*16 + colq)*ST + rowq*8];
        bf16x8 b1 = *(const bf16x8*)&Xt[(nt*16 + colq)*ST + 32 + rowq*8];
        f32x4 acc = {0.f, 0.f, 0.f, 0.f};
        acc = __builtin_amdgcn_mfma_f32_16x16x32_bf16(a0, b0, acc, 0, 0, 0);
        acc = __builtin_amdgcn_mfma_f32_16x16x32_bf16(a1, b1, acc, 0, 0, 0);
        const int p = nt*16 + colq;
        #pragma unroll
        for (int r = 0; r < 4; ++r){
          const int t = w*16 + rowq*4 + r;
          const float xv = bf2f(Xt[p*ST + t]);
          g_xy[(tb + t)*128 + h*32 + p] = f2bf(acc[r] + Dh*xv);
        }
      }
    }
    {
      const int mt = w & 1, nt = w >> 1;
      bf16x8 a0 = *(const bf16x8*)&Xwt[(mt*16 + colq)*ST + rowq*8];
      bf16x8 a1 = *(const bf16x8*)&Xwt[(mt*16 + colq)*ST + 32 + rowq*8];
      bf16x8 b0 = *(const bf16x8*)&Bbt[(nt*16 + colq)*ST + rowq*8];
      bf16x8 b1 = *(const bf16x8*)&Bbt[(nt*16 + colq)*ST + 32 + rowq*8];
      f32x4 acc = {0.f, 0.f, 0.f, 0.f};
      acc = __builtin_amdgcn_mfma_f32_16x16x32_bf16(a0, b0, acc, 0, 0, 0);
      acc = __builtin_amdgcn_mfma_f32_16x16x32_bf16(a1, b1, acc, 0, 0, 0);
      const long base = (((long)b*NCH + cI)*NHD + h)*(HDD*DSD);
      const int n = nt*16 + colq;
      #pragma unroll
      for (int r = 0; r < 4; ++r){
        const int p = mt*16 + rowq*4 + r;
        g_cS[base + p*32 + n] = acc[r];
      }
    }
  }
}

// ---------------- cross-chunk state prefix scan (in place) ----------------
__global__ __launch_bounds__(128) void k_s2()
{
  const int h = blockIdx.x >> 3, seg = blockIdx.x & 7, b = blockIdx.y;
  const int idx = seg*128 + threadIdx.x;
  float H = 0.f;
  for (int c = 0; c < NCH; ++c){
    const long o = (((long)b*NCH + c)*NHD + h)*1024 + idx;
    const float cs = g_cS[o];
    const float lg = g_cL[((long)b*NCH + c)*4 + h];
    g_cS[o] = H;
    H = __expf(lg) * H + cs;
  }
}

// ---------------- z-GEMM + y_inter + gate + out_proj + residual (+ pool), all-MFMA ----------------
__global__ __launch_bounds__(256) void k_s3(
    const float* __restrict__ ipb, const float* __restrict__ bo, int l, int finalLayer)
{
  __shared__ __align__(16) unsigned short Hb[128*40];  // H_in bf16 [hp][n]
  __shared__ __align__(16) unsigned short Cb[64*40];   // C bf16 [t][n]
  __shared__ __align__(16) unsigned short gl[64*136];  // gated y bf16 [t][hp]
  __shared__ __align__(16) unsigned short Afr[4*2*64*8]; // h0 A-fragments (z GEMM), 8 KB
  __shared__ float pcl[4*64];
  __shared__ float csum[4*64];
  const int tid = threadIdx.x;
  const int cI = blockIdx.x, b = blockIdx.y;
  const long tb = (long)b*LSEQ + (long)cI*QC;
  const long hbase = (((long)b*NCH + cI)*NHD)*(long)(HDD*DSD);
  for (int i = tid; i < 1024; i += 256){
    const int hp = i >> 2, n0 = (i & 3) * 8;
    float4 f0 = *(const float4*)&g_cS[hbase + hp*32 + n0];
    float4 f1 = *(const float4*)&g_cS[hbase + hp*32 + n0 + 4];
    *(ushort4*)&Hb[hp*40 + n0]     = make_ushort4(f2bf(f0.x), f2bf(f0.y), f2bf(f0.z), f2bf(f0.w));
    *(ushort4*)&Hb[hp*40 + n0 + 4] = make_ushort4(f2bf(f1.x), f2bf(f1.y), f2bf(f1.z), f2bf(f1.w));
  }
  for (int i = tid; i < 512; i += 256){
    const int t = i >> 3, n0 = (i & 7) * 4;
    *(ushort4*)&Cb[t*40 + n0] = *(const ushort4*)&g_Ca[(tb + t)*32 + n0];
  }
  // stage h0 (64 tokens) -> bf16 A-fragments for the z GEMM
  #pragma unroll
  for (int r = 0; r < 2; ++r){
    const int c = tid + 256*r;               // 0..511 = (t 0..63, k8 0..7)
    const int t = c >> 3, k8 = c & 7;
    float4 f0 = *(const float4*)&g_h0[(tb + t)*64 + k8*8];
    float4 f1 = *(const float4*)&g_h0[(tb + t)*64 + k8*8 + 4];
    const int mt = t >> 4, ks = k8 >> 2, q = k8 & 3, ln = (t & 15) + 16*q;
    unsigned short* d = &Afr[(((mt*2 + ks)*64) + ln)*8];
    *(ushort4*)&d[0] = make_ushort4(f2bf(f0.x), f2bf(f0.y), f2bf(f0.z), f2bf(f0.w));
    *(ushort4*)&d[4] = make_ushort4(f2bf(f1.x), f2bf(f1.y), f2bf(f1.z), f2bf(f1.w));
  }
  { int t = tid >> 2, h = tid & 3; pcl[h*64 + t] = g_pc[(tb + t)*4 + h]; }
  __syncthreads();
  const int w = tid >> 6, lane = tid & 63;
  const int colq = lane & 15, rowq = lane >> 4;
  const float* blz = ipb + (long)l*DPRJ;     // z bias = in_proj bias cols 0..127
  const unsigned short* wfz = &g_wf[(long)l*NT21*2*64*8];
  // ---- phase 1: y_inter = C @ H^T and z = h0 @ Wz (both MFMA); gate -> gl ----
  {
    bf16x8 a  = *(const bf16x8*)&Cb[(w*16 + colq)*40 + rowq*8];
    bf16x8 h0a = *(const bf16x8*)&Afr[(((w*2 + 0)*64) + lane)*8];
    bf16x8 h0b = *(const bf16x8*)&Afr[(((w*2 + 1)*64) + lane)*8];
    #pragma unroll
    for (int nt = 0; nt < 8; ++nt){
      bf16x8 bfr = *(const bf16x8*)&Hb[(nt*16 + colq)*40 + rowq*8];
      f32x4 acc = {0.f, 0.f, 0.f, 0.f};
      acc = __builtin_amdgcn_mfma_f32_16x16x32_bf16(a, bfr, acc, 0, 0, 0);
      bf16x8 bz0 = *(const bf16x8*)&wfz[((nt*2 + 0)*64 + lane)*8];
      bf16x8 bz1 = *(const bf16x8*)&wfz[((nt*2 + 1)*64 + lane)*8];
      f32x4 zac = {0.f, 0.f, 0.f, 0.f};
      zac = __builtin_amdgcn_mfma_f32_16x16x32_bf16(h0a, bz0, zac, 0, 0, 0);
      zac = __builtin_amdgcn_mfma_f32_16x16x32_bf16(h0b, bz1, zac, 0, 0, 0);
      const int hp = nt*16 + colq;
      const int h = hp >> 5;
      const float zb = blz[hp];
      #pragma unroll
      for (int r = 0; r < 4; ++r){
        const int t = w*16 + rowq*4 + r;
        const long tok = tb + t;
        const float v = pcl[h*64 + t] * acc[r] + bf2f(g_xy[tok*128 + hp]);
        gl[t*136 + hp] = f2bf(v * silu_f(zac[r] + zb));
      }
    }
  }
  __syncthreads();
  // ---- phase 2: out = gl @ Wo (MFMA) + bias + residual, colsum for pool ----
  const unsigned short* wo = &g_wo[(long)l*4*4*512];
  #pragma unroll
  for (int nt2 = 0; nt2 < 4; ++nt2){
    f32x4 acc = {0.f, 0.f, 0.f, 0.f};
    #pragma unroll
    for (int ks = 0; ks < 4; ++ks){
      bf16x8 a = *(const bf16x8*)&gl[(w*16 + colq)*136 + ks*32 + rowq*8];
      bf16x8 bfr = *(const bf16x8*)&wo[(nt2*4 + ks)*512 + lane*8];
      acc = __builtin_amdgcn_mfma_f32_16x16x32_bf16(a, bfr, acc, 0, 0, 0);
    }
    const int dm = nt2*16 + colq;
    const float bb = bo[l*64 + dm];
    float part = 0.f;
    #pragma unroll
    for (int r = 0; r < 4; ++r){
      const int t = w*16 + rowq*4 + r;
      const long tok = tb + t;
      const float o = acc[r] + bb + g_h0[tok*64 + dm];
      g_h0[tok*64 + dm] = o;
      part += o;
    }
    if (finalLayer){
      part += __shfl_xor(part, 16);
      part += __shfl_xor(part, 32);
      if (rowq == 0) csum[w*64 + dm] = part;
    }
  }
  if (finalLayer){
    __syncthreads();
    if (tid < 64){
      g_ppc[((long)b*NCH + cI)*64 + tid] =
        csum[tid] + csum[64 + tid] + csum[128 + tid] + csum[192 + tid];
    }
  }
}

// ---------------- pooling + classifier ----------------
__global__ __launch_bounds__(64) void k_pool2(
    const float* __restrict__ cW, const float* __restrict__ cb,
    float* __restrict__ out)
{
  __shared__ float pl[64];
  const int b = blockIdx.x, tid = threadIdx.x;
  float s = 0.f;
  for (int c = 0; c < NCH; ++c) s += g_ppc[((long)b*NCH + c)*64 + tid];
  pl[tid] = s * (1.0f / 8192.0f);
  __syncthreads();
  if (tid < NOUTC){
    float acc = cb[tid];
    for (int dm = 0; dm < 64; ++dm) acc += pl[dm] * cW[dm*NOUTC + tid];
    out[b*NOUTC + tid] = acc;
  }
}

extern "C" void kernel_launch(void* const* d_in, const int* in_sizes, int n_in,
                              void* d_out, int out_size, void* d_ws, size_t ws_size,
                              hipStream_t stream)
{
  const float* x      = (const float*)d_in[0];
  const float* W_in   = (const float*)d_in[1];
  const float* b_in   = (const float*)d_in[2];
  const float* ipW    = (const float*)d_in[3];
  const float* ipb    = (const float*)d_in[4];
  const float* A_log  = (const float*)d_in[5];
  const float* Dp     = (const float*)d_in[6];
  const float* dtb    = (const float*)d_in[7];
  const float* opW    = (const float*)d_in[8];
  const float* opb    = (const float*)d_in[9];
  const float* clsW   = (const float*)d_in[10];
  const float* clsb   = (const float*)d_in[11];
  float* out = (float*)d_out;
  (void)d_ws; (void)ws_size;

  k_wprep<<<dim3(NT21, NLAY), 128, 0, stream>>>(ipW);
  k_wprep2<<<dim3(16, NLAY), 64, 0, stream>>>(opW);
  k_linin<<<2048, 256, 0, stream>>>(x, W_in, b_in);
  for (int l = 0; l < NLAY; ++l){
    k_proj<<<1024, 256, 0, stream>>>(ipb, dtb, l);
    k_s1<<<dim3(NCH, BSZ), 256, 0, stream>>>(A_log, Dp, l);
    k_s2<<<dim3(32, BSZ), 128, 0, stream>>>();
    k_s3<<<dim3(NCH, BSZ), 256, 0, stream>>>(ipb, opb, l, (l == NLAY-1) ? 1 : 0);
  }
  k_pool2<<<BSZ, 64, 0, stream>>>(clsW, clsb, out);
}

// Round 14
// 354.678 us; speedup vs baseline: 16.1897x; 1.0205x over previous
//
#include <hip/hip_runtime.h>

#define BSZ   16
#define LSEQ  8192
#define DMDL  64
#define DSD   32
#define HDD   32
#define NHD   4
#define DIN   128
#define NLAY  2
#define NOUTC 6
#define DPRJ  324
#define QC    64
#define NCH   128   // LSEQ/QC
#define NT21  21    // 21 column tiles of 16 (320 proj cols + 4 dt cols zero-padded)

typedef __attribute__((ext_vector_type(8))) short bf16x8;
typedef __attribute__((ext_vector_type(4))) float f32x4;

// ---- device-global scratch ----
__device__ float          g_h0[BSZ*LSEQ*DMDL];
__device__ unsigned short g_xy[BSZ*LSEQ*DIN];   // silu(x), overwritten by y_intra (bf16)
__device__ unsigned short g_Ba[BSZ*LSEQ*DSD];   // silu(B), bf16
__device__ unsigned short g_Ca[BSZ*LSEQ*DSD];   // silu(C), bf16
__device__ float          g_dt[BSZ*LSEQ*NHD];
__device__ float          g_pc[BSZ*LSEQ*NHD];
__device__ float          g_cS[BSZ*NCH*NHD*HDD*DSD]; // per-chunk outgoing states (fp32)
__device__ unsigned short g_Hb[BSZ*NCH*NHD*HDD*DSD]; // scanned H_in (bf16, written by k_s2)
__device__ float          g_cL[BSZ*NCH*NHD];
__device__ float          g_ppc[BSZ*NCH*DMDL];       // per-chunk column sums (final layer)
__device__ unsigned short g_wf[NLAY*NT21*2*64*8];    // in_proj W, bf16 MFMA B-fragment layout
__device__ unsigned short g_wo[NLAY*4*4*64*8];       // out_proj W, bf16 MFMA B-fragment layout

__device__ __forceinline__ float silu_f(float v){ return v / (1.0f + __expf(-v)); }
__device__ __forceinline__ float softplus_f(float v){ return (v > 15.0f) ? v : __logf(1.0f + __expf(v)); }
__device__ __forceinline__ unsigned short f2bf(float f){
  union { float f; unsigned u; } v; v.f = f;
  unsigned r = v.u + 0x7FFFu + ((v.u >> 16) & 1u);
  return (unsigned short)(r >> 16);
}
__device__ __forceinline__ float bf2f(unsigned short h){
  union { unsigned u; float f; } v; v.u = ((unsigned)h) << 16;
  return v.f;
}

// ---------------- linear_in ----------------
__global__ __launch_bounds__(256) void k_linin(
    const float* __restrict__ x, const float* __restrict__ W,
    const float* __restrict__ bias)
{
  __shared__ float xs[64*60];
  __shared__ float wl[57*64];
  const int tid = threadIdx.x;
  const long tb = (long)blockIdx.x * 64;
  for (int i = tid; i < 64*57; i += 256){
    int t = i / 57, k = i - t*57;
    xs[t*60 + k] = x[tb*57 + i];
  }
  for (int i = tid; i < 57*64; i += 256) wl[i] = W[i];
  __syncthreads();
  const int t0 = (tid >> 4) * 4, d0 = (tid & 15) * 4;
  float acc[4][4];
  #pragma unroll
  for (int i = 0; i < 4; ++i)
    #pragma unroll
    for (int j = 0; j < 4; ++j) acc[i][j] = 0.f;
  for (int k = 0; k < 57; ++k){
    float4 w4 = *(const float4*)&wl[k*64 + d0];
    float wv[4] = {w4.x, w4.y, w4.z, w4.w};
    #pragma unroll
    for (int i = 0; i < 4; ++i){
      float xv = xs[(t0+i)*60 + k];
      #pragma unroll
      for (int j = 0; j < 4; ++j) acc[i][j] += xv * wv[j];
    }
  }
  float4 b4 = *(const float4*)&bias[d0];
  float bv[4] = {b4.x, b4.y, b4.z, b4.w};
  #pragma unroll
  for (int i = 0; i < 4; ++i){
    float4 o;
    o.x = acc[i][0] + bv[0]; o.y = acc[i][1] + bv[1];
    o.z = acc[i][2] + bv[2]; o.w = acc[i][3] + bv[3];
    *(float4*)&g_h0[(tb + t0 + i)*64 + d0] = o;
  }
}

// ---------------- weight prep: ipW -> bf16 B-fragment layout ----------------
__global__ __launch_bounds__(128) void k_wprep(const float* __restrict__ W)
{
  const int nt = blockIdx.x;            // 0..20
  const int l  = blockIdx.y;            // layer
  const int ks = threadIdx.x >> 6, lane = threadIdx.x & 63;
  const float* Wl = W + (long)l*64*DPRJ;
  const int n  = nt*16 + (lane & 15);
  const int k0 = ks*32 + (lane >> 4)*8;
  unsigned short v[8];
  #pragma unroll
  for (int j = 0; j < 8; ++j)
    v[j] = (n < DPRJ) ? f2bf(Wl[(k0 + j)*DPRJ + n]) : (unsigned short)0;
  unsigned short* d = &g_wf[((((long)l*NT21 + nt)*2 + ks)*64 + lane)*8];
  *(ushort4*)&d[0] = make_ushort4(v[0], v[1], v[2], v[3]);
  *(ushort4*)&d[4] = make_ushort4(v[4], v[5], v[6], v[7]);
}

// ---------------- weight prep: out_proj W -> bf16 B-fragment layout ----------------
__global__ __launch_bounds__(64) void k_wprep2(const float* __restrict__ Wo)
{
  const int nt = blockIdx.x >> 2, ks = blockIdx.x & 3, l = blockIdx.y;
  const int lane = threadIdx.x;
  const int n  = nt*16 + (lane & 15);
  const int k0 = ks*32 + (lane >> 4)*8;
  const float* Wl = Wo + (long)l*128*64;
  unsigned short* d = &g_wo[((((long)l*4 + nt)*4 + ks)*64 + lane)*8];
  unsigned short v[8];
  #pragma unroll
  for (int j = 0; j < 8; ++j) v[j] = f2bf(Wl[(k0 + j)*64 + n]);
  *(ushort4*)&d[0] = make_ushort4(v[0], v[1], v[2], v[3]);
  *(ushort4*)&d[4] = make_ushort4(v[4], v[5], v[6], v[7]);
}

// ---------------- in_proj via MFMA (x/B/C/dt only; z computed in k_s3) ----------------
#define OP 136   // Obuf row stride (ushorts)
__global__ __launch_bounds__(256) void k_proj(
    const float* __restrict__ bias, const float* __restrict__ dt_bias, int l)
{
  __shared__ __align__(16) unsigned short Afr[8*2*64*8];  // A fragments, 16 KB
  __shared__ __align__(16) unsigned short Obuf[128*OP];   // output staging, 34.8 KB
  const int tid = threadIdx.x;
  const long tb = (long)blockIdx.x * 128;
  #pragma unroll
  for (int r = 0; r < 4; ++r){
    const int c = tid + 256*r;
    const int t = c >> 3, k8 = c & 7;
    float4 f0 = *(const float4*)&g_h0[(tb + t)*64 + k8*8];
    float4 f1 = *(const float4*)&g_h0[(tb + t)*64 + k8*8 + 4];
    const int mt = t >> 4, ks = k8 >> 2, q = k8 & 3, ln = (t & 15) + 16*q;
    unsigned short* d = &Afr[(((mt*2 + ks)*64) + ln)*8];
    *(ushort4*)&d[0] = make_ushort4(f2bf(f0.x), f2bf(f0.y), f2bf(f0.z), f2bf(f0.w));
    *(ushort4*)&d[4] = make_ushort4(f2bf(f1.x), f2bf(f1.y), f2bf(f1.z), f2bf(f1.w));
  }
  __syncthreads();
  const int w = tid >> 6, lane = tid & 63;
  const int colq = lane & 15, rowq = lane >> 4;
  bf16x8 a[2][2];
  #pragma unroll
  for (int m = 0; m < 2; ++m)
    #pragma unroll
    for (int ks = 0; ks < 2; ++ks)
      a[m][ks] = *(const bf16x8*)&Afr[((((2*w + m)*2 + ks)*64) + lane)*8];
  const float* bl = bias + (long)l*DPRJ;
  const unsigned short* wf = &g_wf[(long)l*NT21*2*64*8];
  // ---- x tiles (nt 8..15, silu) -> Obuf -> coalesced 16B stores ----
  #pragma unroll
  for (int nti = 0; nti < 8; ++nti){
    const int nt = 8 + nti;
    bf16x8 b0 = *(const bf16x8*)&wf[((nt*2 + 0)*64 + lane)*8];
    bf16x8 b1 = *(const bf16x8*)&wf[((nt*2 + 1)*64 + lane)*8];
    const float b = bl[nt*16 + colq];
    #pragma unroll
    for (int m = 0; m < 2; ++m){
      f32x4 acc = {0.f, 0.f, 0.f, 0.f};
      acc = __builtin_amdgcn_mfma_f32_16x16x32_bf16(a[m][0], b0, acc, 0, 0, 0);
      acc = __builtin_amdgcn_mfma_f32_16x16x32_bf16(a[m][1], b1, acc, 0, 0, 0);
      const int tbase = (2*w + m)*16 + rowq*4;
      const int ocol = nti*16 + colq;
      #pragma unroll
      for (int r = 0; r < 4; ++r)
        Obuf[(tbase + r)*OP + ocol] = f2bf(silu_f(acc[r] + b));
    }
  }
  __syncthreads();
  #pragma unroll
  for (int it = 0; it < 8; ++it){
    const int i = tid + 256*it;            // 2048 chunks of 16B
    const int t = i >> 4, c0 = (i & 15) * 8;
    *(uint4*)&g_xy[(tb + t)*128 + c0] = *(const uint4*)&Obuf[t*OP + c0];
  }
  __syncthreads();
  // ---- B (nt16,17 -> Obuf cols 0..31), C (nt18,19 -> cols 32..63), both silu ----
  #pragma unroll
  for (int nti = 0; nti < 4; ++nti){
    const int nt = 16 + nti;
    bf16x8 b0 = *(const bf16x8*)&wf[((nt*2 + 0)*64 + lane)*8];
    bf16x8 b1 = *(const bf16x8*)&wf[((nt*2 + 1)*64 + lane)*8];
    const float b = bl[nt*16 + colq];
    #pragma unroll
    for (int m = 0; m < 2; ++m){
      f32x4 acc = {0.f, 0.f, 0.f, 0.f};
      acc = __builtin_amdgcn_mfma_f32_16x16x32_bf16(a[m][0], b0, acc, 0, 0, 0);
      acc = __builtin_amdgcn_mfma_f32_16x16x32_bf16(a[m][1], b1, acc, 0, 0, 0);
      const int tbase = (2*w + m)*16 + rowq*4;
      const int ocol = nti*16 + colq;       // 0..63 = B|C
      #pragma unroll
      for (int r = 0; r < 4; ++r)
        Obuf[(tbase + r)*OP + ocol] = f2bf(silu_f(acc[r] + b));
    }
  }
  // ---- dt (nt 20, cols 320..323) direct ----
  {
    bf16x8 b0 = *(const bf16x8*)&wf[((20*2 + 0)*64 + lane)*8];
    bf16x8 b1 = *(const bf16x8*)&wf[((20*2 + 1)*64 + lane)*8];
    #pragma unroll
    for (int m = 0; m < 2; ++m){
      f32x4 acc = {0.f, 0.f, 0.f, 0.f};
      acc = __builtin_amdgcn_mfma_f32_16x16x32_bf16(a[m][0], b0, acc, 0, 0, 0);
      acc = __builtin_amdgcn_mfma_f32_16x16x32_bf16(a[m][1], b1, acc, 0, 0, 0);
      if (colq < 4){
        const int tbase = (2*w + m)*16 + rowq*4;
        const float b = bl[320 + colq] + dt_bias[l*4 + colq];
        #pragma unroll
        for (int r = 0; r < 4; ++r)
          g_dt[(tb + tbase + r)*4 + colq] = softplus_f(acc[r] + b);
      }
    }
  }
  __syncthreads();
  #pragma unroll
  for (int it = 0; it < 4; ++it){
    const int i = tid + 256*it;              // 1024 chunks of 16B: 4 Ba + 4 Ca per row
    const int t = i >> 3, k = i & 7;
    const int c0 = (k & 3) * 8;
    if (k < 4){
      *(uint4*)&g_Ba[(tb + t)*32 + c0] = *(const uint4*)&Obuf[t*OP + c0];
    } else {
      *(uint4*)&g_Ca[(tb + t)*32 + c0] = *(const uint4*)&Obuf[t*OP + 32 + c0];
    }
  }
}

// ---------------- chunk intra: all-MFMA (G, y_intra, chunkS) ----------------
#define SB 40   // Bb/Cb row stride (ushorts)
#define ST 72   // Mb/Xt/Xwt/Bbt row stride (ushorts)
__global__ __launch_bounds__(256) void k_s1(
    const float* __restrict__ A_log, const float* __restrict__ Dp, int l)
{
  __shared__ __align__(16) unsigned short u_bc[2*64*SB]; // Bb[64][SB]+Cb[64][SB]; later Xt[32][ST]+Xwt[32][ST]
  __shared__ __align__(16) unsigned short Bbt[32*ST];    // B transposed [n][s]
  __shared__ __align__(16) unsigned short Mb[64*ST];     // per-head decay-scaled M [t][s]
  __shared__ float Sl[4*64];
  __shared__ float dts[4*64];
  __shared__ float wls[4*64];
  const int tid = threadIdx.x;
  const int cI = blockIdx.x, b = blockIdx.y;
  const long tb = (long)b*LSEQ + (long)cI*QC;
  unsigned short* Bb = u_bc;
  unsigned short* Cb = u_bc + 64*SB;
  for (int i = tid; i < 512; i += 256){
    const int s = i >> 3, n0 = (i & 7) * 4;
    ushort4 bu = *(const ushort4*)&g_Ba[(tb + s)*32 + n0];
    ushort4 cu = *(const ushort4*)&g_Ca[(tb + s)*32 + n0];
    *(ushort4*)&Bb[s*SB + n0] = bu;
    *(ushort4*)&Cb[s*SB + n0] = cu;
    Bbt[(n0    )*ST + s] = bu.x;
    Bbt[(n0 + 1)*ST + s] = bu.y;
    Bbt[(n0 + 2)*ST + s] = bu.z;
    Bbt[(n0 + 3)*ST + s] = bu.w;
  }
  // ---- wave-parallel scan: wave = head, lane = token ----
  {
    const int h = tid >> 6, t = tid & 63;
    const float Ah = -__expf(A_log[l*4 + h]);
    const float v = g_dt[(tb + t)*4 + h];
    float x = v * Ah;
    #pragma unroll
    for (int d = 1; d < 64; d <<= 1){
      float y = __shfl_up(x, d);
      if (t >= d) x += y;
    }
    Sl[h*64 + t] = x;
    dts[h*64 + t] = v;
    const float send = __shfl(x, 63);
    wls[h*64 + t] = __expf(send - x) * v;
    if (t == 63) g_cL[((long)b*NCH + cI)*4 + h] = x;
    g_pc[(tb + t)*4 + h] = __expf(x);
  }
  __syncthreads();
  const int w = tid >> 6, lane = tid & 63;
  const int colq = lane & 15, rowq = lane >> 4;
  // ---- G = C . B^T via MFMA: 10 lower-triangle tiles round-robin over waves ----
  float Greg[3][4];
  int Gmt[3], Gst[3];
  #pragma unroll
  for (int rep = 0; rep < 3; ++rep){
    const int k = w + rep*4;
    if (k < 10){
      const int mt = (k >= 6) ? 3 : ((k >= 3) ? 2 : ((k >= 1) ? 1 : 0));
      const int st = k - mt*(mt+1)/2;
      Gmt[rep] = mt; Gst[rep] = st;
      bf16x8 af = *(const bf16x8*)&Cb[(mt*16 + colq)*SB + rowq*8];
      bf16x8 bf = *(const bf16x8*)&Bb[(st*16 + colq)*SB + rowq*8];
      f32x4 acc = {0.f, 0.f, 0.f, 0.f};
      acc = __builtin_amdgcn_mfma_f32_16x16x32_bf16(af, bf, acc, 0, 0, 0);
      #pragma unroll
      for (int r = 0; r < 4; ++r) Greg[rep][r] = acc[r];
    } else { Gmt[rep] = -1; Gst[rep] = 0; }
  }
  #pragma unroll
  for (int rep = 0; rep < 2; ++rep){
    const int k = w + rep*4;
    if (k < 6){
      const int mt = (k < 3) ? 0 : ((k < 5) ? 1 : 2);
      const int st = (k < 3) ? (k + 1) : ((k < 5) ? (k - 1) : 3);
      #pragma unroll
      for (int r = 0; r < 4; ++r)
        Mb[(mt*16 + rowq*4 + r)*ST + st*16 + colq] = 0;
    }
  }
  unsigned short* Xt  = u_bc;             // alias: Bb/Cb dead after G
  unsigned short* Xwt = u_bc + 32*ST;
  for (int h = 0; h < NHD; ++h){
    __syncthreads();
    for (int i = tid; i < 512; i += 256){
      const int s = i >> 3, p0 = (i & 7) * 4;
      ushort4 u = *(const ushort4*)&g_xy[(tb + s)*128 + h*32 + p0];
      const float wv = wls[h*64 + s];
      Xt[(p0    )*ST + s] = u.x;  Xwt[(p0    )*ST + s] = f2bf(wv * bf2f(u.x));
      Xt[(p0 + 1)*ST + s] = u.y;  Xwt[(p0 + 1)*ST + s] = f2bf(wv * bf2f(u.y));
      Xt[(p0 + 2)*ST + s] = u.z;  Xwt[(p0 + 2)*ST + s] = f2bf(wv * bf2f(u.z));
      Xt[(p0 + 3)*ST + s] = u.w;  Xwt[(p0 + 3)*ST + s] = f2bf(wv * bf2f(u.w));
    }
    #pragma unroll
    for (int rep = 0; rep < 3; ++rep){
      if (Gmt[rep] >= 0){
        const int mt = Gmt[rep], st = Gst[rep];
        const int s = st*16 + colq;
        const float sls = Sl[h*64 + s];
        const float dv = dts[h*64 + s];
        #pragma unroll
        for (int r = 0; r < 4; ++r){
          const int t = mt*16 + rowq*4 + r;
          const float m = (s <= t) ? __expf(Sl[h*64 + t] - sls) * dv * Greg[rep][r] : 0.f;
          Mb[t*ST + s] = f2bf(m);
        }
      }
    }
    __syncthreads();
    const float Dh = Dp[l*4 + h];
    {
      bf16x8 a0 = *(const bf16x8*)&Mb[(w*16 + colq)*ST + rowq*8];
      bf16x8 a1 = *(const bf16x8*)&Mb[(w*16 + colq)*ST + 32 + rowq*8];
      #pragma unroll
      for (int nt = 0; nt < 2; ++nt){
        bf16x8 b0 = *(const bf16x8*)&Xt[(nt*16 + colq)*ST + rowq*8];
        bf16x8 b1 = *(const bf16x8*)&Xt[(nt*16 + colq)*ST + 32 + rowq*8];
        f32x4 acc = {0.f, 0.f, 0.f, 0.f};
        acc = __builtin_amdgcn_mfma_f32_16x16x32_bf16(a0, b0, acc, 0, 0, 0);
        acc = __builtin_amdgcn_mfma_f32_16x16x32_bf16(a1, b1, acc, 0, 0, 0);
        const int p = nt*16 + colq;
        #pragma unroll
        for (int r = 0; r < 4; ++r){
          const int t = w*16 + rowq*4 + r;
          const float xv = bf2f(Xt[p*ST + t]);
          g_xy[(tb + t)*128 + h*32 + p] = f2bf(acc[r] + Dh*xv);
        }
      }
    }
    {
      const int mt = w & 1, nt = w >> 1;
      bf16x8 a0 = *(const bf16x8*)&Xwt[(mt*16 + colq)*ST + rowq*8];
      bf16x8 a1 = *(const bf16x8*)&Xwt[(mt*16 + colq)*ST + 32 + rowq*8];
      bf16x8 b0 = *(const bf16x8*)&Bbt[(nt*16 + colq)*ST + rowq*8];
      bf16x8 b1 = *(const bf16x8*)&Bbt[(nt*16 + colq)*ST + 32 + rowq*8];
      f32x4 acc = {0.f, 0.f, 0.f, 0.f};
      acc = __builtin_amdgcn_mfma_f32_16x16x32_bf16(a0, b0, acc, 0, 0, 0);
      acc = __builtin_amdgcn_mfma_f32_16x16x32_bf16(a1, b1, acc, 0, 0, 0);
      const long base = (((long)b*NCH + cI)*NHD + h)*(HDD*DSD);
      const int n = nt*16 + colq;
      #pragma unroll
      for (int r = 0; r < 4; ++r){
        const int p = mt*16 + rowq*4 + r;
        g_cS[base + p*32 + n] = acc[r];
      }
    }
  }
}

// ---------------- cross-chunk state prefix scan: fp32 in, bf16 H_in out ----------------
__global__ __launch_bounds__(128) void k_s2()
{
  const int h = blockIdx.x >> 3, seg = blockIdx.x & 7, b = blockIdx.y;
  const int idx = seg*128 + threadIdx.x;
  float H = 0.f;
  for (int c = 0; c < NCH; ++c){
    const long o = (((long)b*NCH + c)*NHD + h)*1024 + idx;
    const float cs = g_cS[o];
    const float lg = g_cL[((long)b*NCH + c)*4 + h];
    g_Hb[o] = f2bf(H);
    H = __expf(lg) * H + cs;
  }
}

// ---------------- z-GEMM + y_inter + gate + out_proj + residual (+ pool), all-MFMA ----------------
__global__ __launch_bounds__(256) void k_s3(
    const float* __restrict__ ipb, const float* __restrict__ bo, int l, int finalLayer)
{
  __shared__ __align__(16) unsigned short Hb[128*40];  // H_in bf16 [hp][n]
  __shared__ __align__(16) unsigned short Cb[64*40];   // C bf16 [t][n]
  __shared__ __align__(16) unsigned short gl[64*136];  // gated y bf16 [t][hp]
  __shared__ float pcl[4*64];
  __shared__ float csum[4*64];
  const int tid = threadIdx.x;
  const int cI = blockIdx.x, b = blockIdx.y;
  const long tb = (long)b*LSEQ + (long)cI*QC;
  const long hbase = (((long)b*NCH + cI)*NHD)*(long)(HDD*DSD);
  for (int i = tid; i < 512; i += 256){
    const int hp = i >> 2, n0 = (i & 3) * 8;
    *(uint4*)&Hb[hp*40 + n0] = *(const uint4*)&g_Hb[hbase + hp*32 + n0];
  }
  for (int i = tid; i < 512; i += 256){
    const int t = i >> 3, n0 = (i & 7) * 4;
    *(ushort4*)&Cb[t*40 + n0] = *(const ushort4*)&g_Ca[(tb + t)*32 + n0];
  }
  { int t = tid >> 2, h = tid & 3; pcl[h*64 + t] = g_pc[(tb + t)*4 + h]; }
  __syncthreads();
  const int w = tid >> 6, lane = tid & 63;
  const int colq = lane & 15, rowq = lane >> 4;
  const float* blz = ipb + (long)l*DPRJ;     // z bias = in_proj bias cols 0..127
  const unsigned short* wfz = &g_wf[(long)l*NT21*2*64*8];
  // ---- phase 1: y_inter = C @ H^T and z = h0 @ Wz (both MFMA); gate -> gl ----
  {
    // z-GEMM A-fragment loaded directly from global (L2-hot; h0 re-read in phase 2 anyway)
    // A[m=colq][k=rowq*8+j+32*ks], row tok = tb + w*16 + colq
    const long tok0 = tb + w*16 + colq;
    bf16x8 h0a, h0b;
    {
      float4 f0 = *(const float4*)&g_h0[tok0*64 + rowq*8];
      float4 f1 = *(const float4*)&g_h0[tok0*64 + rowq*8 + 4];
      float4 f2 = *(const float4*)&g_h0[tok0*64 + 32 + rowq*8];
      float4 f3 = *(const float4*)&g_h0[tok0*64 + 32 + rowq*8 + 4];
      union { bf16x8 v; unsigned short u[8]; } ca, cb2;
      ca.u[0]=f2bf(f0.x); ca.u[1]=f2bf(f0.y); ca.u[2]=f2bf(f0.z); ca.u[3]=f2bf(f0.w);
      ca.u[4]=f2bf(f1.x); ca.u[5]=f2bf(f1.y); ca.u[6]=f2bf(f1.z); ca.u[7]=f2bf(f1.w);
      cb2.u[0]=f2bf(f2.x); cb2.u[1]=f2bf(f2.y); cb2.u[2]=f2bf(f2.z); cb2.u[3]=f2bf(f2.w);
      cb2.u[4]=f2bf(f3.x); cb2.u[5]=f2bf(f3.y); cb2.u[6]=f2bf(f3.z); cb2.u[7]=f2bf(f3.w);
      h0a = ca.v; h0b = cb2.v;
    }
    bf16x8 a = *(const bf16x8*)&Cb[(w*16 + colq)*40 + rowq*8];
    #pragma unroll
    for (int nt = 0; nt < 8; ++nt){
      bf16x8 bfr = *(const bf16x8*)&Hb[(nt*16 + colq)*40 + rowq*8];
      f32x4 acc = {0.f, 0.f, 0.f, 0.f};
      acc = __builtin_amdgcn_mfma_f32_16x16x32_bf16(a, bfr, acc, 0, 0, 0);
      bf16x8 bz0 = *(const bf16x8*)&wfz[((nt*2 + 0)*64 + lane)*8];
      bf16x8 bz1 = *(const bf16x8*)&wfz[((nt*2 + 1)*64 + lane)*8];
      f32x4 zac = {0.f, 0.f, 0.f, 0.f};
      zac = __builtin_amdgcn_mfma_f32_16x16x32_bf16(h0a, bz0, zac, 0, 0, 0);
      zac = __builtin_amdgcn_mfma_f32_16x16x32_bf16(h0b, bz1, zac, 0, 0, 0);
      const int hp = nt*16 + colq;
      const int h = hp >> 5;
      const float zb = blz[hp];
      #pragma unroll
      for (int r = 0; r < 4; ++r){
        const int t = w*16 + rowq*4 + r;
        const long tok = tb + t;
        const float v = pcl[h*64 + t] * acc[r] + bf2f(g_xy[tok*128 + hp]);
        gl[t*136 + hp] = f2bf(v * silu_f(zac[r] + zb));
      }
    }
  }
  __syncthreads();
  // ---- phase 2: out = gl @ Wo (MFMA) + bias + residual, colsum for pool ----
  const unsigned short* wo = &g_wo[(long)l*4*4*512];
  #pragma unroll
  for (int nt2 = 0; nt2 < 4; ++nt2){
    f32x4 acc = {0.f, 0.f, 0.f, 0.f};
    #pragma unroll
    for (int ks = 0; ks < 4; ++ks){
      bf16x8 a = *(const bf16x8*)&gl[(w*16 + colq)*136 + ks*32 + rowq*8];
      bf16x8 bfr = *(const bf16x8*)&wo[(nt2*4 + ks)*512 + lane*8];
      acc = __builtin_amdgcn_mfma_f32_16x16x32_bf16(a, bfr, acc, 0, 0, 0);
    }
    const int dm = nt2*16 + colq;
    const float bb = bo[l*64 + dm];
    float part = 0.f;
    #pragma unroll
    for (int r = 0; r < 4; ++r){
      const int t = w*16 + rowq*4 + r;
      const long tok = tb + t;
      const float o = acc[r] + bb + g_h0[tok*64 + dm];
      g_h0[tok*64 + dm] = o;
      part += o;
    }
    if (finalLayer){
      part += __shfl_xor(part, 16);
      part += __shfl_xor(part, 32);
      if (rowq == 0) csum[w*64 + dm] = part;
    }
  }
  if (finalLayer){
    __syncthreads();
    if (tid < 64){
      g_ppc[((long)b*NCH + cI)*64 + tid] =
        csum[tid] + csum[64 + tid] + csum[128 + tid] + csum[192 + tid];
    }
  }
}

// ---------------- pooling + classifier ----------------
__global__ __launch_bounds__(64) void k_pool2(
    const float* __restrict__ cW, const float* __restrict__ cb,
    float* __restrict__ out)
{
  __shared__ float pl[64];
  const int b = blockIdx.x, tid = threadIdx.x;
  float s = 0.f;
  for (int c = 0; c < NCH; ++c) s += g_ppc[((long)b*NCH + c)*64 + tid];
  pl[tid] = s * (1.0f / 8192.0f);
  __syncthreads();
  if (tid < NOUTC){
    float acc = cb[tid];
    for (int dm = 0; dm < 64; ++dm) acc += pl[dm] * cW[dm*NOUTC + tid];
    out[b*NOUTC + tid] = acc;
  }
}

extern "C" void kernel_launch(void* const* d_in, const int* in_sizes, int n_in,
                              void* d_out, int out_size, void* d_ws, size_t ws_size,
                              hipStream_t stream)
{
  const float* x      = (const float*)d_in[0];
  const float* W_in   = (const float*)d_in[1];
  const float* b_in   = (const float*)d_in[2];
  const float* ipW    = (const float*)d_in[3];
  const float* ipb    = (const float*)d_in[4];
  const float* A_log  = (const float*)d_in[5];
  const float* Dp     = (const float*)d_in[6];
  const float* dtb    = (const float*)d_in[7];
  const float* opW    = (const float*)d_in[8];
  const float* opb    = (const float*)d_in[9];
  const float* clsW   = (const float*)d_in[10];
  const float* clsb   = (const float*)d_in[11];
  float* out = (float*)d_out;
  (void)d_ws; (void)ws_size;

  k_wprep<<<dim3(NT21, NLAY), 128, 0, stream>>>(ipW);
  k_wprep2<<<dim3(16, NLAY), 64, 0, stream>>>(opW);
  k_linin<<<2048, 256, 0, stream>>>(x, W_in, b_in);
  for (int l = 0; l < NLAY; ++l){
    k_proj<<<1024, 256, 0, stream>>>(ipb, dtb, l);
    k_s1<<<dim3(NCH, BSZ), 256, 0, stream>>>(A_log, Dp, l);
    k_s2<<<dim3(32, BSZ), 128, 0, stream>>>();
    k_s3<<<dim3(NCH, BSZ), 256, 0, stream>>>(ipb, opb, l, (l == NLAY-1) ? 1 : 0);
  }
  k_pool2<<<BSZ, 64, 0, stream>>>(clsW, clsb, out);
}